// Round 6
// baseline (408.283 us; speedup 1.0000x reference)
//
#include <hip/hip_runtime.h>
#include <hip/hip_bf16.h>

typedef __hip_bfloat16 bf16;
typedef __attribute__((ext_vector_type(8))) short s8v;      // 8 bf16 (4 VGPRs) MFMA A/B frag
typedef __attribute__((ext_vector_type(4))) float f32x4;    // MFMA C/D frag

__device__ __forceinline__ float bits2f(unsigned short u) {
    return __uint_as_float(((unsigned)u) << 16);
}
__device__ __forceinline__ unsigned short f2b(float f) {   // fp32 -> bf16 RNE
    union { float f; unsigned u; } x{f};
    return (unsigned short)((x.u + 0x7fff + ((x.u >> 16) & 1)) >> 16);
}
__device__ __forceinline__ float to_f(float x) { return x; }
__device__ __forceinline__ float to_f(unsigned short x) { return bits2f(x); }

__device__ __forceinline__ void load4(const float* p, float* a) {
    float4 t = *(const float4*)p;
    a[0] = t.x; a[1] = t.y; a[2] = t.z; a[3] = t.w;
}
__device__ __forceinline__ void load4(const unsigned short* p, float* a) {
    ushort4 t = *(const ushort4*)p;
    a[0] = bits2f(t.x); a[1] = bits2f(t.y); a[2] = bits2f(t.z); a[3] = bits2f(t.w);
}

// ---------------- fused fp32 -> bf16 convert of x + all weights ----------------
__global__ __launch_bounds__(256)
void cvt_all_kernel(const float* __restrict__ x,
                    const float* __restrict__ Wq, const float* __restrict__ Wk,
                    const float* __restrict__ Wv, const float* __restrict__ Wo,
                    const float* __restrict__ W1, const float* __restrict__ W2,
                    unsigned short* __restrict__ xb, unsigned short* __restrict__ Wqkvb,
                    unsigned short* __restrict__ Wob,
                    unsigned short* __restrict__ W1b, unsigned short* __restrict__ W2b)
{
    int i = blockIdx.x * 256 + threadIdx.x;
    const float* src; unsigned short* dst; int off;
    if (i < (1 << 20))      { src = x;  dst = xb;  off = i; }
    else if (i < (2 << 20)) { src = W1; dst = W1b; off = i - (1 << 20); }
    else if (i < (3 << 20)) { src = W2; dst = W2b; off = i - (2 << 20); }
    else {
        int j = i - (3 << 20);
        int sel = j >> 18;
        off = j & ((1 << 18) - 1);
        src = sel == 0 ? Wq : sel == 1 ? Wk : sel == 2 ? Wv : Wo;
        dst = sel == 3 ? Wob : Wqkvb + ((size_t)sel << 20);
    }
    float4 v = ((const float4*)src)[off];
    ushort4 o = { f2b(v.x), f2b(v.y), f2b(v.z), f2b(v.w) };
    ((ushort4*)dst)[off] = o;
}

// ---------------- per-head relative-position bias by delta (T5 buckets, double math) ----------------
__global__ void rbias_kernel(const float* __restrict__ rel_emb, unsigned short* __restrict__ rbias)
{
    int idx = blockIdx.x * 256 + threadIdx.x;   // 16 * 2048
    if (idx >= 16 * 2048) return;
    int h = idx >> 11, q = idx & 2047;
    int n = q - 1023, ret = 0;                  // n = j - i
    if (n < 0) { ret = 16; n = -n; }
    int b;
    if (n < 8) b = n;
    else {
        double t = log((double)n / 8.0) / log(16.0) * 8.0;
        int v = 8 + (int)t;
        b = v < 15 ? v : 15;
    }
    rbias[idx] = f2b(rel_emb[(ret + b) * 16 + h]);
}

// ============ 128x128 MFMA GEMM, BK=32 dbuf + FULL conflict-free swizzle ============
// Round-5 structure (issue-early double-buffer, 32KB LDS, XCD swizzle) with the
// BK=32 bank aliasing fixed: slot p(rr,q) = (rr*4 + (q^(rr&3))) ^ (((rr>>2)&1)<<2)
// in 16B units — p mod 8 covers each bank-group exactly twice per 16-lane read
// group (2-way = free, m136). Staging keeps the linear global_load_lds dest and
// applies the INVERSE permutation on the per-lane global source (rule 21):
//   sp = dest slot & 63; r0 = ((sp>>2)^(sp>>4))&1;
//   rr = region*16 | (sp>>2)&0xE | r0;  q = (sp&3) ^ ((((sp>>3)&1)<<1) | r0)
template<typename TC, typename TR, int RELU, int QKV>
__global__ __launch_bounds__(256)
void mfma_gemm(const unsigned short* __restrict__ A, int lda,
               const unsigned short* __restrict__ W, int ldw,
               const float* __restrict__ b0, const float* __restrict__ b1,
               const float* __restrict__ b2,
               const TR* __restrict__ res,
               void* __restrict__ C0, void* __restrict__ C1, void* __restrict__ C2,
               int ldc, int M, int N, int Ksplit)
{
    __shared__ unsigned short sm[4 * 128 * 32];   // 32KB: As[2] + Ws[2], [128][32] each
    const int tid = threadIdx.x;
    const int w = tid >> 6, lane = tid & 63;
    const int quad = lane >> 4, col = lane & 15;

    // XCD-bijective swizzle over the x-y grid (nwg % 8 == 0 for all launches here)
    const int bid = blockIdx.x + gridDim.x * blockIdx.y;
    const int nwg = gridDim.x * gridDim.y;
    const int swz = (bid & 7) * (nwg >> 3) + (bid >> 3);
    const int m0 = (swz / gridDim.x) * 128;
    const int n0 = (swz % gridDim.x) * 128;

    const int wrow = (w & 1) * 64, wcol = (w >> 1) * 64;
    const int kz = blockIdx.z * Ksplit;
    const int NT = Ksplit >> 5;

    // staging geometry: dest slots idx0 = tid, idx1 = 256+tid (512 x 16B per matrix);
    // per-slot inverse permutation gives the (row, k-chunk) whose data lives there.
    int sr0, sq0, sr1, sq1;
    {
        const int i0_ = tid;
        int sp = i0_ & 63, rl = ((sp >> 2) ^ (sp >> 4)) & 1;
        sr0 = ((i0_ >> 6) << 4) | ((sp >> 2) & 0xE) | rl;
        sq0 = (sp & 3) ^ ((((sp >> 3) & 1) << 1) | rl);
        const int i1_ = 256 + tid;
        sp = i1_ & 63; rl = ((sp >> 2) ^ (sp >> 4)) & 1;
        sr1 = ((i1_ >> 6) << 4) | ((sp >> 2) & 0xE) | rl;
        sq1 = (sp & 3) ^ ((((sp >> 3) & 1) << 1) | rl);
    }
    const unsigned off0 = (unsigned)__builtin_amdgcn_readfirstlane((unsigned)((0 * 256 + (tid & 192)) * 16));
    const unsigned off1 = (unsigned)__builtin_amdgcn_readfirstlane((unsigned)((1 * 256 + (tid & 192)) * 16));

#define STAGE32(buf, k0)                                                                     \
    {                                                                                        \
        unsigned short* As_ = sm + (buf) * 4096;                                             \
        unsigned short* Ws_ = sm + 8192 + (buf) * 4096;                                      \
        const unsigned short* ga0 = A + (size_t)(m0 + sr0) * lda + (k0) + sq0 * 8;           \
        __builtin_amdgcn_global_load_lds(                                                    \
            (const __attribute__((address_space(1))) unsigned int*)ga0,                      \
            (__attribute__((address_space(3))) unsigned int*)((char*)As_ + off0), 16, 0, 0); \
        const unsigned short* ga1 = A + (size_t)(m0 + sr1) * lda + (k0) + sq1 * 8;           \
        __builtin_amdgcn_global_load_lds(                                                    \
            (const __attribute__((address_space(1))) unsigned int*)ga1,                      \
            (__attribute__((address_space(3))) unsigned int*)((char*)As_ + off1), 16, 0, 0); \
        const unsigned short* gw0 = W + (size_t)(n0 + sr0) * ldw + (k0) + sq0 * 8;           \
        __builtin_amdgcn_global_load_lds(                                                    \
            (const __attribute__((address_space(1))) unsigned int*)gw0,                      \
            (__attribute__((address_space(3))) unsigned int*)((char*)Ws_ + off0), 16, 0, 0); \
        const unsigned short* gw1 = W + (size_t)(n0 + sr1) * ldw + (k0) + sq1 * 8;           \
        __builtin_amdgcn_global_load_lds(                                                    \
            (const __attribute__((address_space(1))) unsigned int*)gw1,                      \
            (__attribute__((address_space(3))) unsigned int*)((char*)Ws_ + off1), 16, 0, 0); \
    }

    f32x4 acc[4][4] = {};

    STAGE32(0, kz);                      // prologue: tile 0 -> buf 0

    for (int t = 0; t < NT; ++t) {
        __syncthreads();                 // drains buf[cur] staging (issued one phase ago)
        const int cur = t & 1;
        if (t + 1 < NT) STAGE32(cur ^ 1, kz + (t + 1) * 32);   // issue-early (T3)

        const unsigned short* As = sm + cur * 4096;
        const unsigned short* Ws = sm + 8192 + cur * 4096;
        s8v af[4], bfr[4];
        #pragma unroll
        for (int mt = 0; mt < 4; ++mt) {
            int rr = wrow + mt * 16 + col;
            af[mt] = *(const s8v*)(As + ((rr * 32 + ((quad ^ (rr & 3)) << 3)) ^ (((rr >> 2) & 1) << 5)));
        }
        #pragma unroll
        for (int nt = 0; nt < 4; ++nt) {
            int rr = wcol + nt * 16 + col;
            bfr[nt] = *(const s8v*)(Ws + ((rr * 32 + ((quad ^ (rr & 3)) << 3)) ^ (((rr >> 2) & 1) << 5)));
        }
        __builtin_amdgcn_s_setprio(1);
        #pragma unroll
        for (int mt = 0; mt < 4; ++mt)
            #pragma unroll
            for (int nt = 0; nt < 4; ++nt)
                acc[mt][nt] = __builtin_amdgcn_mfma_f32_16x16x32_bf16(af[mt], bfr[nt], acc[mt][nt], 0, 0, 0);
        __builtin_amdgcn_s_setprio(0);
    }
#undef STAGE32

    if (QKV) {
        const int sel = n0 >> 10;
        unsigned short* Cb = (unsigned short*)(sel == 0 ? C0 : sel == 1 ? C1 : C2);
        const float* bs = sel == 0 ? b0 : sel == 1 ? b1 : b2;
        #pragma unroll
        for (int mt = 0; mt < 4; ++mt)
            #pragma unroll
            for (int rg = 0; rg < 4; ++rg) {
                int gm = m0 + wrow + mt * 16 + quad * 4 + rg;
                #pragma unroll
                for (int nt = 0; nt < 4; ++nt) {
                    int gnc = (n0 + wcol + nt * 16 + col) & 1023;
                    Cb[(size_t)gm * 1024 + gnc] = f2b(acc[mt][nt][rg] + bs[gnc]);
                }
            }
    } else {
        void* Cv = blockIdx.z ? C1 : C0;
        const bool z0 = (blockIdx.z == 0);
        #pragma unroll
        for (int mt = 0; mt < 4; ++mt)
            #pragma unroll
            for (int rg = 0; rg < 4; ++rg) {
                int gm = m0 + wrow + mt * 16 + quad * 4 + rg;
                #pragma unroll
                for (int nt = 0; nt < 4; ++nt) {
                    int gn = n0 + wcol + nt * 16 + col;
                    float c = acc[mt][nt][rg];
                    if (z0) {
                        if (b0)  c += b0[gn];
                        if (res) c += to_f(res[(size_t)gm * ldc + gn]);
                    }
                    if (RELU) c = fmaxf(c, 0.f);
                    if (sizeof(TC) == 2) ((unsigned short*)Cv)[(size_t)gm * ldc + gn] = f2b(c);
                    else                 ((float*)Cv)[(size_t)gm * ldc + gn] = c;
                }
            }
    }
}

// ---------------- V transpose: vb bf16 [4096][1024] -> vt bf16 [bp][d][j] ----------------
__global__ __launch_bounds__(256)
void vtrans_kernel(const unsigned short* __restrict__ v, unsigned short* __restrict__ vt)
{
    __shared__ unsigned short t[64][68];
    const int bpmm = blockIdx.x;
    const int bp = bpmm >> 6, mm = bpmm & 63;
    const unsigned short* vr = v + (size_t)(bp * 64 + mm) * 1024;
    const int tid = threadIdx.x;
    #pragma unroll
    for (int it = 0; it < 4; ++it) {
        int c = (tid >> 6) + it * 4;
        int d = tid & 63;
        t[d][c] = vr[c * 64 + d];
    }
    __syncthreads();
    int d = tid >> 2, qq = tid & 3;
    ushort4 o = { t[d][qq * 4 + 0], t[d][qq * 4 + 1], t[d][qq * 4 + 2], t[d][qq * 4 + 3] };
    *(ushort4*)(vt + (size_t)bp * 65536 + (size_t)d * 1024 + mm * 16 + qq * 4) = o;
}

// ---------------- MFMA attention v3 (unchanged, proven) ----------------
__global__ __launch_bounds__(256, 2)
void attn_mfma_kernel(const unsigned short* __restrict__ qb,
                      const unsigned short* __restrict__ kb,
                      const unsigned short* __restrict__ vt,
                      const unsigned short* __restrict__ rbias,
                      const int* __restrict__ pmask,
                      unsigned short* __restrict__ att)
{
    __shared__ unsigned short Qs[128 * 64];
    __shared__ unsigned short KP[128 * 64];
    __shared__ unsigned short Vt[64 * 128];
    __shared__ unsigned short rbs[2048];
    __shared__ unsigned short pmls[1024];

    const int tid = threadIdx.x;
    const int w = tid >> 6, lane = tid & 63;
    const int quad = lane >> 4, col = lane & 15;
    const int bp = blockIdx.x, i0 = blockIdx.y * 128;
    const int h = bp & 15, bb = bp >> 4;
    const size_t base = (size_t)bp << 16;
    const int myrow0 = w * 32, myrow1 = w * 32 + 16;

    {
        const unsigned short* qg = qb + base + (size_t)i0 * 64;
        #pragma unroll
        for (int it = 0; it < 4; ++it) {
            int idx = it * 256 + tid;
            int r = idx >> 3, c = idx & 7;
            s8v d = *(const s8v*)(qg + (size_t)r * 64 + (c ^ (r & 7)) * 8);
            *(s8v*)(Qs + r * 64 + c * 8) = d;
        }
    }
    {
        const unsigned short* rg = rbias + h * 2048;
        #pragma unroll
        for (int it = 0; it < 8; ++it) rbs[it * 256 + tid] = rg[it * 256 + tid];
    }
    #pragma unroll
    for (int it = 0; it < 4; ++it) {
        int j = it * 256 + tid;
        pmls[j] = f2b(__logf((float)pmask[bb * 1024 + j]));
    }

    f32x4 O0[4] = {}, O1[4] = {};
    float lrow0[4] = {0.f, 0.f, 0.f, 0.f};
    float lrow1[4] = {0.f, 0.f, 0.f, 0.f};

    unsigned short* Pw = KP + w * 2048;

    for (int jt = 0; jt < 8; ++jt) {
        const int j0 = jt * 128;
        __syncthreads();
        {
            const unsigned short* kg = kb + base + (size_t)j0 * 64;
            #pragma unroll
            for (int it = 0; it < 4; ++it) {
                int idx = it * 256 + tid;
                int r = idx >> 3, c = idx & 7;
                s8v d = *(const s8v*)(kg + (size_t)r * 64 + (c ^ (r & 7)) * 8);
                *(s8v*)(KP + r * 64 + c * 8) = d;
            }
            const unsigned short* vg = vt + base + j0;
            #pragma unroll
            for (int it = 0; it < 4; ++it) {
                int idx = it * 256 + tid;
                int r = idx >> 4, c = idx & 15;
                s8v d = *(const s8v*)(vg + (size_t)r * 1024 + (c ^ (r & 15)) * 8);
                *(s8v*)(Vt + r * 128 + c * 8) = d;
            }
        }
        __syncthreads();

        f32x4 S0[8] = {}, S1[8] = {};
        #pragma unroll
        for (int ks = 0; ks < 2; ++ks) {
            int ar0 = myrow0 + col, ar1 = myrow1 + col;
            s8v a0 = *(const s8v*)(Qs + ar0 * 64 + (((ks * 4 + quad) ^ (ar0 & 7)) * 8));
            s8v a1 = *(const s8v*)(Qs + ar1 * 64 + (((ks * 4 + quad) ^ (ar1 & 7)) * 8));
            #pragma unroll
            for (int ct = 0; ct < 8; ++ct) {
                int br = ct * 16 + col;
                s8v b = *(const s8v*)(KP + br * 64 + (((ks * 4 + quad) ^ (br & 7)) * 8));
                S0[ct] = __builtin_amdgcn_mfma_f32_16x16x32_bf16(a0, b, S0[ct], 0, 0, 0);
                S1[ct] = __builtin_amdgcn_mfma_f32_16x16x32_bf16(a1, b, S1[ct], 0, 0, 0);
            }
        }

        #pragma unroll
        for (int ct = 0; ct < 8; ++ct) {
            int gj = j0 + ct * 16 + col;
            float pmv = bits2f(pmls[gj]);
            int d0 = gj - (i0 + myrow0 + quad * 4) + 1023;
            int d1 = gj - (i0 + myrow1 + quad * 4) + 1023;
            #pragma unroll
            for (int r = 0; r < 4; ++r) {
                float e0 = __expf(S0[ct][r] + bits2f(rbs[d0 - r]) + pmv);
                float e1 = __expf(S1[ct][r] + bits2f(rbs[d1 - r]) + pmv);
                S0[ct][r] = e0; lrow0[r] += e0;
                S1[ct][r] = e1; lrow1[r] += e1;
            }
        }

        __syncthreads();

        #pragma unroll
        for (int ct = 0; ct < 8; ++ct)
            #pragma unroll
            for (int r = 0; r < 4; ++r) {
                int lr = quad * 4 + r;
                int j = ct * 16 + col;
                Pw[lr * 128 + (((j >> 3) ^ lr) << 3) + (j & 7)] = f2b(S0[ct][r]);
            }
        #pragma unroll
        for (int kt = 0; kt < 4; ++kt) {
            int pr = col;
            s8v a = *(const s8v*)(Pw + pr * 128 + (((kt * 4 + quad) ^ pr) * 8));
            #pragma unroll
            for (int nt = 0; nt < 4; ++nt) {
                int vr = nt * 16 + col;
                s8v b = *(const s8v*)(Vt + vr * 128 + (((kt * 4 + quad) ^ (vr & 15)) * 8));
                O0[nt] = __builtin_amdgcn_mfma_f32_16x16x32_bf16(a, b, O0[nt], 0, 0, 0);
            }
        }

        #pragma unroll
        for (int ct = 0; ct < 8; ++ct)
            #pragma unroll
            for (int r = 0; r < 4; ++r) {
                int lr = quad * 4 + r;
                int j = ct * 16 + col;
                Pw[lr * 128 + (((j >> 3) ^ lr) << 3) + (j & 7)] = f2b(S1[ct][r]);
            }
        #pragma unroll
        for (int kt = 0; kt < 4; ++kt) {
            int pr = col;
            s8v a = *(const s8v*)(Pw + pr * 128 + (((kt * 4 + quad) ^ pr) * 8));
            #pragma unroll
            for (int nt = 0; nt < 4; ++nt) {
                int vr = nt * 16 + col;
                s8v b = *(const s8v*)(Vt + vr * 128 + (((kt * 4 + quad) ^ (vr & 15)) * 8));
                O1[nt] = __builtin_amdgcn_mfma_f32_16x16x32_bf16(a, b, O1[nt], 0, 0, 0);
            }
        }
    }

    #pragma unroll
    for (int off = 1; off < 16; off <<= 1)
        #pragma unroll
        for (int r = 0; r < 4; ++r) {
            lrow0[r] += __shfl_xor(lrow0[r], off);
            lrow1[r] += __shfl_xor(lrow1[r], off);
        }
    #pragma unroll
    for (int r = 0; r < 4; ++r) {
        lrow0[r] = 1.f / lrow0[r];
        lrow1[r] = 1.f / lrow1[r];
    }

    unsigned short* ag0 = att + base + (size_t)(i0 + myrow0) * 64;
    unsigned short* ag1 = att + base + (size_t)(i0 + myrow1) * 64;
    #pragma unroll
    for (int nt = 0; nt < 4; ++nt)
        #pragma unroll
        for (int r = 0; r < 4; ++r) {
            ag0[(size_t)(quad * 4 + r) * 64 + nt * 16 + col] = f2b(O0[nt][r] * lrow0[r]);
            ag1[(size_t)(quad * 4 + r) * 64 + nt * 16 + col] = f2b(O1[nt][r] * lrow1[r]);
        }
}

// ---------------- layernorm over rows of 1024: in1+in2 -> (outF fp32, outB bf16) ----------------
template<typename TIN>
__global__ __launch_bounds__(256)
void ln_kernel(const TIN* __restrict__ in1, const TIN* __restrict__ in2,
               float* __restrict__ outF, unsigned short* __restrict__ outB)
{
    __shared__ float sred[8];
    const int row = blockIdx.x;
    const int tid = threadIdx.x;
    const size_t off = (size_t)row * 1024 + tid * 4;
    float a[4];
    load4(in1 + off, a);
    if (in2) {
        float b[4];
        load4(in2 + off, b);
        #pragma unroll
        for (int i = 0; i < 4; ++i) a[i] += b[i];
    }

    float lsum = a[0] + a[1] + a[2] + a[3];
    #pragma unroll
    for (int o = 32; o; o >>= 1) lsum += __shfl_down(lsum, o);
    const int lane = tid & 63, wid = tid >> 6;
    if (lane == 0) sred[wid] = lsum;
    __syncthreads();
    if (tid == 0) sred[4] = (sred[0] + sred[1] + sred[2] + sred[3]) * (1.f / 1024.f);
    __syncthreads();
    const float mean = sred[4];

    float d0 = a[0] - mean, d1 = a[1] - mean, d2 = a[2] - mean, d3 = a[3] - mean;
    float lsq = d0 * d0 + d1 * d1 + d2 * d2 + d3 * d3;
    #pragma unroll
    for (int o = 32; o; o >>= 1) lsq += __shfl_down(lsq, o);
    __syncthreads();
    if (lane == 0) sred[wid] = lsq;
    __syncthreads();
    if (tid == 0) sred[5] = rsqrtf((sred[0] + sred[1] + sred[2] + sred[3]) * (1.f / 1024.f));
    __syncthreads();
    const float r = sred[5];

    float o0 = d0 * r, o1 = d1 * r, o2 = d2 * r, o3 = d3 * r;
    if (outF) {
        float4 o = {o0, o1, o2, o3};
        *(float4*)&outF[off] = o;
    }
    if (outB) {
        ushort4 o = { f2b(o0), f2b(o1), f2b(o2), f2b(o3) };
        *(ushort4*)&outB[off] = o;
    }
}

extern "C" void kernel_launch(void* const* d_in, const int* in_sizes, int n_in,
                              void* d_out, int out_size, void* d_ws, size_t ws_size,
                              hipStream_t stream)
{
    const float* x     = (const float*)d_in[0];
    const int*   pmask = (const int*)  d_in[1];
    const float* Wq    = (const float*)d_in[2];
    const float* bq    = (const float*)d_in[3];
    const float* Wk    = (const float*)d_in[4];
    const float* bk    = (const float*)d_in[5];
    const float* Wv    = (const float*)d_in[6];
    const float* bv    = (const float*)d_in[7];
    const float* Wo    = (const float*)d_in[8];
    const float* bo    = (const float*)d_in[9];
    const float* rel   = (const float*)d_in[10];
    const float* W1    = (const float*)d_in[11];
    const float* b1    = (const float*)d_in[12];
    const float* W2    = (const float*)d_in[13];
    const float* b2    = (const float*)d_in[14];

    const int M = 4096, D = 1024;
    dim3 blk(256);

    // ---- workspace map (identical to round-7/8-proven; peak write 64MB+64KB) ----
    char* ws = (char*)d_ws;
    unsigned short* W1b   = (unsigned short*)(ws);                 // 0-8
    unsigned short* W2b   = (unsigned short*)(ws + ( 8u << 20));   // 8-16
    unsigned short* xb    = (unsigned short*)(ws + (16u << 20));   // 16-24
    unsigned short* Wqkvb = (unsigned short*)(ws + (24u << 20));   // 24-30
    unsigned short* Wob   = (unsigned short*)(ws + (30u << 20));   // 30-32
    unsigned short* qb    = (unsigned short*)(ws + (32u << 20));   // 32-40
    unsigned short* kb    = (unsigned short*)(ws + (40u << 20));   // 40-48
    unsigned short* vb    = (unsigned short*)(ws + (48u << 20));   // 48-56
    unsigned short* vt    = (unsigned short*)(ws + (56u << 20));   // 56-64
    unsigned short* rbias = (unsigned short*)(ws + (64u << 20));   // 64-64.0625
    float*          tmpA    = (float*)(ws + (32u << 20));          // 32-48 (qb/kb dead after attn)
    float*          tmpB    = (float*)(ws + (48u << 20));          // 48-64 (vb/vt dead after attn)
    unsigned short* attoutB = (unsigned short*)(ws + (16u << 20)); // 16-24 (xb dead after qkv)
    unsigned short* ff1     = (unsigned short*)(ws + (32u << 20)); // 32-64 (tmpA/B dead after ln1)
    unsigned short* ff2a    = (unsigned short*)(ws);               // 0-8   (W1b dead after ff1)
    unsigned short* ff2b    = (unsigned short*)(ws + (24u << 20)); // 24-32 (Wqkvb/Wob dead)
    unsigned short* attb    = (unsigned short*)d_out;              // d_out scratch (proven)

    // ---- conversions / tables ----
    cvt_all_kernel<<<16384, blk, 0, stream>>>(x, Wq, Wk, Wv, Wo, W1, W2,
                                              xb, Wqkvb, Wob, W1b, W2b);
    rbias_kernel<<<128, blk, 0, stream>>>(rel, rbias);

    // ---- fused QKV projection: N=3072, routed to qb/kb/vb ----
    mfma_gemm<unsigned short, float, 0, 1><<<dim3(24, 32), blk, 0, stream>>>(
        xb, D, Wqkvb, D, bq, bk, bv, (const float*)nullptr, qb, kb, vb, D, M, 3072, D);

    vtrans_kernel<<<4096, blk, 0, stream>>>(vb, vt);

    // ---- attention v3: 128-query tiles, bp-major grid, 2 blocks/CU even ----
    attn_mfma_kernel<<<dim3(64, 8), blk, 0, stream>>>(qb, kb, vt, rbias, pmask, attb);

    // ---- Wo projection + residual x, split-K z=2 -> tmpA/tmpB fp32; LN1 -> attoutB ----
    mfma_gemm<float, float, 0, 0><<<dim3(8, 32, 2), blk, 0, stream>>>(
        attb, D, Wob, D, bo, nullptr, nullptr, x, tmpA, tmpB, nullptr, D, M, D, 512);
    ln_kernel<float><<<4096, blk, 0, stream>>>(tmpA, tmpB, nullptr, attoutB);

    // ---- FFN: ff1 full N=4096; ff2 split-K z=2 (res = attoutB bf16); LN2 sums ----
    mfma_gemm<unsigned short, float, 1, 0><<<dim3(32, 32), blk, 0, stream>>>(
        attoutB, D, W1b, D, b1, nullptr, nullptr, (const float*)nullptr,
        ff1, nullptr, nullptr, 4096, M, 4096, D);
    mfma_gemm<unsigned short, unsigned short, 0, 0><<<dim3(8, 32, 2), blk, 0, stream>>>(
        ff1, 4096, W2b, 4096, b2, nullptr, nullptr, attoutB, ff2a, ff2b, nullptr, D, M, D, 2048);
    ln_kernel<unsigned short><<<4096, blk, 0, stream>>>(ff2a, ff2b, (float*)d_out, nullptr);
}

// Round 7
// 396.155 us; speedup vs baseline: 1.0306x; 1.0306x over previous
//
#include <hip/hip_runtime.h>
#include <hip/hip_bf16.h>

typedef __hip_bfloat16 bf16;
typedef __attribute__((ext_vector_type(8))) short s8v;      // 8 bf16 (4 VGPRs) MFMA A/B frag
typedef __attribute__((ext_vector_type(4))) float f32x4;    // MFMA C/D frag

__device__ __forceinline__ float bits2f(unsigned short u) {
    return __uint_as_float(((unsigned)u) << 16);
}
__device__ __forceinline__ unsigned short f2b(float f) {   // fp32 -> bf16 RNE
    union { float f; unsigned u; } x{f};
    return (unsigned short)((x.u + 0x7fff + ((x.u >> 16) & 1)) >> 16);
}
__device__ __forceinline__ float to_f(float x) { return x; }
__device__ __forceinline__ float to_f(unsigned short x) { return bits2f(x); }

__device__ __forceinline__ void load4(const float* p, float* a) {
    float4 t = *(const float4*)p;
    a[0] = t.x; a[1] = t.y; a[2] = t.z; a[3] = t.w;
}
__device__ __forceinline__ void load4(const unsigned short* p, float* a) {
    ushort4 t = *(const ushort4*)p;
    a[0] = bits2f(t.x); a[1] = bits2f(t.y); a[2] = bits2f(t.z); a[3] = bits2f(t.w);
}

// ---------------- fused fp32 -> bf16 convert of x + all weights ----------------
__global__ __launch_bounds__(256)
void cvt_all_kernel(const float* __restrict__ x,
                    const float* __restrict__ Wq, const float* __restrict__ Wk,
                    const float* __restrict__ Wv, const float* __restrict__ Wo,
                    const float* __restrict__ W1, const float* __restrict__ W2,
                    unsigned short* __restrict__ xb, unsigned short* __restrict__ Wqkvb,
                    unsigned short* __restrict__ Wob,
                    unsigned short* __restrict__ W1b, unsigned short* __restrict__ W2b)
{
    int i = blockIdx.x * 256 + threadIdx.x;
    const float* src; unsigned short* dst; int off;
    if (i < (1 << 20))      { src = x;  dst = xb;  off = i; }
    else if (i < (2 << 20)) { src = W1; dst = W1b; off = i - (1 << 20); }
    else if (i < (3 << 20)) { src = W2; dst = W2b; off = i - (2 << 20); }
    else {
        int j = i - (3 << 20);
        int sel = j >> 18;
        off = j & ((1 << 18) - 1);
        src = sel == 0 ? Wq : sel == 1 ? Wk : sel == 2 ? Wv : Wo;
        dst = sel == 3 ? Wob : Wqkvb + ((size_t)sel << 20);
    }
    float4 v = ((const float4*)src)[off];
    ushort4 o = { f2b(v.x), f2b(v.y), f2b(v.z), f2b(v.w) };
    ((ushort4*)dst)[off] = o;
}

// ---------------- per-head relative-position bias by delta (T5 buckets, double math) ----------------
__global__ void rbias_kernel(const float* __restrict__ rel_emb, unsigned short* __restrict__ rbias)
{
    int idx = blockIdx.x * 256 + threadIdx.x;   // 16 * 2048
    if (idx >= 16 * 2048) return;
    int h = idx >> 11, q = idx & 2047;
    int n = q - 1023, ret = 0;                  // n = j - i
    if (n < 0) { ret = 16; n = -n; }
    int b;
    if (n < 8) b = n;
    else {
        double t = log((double)n / 8.0) / log(16.0) * 8.0;
        int v = 8 + (int)t;
        b = v < 15 ? v : 15;
    }
    rbias[idx] = f2b(rel_emb[(ret + b) * 16 + h]);
}

// ============ 256x128 MFMA GEMM, 8 waves, BK=32 dbuf, 2D-XCD chunking ============
// R4/5/6 showed the K-loop schedule is off the critical path (3 variants, same
// 70.4us). This round attacks the macro structure: (1) 256x128 tile halves the
// block count, doubles MFMA/barrier, amortizes per-block fixed cost; (2) 2D XCD
// chunking — XCD (= bid%8) owns a (gy/2)x(gx/4) rectangle of tiles, cutting the
// all-B-per-XCD refetch of the 1D swizzle (ff1: ~70MB -> ~48MB predicted).
// Inner loop, slot swizzle, and staging are verbatim from the verified R6 kernel
// (wave output 64x64, 4x4 frags, same per-wave instruction stream).
template<typename TC, typename TR, int RELU, int QKV>
__global__ __launch_bounds__(512)
void mfma_gemm(const unsigned short* __restrict__ A, int lda,
               const unsigned short* __restrict__ W, int ldw,
               const float* __restrict__ b0, const float* __restrict__ b1,
               const float* __restrict__ b2,
               const TR* __restrict__ res,
               void* __restrict__ C0, void* __restrict__ C1, void* __restrict__ C2,
               int ldc, int M, int N, int Ksplit)
{
    __shared__ unsigned short sm[2 * 8192 + 2 * 4096];   // 48KB: A dbuf [2][256][32], W dbuf [2][128][32]
    const int tid = threadIdx.x;
    const int w = tid >> 6, lane = tid & 63;
    const int quad = lane >> 4, col = lane & 15;

    // 2D XCD chunking: hw places bid%8 on XCD (gx*gy % 8 == 0 for all launches);
    // XCD owns rect rows [(xcd&1)*rh, +rh) x cols [(xcd>>1)*cw, +cw); gy%2==0, gx%4==0.
    const int bid = blockIdx.x + gridDim.x * blockIdx.y;
    const int xcd = bid & 7, j = bid >> 3;
    const int rh = gridDim.y >> 1, cw = gridDim.x >> 2;
    const int m0 = (((xcd & 1) * rh) + (j % rh)) * 256;
    const int n0 = (((xcd >> 1) * cw) + (j / rh)) * 128;

    const int wrow = (w & 3) * 64, wcol = (w >> 2) * 64;
    const int kz = blockIdx.z * Ksplit;
    const int NT = Ksplit >> 5;

    // staging slots: A idx0 = tid, idx1 = 512+tid (1024 x 16B); W idx2 = tid (512 x 16B).
    // inverse of slot perm p(rr,q) = ((rr&15)*4 + (q^(rr&3))) ^ (((rr>>2)&1)<<2) per
    // 64-slot (16-row) region (verified R6): from slot sp: r0=(sp>>2 ^ sp>>4)&1,
    // rr = region<<4 | (sp>>2)&0xE | r0, q = (sp&3) ^ (((sp>>3)&1)<<1 | r0).
    int sr0, sq0, sr1, sq1, sr2, sq2;
    {
        int idx = tid;
        int sp = idx & 63, rl = ((sp >> 2) ^ (sp >> 4)) & 1;
        sr0 = ((idx >> 6) << 4) | ((sp >> 2) & 0xE) | rl;
        sq0 = (sp & 3) ^ ((((sp >> 3) & 1) << 1) | rl);
        idx = 512 + tid;
        sp = idx & 63; rl = ((sp >> 2) ^ (sp >> 4)) & 1;
        sr1 = ((idx >> 6) << 4) | ((sp >> 2) & 0xE) | rl;
        sq1 = (sp & 3) ^ ((((sp >> 3) & 1) << 1) | rl);
        sr2 = sr0; sq2 = sq0;                           // W uses slots 0..511 too
    }
    const unsigned offA0 = (unsigned)__builtin_amdgcn_readfirstlane((unsigned)((tid & 448) * 16));
    const unsigned offA1 = (unsigned)__builtin_amdgcn_readfirstlane((unsigned)((512 + (tid & 448)) * 16));
    const unsigned offW0 = offA0;

#define STAGE(buf, k0)                                                                       \
    {                                                                                        \
        unsigned short* As_ = sm + (buf) * 8192;                                             \
        unsigned short* Ws_ = sm + 16384 + (buf) * 4096;                                     \
        const unsigned short* ga0 = A + (size_t)(m0 + sr0) * lda + (k0) + sq0 * 8;           \
        __builtin_amdgcn_global_load_lds(                                                    \
            (const __attribute__((address_space(1))) unsigned int*)ga0,                      \
            (__attribute__((address_space(3))) unsigned int*)((char*)As_ + offA0), 16, 0, 0);\
        const unsigned short* ga1 = A + (size_t)(m0 + sr1) * lda + (k0) + sq1 * 8;           \
        __builtin_amdgcn_global_load_lds(                                                    \
            (const __attribute__((address_space(1))) unsigned int*)ga1,                      \
            (__attribute__((address_space(3))) unsigned int*)((char*)As_ + offA1), 16, 0, 0);\
        const unsigned short* gw0 = W + (size_t)(n0 + sr2) * ldw + (k0) + sq2 * 8;           \
        __builtin_amdgcn_global_load_lds(                                                    \
            (const __attribute__((address_space(1))) unsigned int*)gw0,                      \
            (__attribute__((address_space(3))) unsigned int*)((char*)Ws_ + offW0), 16, 0, 0);\
    }

    f32x4 acc[4][4] = {};

    STAGE(0, kz);                        // prologue: tile 0 -> buf 0

    for (int t = 0; t < NT; ++t) {
        __syncthreads();                 // drains buf[cur] staging (issued one phase ago)
        const int cur = t & 1;
        if (t + 1 < NT) STAGE(cur ^ 1, kz + (t + 1) * 32);   // issue-early (T3)

        const unsigned short* As = sm + cur * 8192;
        const unsigned short* Ws = sm + 16384 + cur * 4096;
        s8v af[4], bfr[4];
        #pragma unroll
        for (int mt = 0; mt < 4; ++mt) {
            int rr = wrow + mt * 16 + col;
            af[mt] = *(const s8v*)(As + ((rr * 32 + ((quad ^ (rr & 3)) << 3)) ^ (((rr >> 2) & 1) << 5)));
        }
        #pragma unroll
        for (int nt = 0; nt < 4; ++nt) {
            int rr = wcol + nt * 16 + col;
            bfr[nt] = *(const s8v*)(Ws + ((rr * 32 + ((quad ^ (rr & 3)) << 3)) ^ (((rr >> 2) & 1) << 5)));
        }
        __builtin_amdgcn_s_setprio(1);
        #pragma unroll
        for (int mt = 0; mt < 4; ++mt)
            #pragma unroll
            for (int nt = 0; nt < 4; ++nt)
                acc[mt][nt] = __builtin_amdgcn_mfma_f32_16x16x32_bf16(af[mt], bfr[nt], acc[mt][nt], 0, 0, 0);
        __builtin_amdgcn_s_setprio(0);
    }
#undef STAGE

    if (QKV) {
        const int sel = n0 >> 10;
        unsigned short* Cb = (unsigned short*)(sel == 0 ? C0 : sel == 1 ? C1 : C2);
        const float* bs = sel == 0 ? b0 : sel == 1 ? b1 : b2;
        #pragma unroll
        for (int mt = 0; mt < 4; ++mt)
            #pragma unroll
            for (int rg = 0; rg < 4; ++rg) {
                int gm = m0 + wrow + mt * 16 + quad * 4 + rg;
                #pragma unroll
                for (int nt = 0; nt < 4; ++nt) {
                    int gnc = (n0 + wcol + nt * 16 + col) & 1023;
                    Cb[(size_t)gm * 1024 + gnc] = f2b(acc[mt][nt][rg] + bs[gnc]);
                }
            }
    } else {
        void* Cv = blockIdx.z ? C1 : C0;
        const bool z0 = (blockIdx.z == 0);
        #pragma unroll
        for (int mt = 0; mt < 4; ++mt)
            #pragma unroll
            for (int rg = 0; rg < 4; ++rg) {
                int gm = m0 + wrow + mt * 16 + quad * 4 + rg;
                #pragma unroll
                for (int nt = 0; nt < 4; ++nt) {
                    int gn = n0 + wcol + nt * 16 + col;
                    float c = acc[mt][nt][rg];
                    if (z0) {
                        if (b0)  c += b0[gn];
                        if (res) c += to_f(res[(size_t)gm * ldc + gn]);
                    }
                    if (RELU) c = fmaxf(c, 0.f);
                    if (sizeof(TC) == 2) ((unsigned short*)Cv)[(size_t)gm * ldc + gn] = f2b(c);
                    else                 ((float*)Cv)[(size_t)gm * ldc + gn] = c;
                }
            }
    }
}

// ---------------- V transpose: vb bf16 [4096][1024] -> vt bf16 [bp][d][j] ----------------
__global__ __launch_bounds__(256)
void vtrans_kernel(const unsigned short* __restrict__ v, unsigned short* __restrict__ vt)
{
    __shared__ unsigned short t[64][68];
    const int bpmm = blockIdx.x;
    const int bp = bpmm >> 6, mm = bpmm & 63;
    const unsigned short* vr = v + (size_t)(bp * 64 + mm) * 1024;
    const int tid = threadIdx.x;
    #pragma unroll
    for (int it = 0; it < 4; ++it) {
        int c = (tid >> 6) + it * 4;
        int d = tid & 63;
        t[d][c] = vr[c * 64 + d];
    }
    __syncthreads();
    int d = tid >> 2, qq = tid & 3;
    ushort4 o = { t[d][qq * 4 + 0], t[d][qq * 4 + 1], t[d][qq * 4 + 2], t[d][qq * 4 + 3] };
    *(ushort4*)(vt + (size_t)bp * 65536 + (size_t)d * 1024 + mm * 16 + qq * 4) = o;
}

// ---------------- MFMA attention v3 (unchanged, proven) ----------------
__global__ __launch_bounds__(256, 2)
void attn_mfma_kernel(const unsigned short* __restrict__ qb,
                      const unsigned short* __restrict__ kb,
                      const unsigned short* __restrict__ vt,
                      const unsigned short* __restrict__ rbias,
                      const int* __restrict__ pmask,
                      unsigned short* __restrict__ att)
{
    __shared__ unsigned short Qs[128 * 64];
    __shared__ unsigned short KP[128 * 64];
    __shared__ unsigned short Vt[64 * 128];
    __shared__ unsigned short rbs[2048];
    __shared__ unsigned short pmls[1024];

    const int tid = threadIdx.x;
    const int w = tid >> 6, lane = tid & 63;
    const int quad = lane >> 4, col = lane & 15;
    const int bp = blockIdx.x, i0 = blockIdx.y * 128;
    const int h = bp & 15, bb = bp >> 4;
    const size_t base = (size_t)bp << 16;
    const int myrow0 = w * 32, myrow1 = w * 32 + 16;

    {
        const unsigned short* qg = qb + base + (size_t)i0 * 64;
        #pragma unroll
        for (int it = 0; it < 4; ++it) {
            int idx = it * 256 + tid;
            int r = idx >> 3, c = idx & 7;
            s8v d = *(const s8v*)(qg + (size_t)r * 64 + (c ^ (r & 7)) * 8);
            *(s8v*)(Qs + r * 64 + c * 8) = d;
        }
    }
    {
        const unsigned short* rg = rbias + h * 2048;
        #pragma unroll
        for (int it = 0; it < 8; ++it) rbs[it * 256 + tid] = rg[it * 256 + tid];
    }
    #pragma unroll
    for (int it = 0; it < 4; ++it) {
        int j = it * 256 + tid;
        pmls[j] = f2b(__logf((float)pmask[bb * 1024 + j]));
    }

    f32x4 O0[4] = {}, O1[4] = {};
    float lrow0[4] = {0.f, 0.f, 0.f, 0.f};
    float lrow1[4] = {0.f, 0.f, 0.f, 0.f};

    unsigned short* Pw = KP + w * 2048;

    for (int jt = 0; jt < 8; ++jt) {
        const int j0 = jt * 128;
        __syncthreads();
        {
            const unsigned short* kg = kb + base + (size_t)j0 * 64;
            #pragma unroll
            for (int it = 0; it < 4; ++it) {
                int idx = it * 256 + tid;
                int r = idx >> 3, c = idx & 7;
                s8v d = *(const s8v*)(kg + (size_t)r * 64 + (c ^ (r & 7)) * 8);
                *(s8v*)(KP + r * 64 + c * 8) = d;
            }
            const unsigned short* vg = vt + base + j0;
            #pragma unroll
            for (int it = 0; it < 4; ++it) {
                int idx = it * 256 + tid;
                int r = idx >> 4, c = idx & 15;
                s8v d = *(const s8v*)(vg + (size_t)r * 1024 + (c ^ (r & 15)) * 8);
                *(s8v*)(Vt + r * 128 + c * 8) = d;
            }
        }
        __syncthreads();

        f32x4 S0[8] = {}, S1[8] = {};
        #pragma unroll
        for (int ks = 0; ks < 2; ++ks) {
            int ar0 = myrow0 + col, ar1 = myrow1 + col;
            s8v a0 = *(const s8v*)(Qs + ar0 * 64 + (((ks * 4 + quad) ^ (ar0 & 7)) * 8));
            s8v a1 = *(const s8v*)(Qs + ar1 * 64 + (((ks * 4 + quad) ^ (ar1 & 7)) * 8));
            #pragma unroll
            for (int ct = 0; ct < 8; ++ct) {
                int br = ct * 16 + col;
                s8v b = *(const s8v*)(KP + br * 64 + (((ks * 4 + quad) ^ (br & 7)) * 8));
                S0[ct] = __builtin_amdgcn_mfma_f32_16x16x32_bf16(a0, b, S0[ct], 0, 0, 0);
                S1[ct] = __builtin_amdgcn_mfma_f32_16x16x32_bf16(a1, b, S1[ct], 0, 0, 0);
            }
        }

        #pragma unroll
        for (int ct = 0; ct < 8; ++ct) {
            int gj = j0 + ct * 16 + col;
            float pmv = bits2f(pmls[gj]);
            int d0 = gj - (i0 + myrow0 + quad * 4) + 1023;
            int d1 = gj - (i0 + myrow1 + quad * 4) + 1023;
            #pragma unroll
            for (int r = 0; r < 4; ++r) {
                float e0 = __expf(S0[ct][r] + bits2f(rbs[d0 - r]) + pmv);
                float e1 = __expf(S1[ct][r] + bits2f(rbs[d1 - r]) + pmv);
                S0[ct][r] = e0; lrow0[r] += e0;
                S1[ct][r] = e1; lrow1[r] += e1;
            }
        }

        __syncthreads();

        #pragma unroll
        for (int ct = 0; ct < 8; ++ct)
            #pragma unroll
            for (int r = 0; r < 4; ++r) {
                int lr = quad * 4 + r;
                int j = ct * 16 + col;
                Pw[lr * 128 + (((j >> 3) ^ lr) << 3) + (j & 7)] = f2b(S0[ct][r]);
            }
        #pragma unroll
        for (int kt = 0; kt < 4; ++kt) {
            int pr = col;
            s8v a = *(const s8v*)(Pw + pr * 128 + (((kt * 4 + quad) ^ pr) * 8));
            #pragma unroll
            for (int nt = 0; nt < 4; ++nt) {
                int vr = nt * 16 + col;
                s8v b = *(const s8v*)(Vt + vr * 128 + (((kt * 4 + quad) ^ (vr & 15)) * 8));
                O0[nt] = __builtin_amdgcn_mfma_f32_16x16x32_bf16(a, b, O0[nt], 0, 0, 0);
            }
        }

        #pragma unroll
        for (int ct = 0; ct < 8; ++ct)
            #pragma unroll
            for (int r = 0; r < 4; ++r) {
                int lr = quad * 4 + r;
                int j = ct * 16 + col;
                Pw[lr * 128 + (((j >> 3) ^ lr) << 3) + (j & 7)] = f2b(S1[ct][r]);
            }
        #pragma unroll
        for (int kt = 0; kt < 4; ++kt) {
            int pr = col;
            s8v a = *(const s8v*)(Pw + pr * 128 + (((kt * 4 + quad) ^ pr) * 8));
            #pragma unroll
            for (int nt = 0; nt < 4; ++nt) {
                int vr = nt * 16 + col;
                s8v b = *(const s8v*)(Vt + vr * 128 + (((kt * 4 + quad) ^ (vr & 15)) * 8));
                O1[nt] = __builtin_amdgcn_mfma_f32_16x16x32_bf16(a, b, O1[nt], 0, 0, 0);
            }
        }
    }

    #pragma unroll
    for (int off = 1; off < 16; off <<= 1)
        #pragma unroll
        for (int r = 0; r < 4; ++r) {
            lrow0[r] += __shfl_xor(lrow0[r], off);
            lrow1[r] += __shfl_xor(lrow1[r], off);
        }
    #pragma unroll
    for (int r = 0; r < 4; ++r) {
        lrow0[r] = 1.f / lrow0[r];
        lrow1[r] = 1.f / lrow1[r];
    }

    unsigned short* ag0 = att + base + (size_t)(i0 + myrow0) * 64;
    unsigned short* ag1 = att + base + (size_t)(i0 + myrow1) * 64;
    #pragma unroll
    for (int nt = 0; nt < 4; ++nt)
        #pragma unroll
        for (int r = 0; r < 4; ++r) {
            ag0[(size_t)(quad * 4 + r) * 64 + nt * 16 + col] = f2b(O0[nt][r] * lrow0[r]);
            ag1[(size_t)(quad * 4 + r) * 64 + nt * 16 + col] = f2b(O1[nt][r] * lrow1[r]);
        }
}

// ---------------- layernorm over rows of 1024: in1+in2 -> (outF fp32, outB bf16) ----------------
template<typename TIN>
__global__ __launch_bounds__(256)
void ln_kernel(const TIN* __restrict__ in1, const TIN* __restrict__ in2,
               float* __restrict__ outF, unsigned short* __restrict__ outB)
{
    __shared__ float sred[8];
    const int row = blockIdx.x;
    const int tid = threadIdx.x;
    const size_t off = (size_t)row * 1024 + tid * 4;
    float a[4];
    load4(in1 + off, a);
    if (in2) {
        float b[4];
        load4(in2 + off, b);
        #pragma unroll
        for (int i = 0; i < 4; ++i) a[i] += b[i];
    }

    float lsum = a[0] + a[1] + a[2] + a[3];
    #pragma unroll
    for (int o = 32; o; o >>= 1) lsum += __shfl_down(lsum, o);
    const int lane = tid & 63, wid = tid >> 6;
    if (lane == 0) sred[wid] = lsum;
    __syncthreads();
    if (tid == 0) sred[4] = (sred[0] + sred[1] + sred[2] + sred[3]) * (1.f / 1024.f);
    __syncthreads();
    const float mean = sred[4];

    float d0 = a[0] - mean, d1 = a[1] - mean, d2 = a[2] - mean, d3 = a[3] - mean;
    float lsq = d0 * d0 + d1 * d1 + d2 * d2 + d3 * d3;
    #pragma unroll
    for (int o = 32; o; o >>= 1) lsq += __shfl_down(lsq, o);
    __syncthreads();
    if (lane == 0) sred[wid] = lsq;
    __syncthreads();
    if (tid == 0) sred[5] = rsqrtf((sred[0] + sred[1] + sred[2] + sred[3]) * (1.f / 1024.f));
    __syncthreads();
    const float r = sred[5];

    float o0 = d0 * r, o1 = d1 * r, o2 = d2 * r, o3 = d3 * r;
    if (outF) {
        float4 o = {o0, o1, o2, o3};
        *(float4*)&outF[off] = o;
    }
    if (outB) {
        ushort4 o = { f2b(o0), f2b(o1), f2b(o2), f2b(o3) };
        *(ushort4*)&outB[off] = o;
    }
}

extern "C" void kernel_launch(void* const* d_in, const int* in_sizes, int n_in,
                              void* d_out, int out_size, void* d_ws, size_t ws_size,
                              hipStream_t stream)
{
    const float* x     = (const float*)d_in[0];
    const int*   pmask = (const int*)  d_in[1];
    const float* Wq    = (const float*)d_in[2];
    const float* bq    = (const float*)d_in[3];
    const float* Wk    = (const float*)d_in[4];
    const float* bk    = (const float*)d_in[5];
    const float* Wv    = (const float*)d_in[6];
    const float* bv    = (const float*)d_in[7];
    const float* Wo    = (const float*)d_in[8];
    const float* bo    = (const float*)d_in[9];
    const float* rel   = (const float*)d_in[10];
    const float* W1    = (const float*)d_in[11];
    const float* b1    = (const float*)d_in[12];
    const float* W2    = (const float*)d_in[13];
    const float* b2    = (const float*)d_in[14];

    const int M = 4096, D = 1024;
    dim3 blk(256);
    dim3 gblk(512);

    // ---- workspace map (identical to round-7/8-proven; peak write 64MB+64KB) ----
    char* ws = (char*)d_ws;
    unsigned short* W1b   = (unsigned short*)(ws);                 // 0-8
    unsigned short* W2b   = (unsigned short*)(ws + ( 8u << 20));   // 8-16
    unsigned short* xb    = (unsigned short*)(ws + (16u << 20));   // 16-24
    unsigned short* Wqkvb = (unsigned short*)(ws + (24u << 20));   // 24-30
    unsigned short* Wob   = (unsigned short*)(ws + (30u << 20));   // 30-32
    unsigned short* qb    = (unsigned short*)(ws + (32u << 20));   // 32-40
    unsigned short* kb    = (unsigned short*)(ws + (40u << 20));   // 40-48
    unsigned short* vb    = (unsigned short*)(ws + (48u << 20));   // 48-56
    unsigned short* vt    = (unsigned short*)(ws + (56u << 20));   // 56-64
    unsigned short* rbias = (unsigned short*)(ws + (64u << 20));   // 64-64.0625
    float*          tmpA    = (float*)(ws + (32u << 20));          // 32-48 (qb/kb dead after attn)
    float*          tmpB    = (float*)(ws + (48u << 20));          // 48-64 (vb/vt dead after attn)
    unsigned short* attoutB = (unsigned short*)(ws + (16u << 20)); // 16-24 (xb dead after qkv)
    unsigned short* ff1     = (unsigned short*)(ws + (32u << 20)); // 32-64 (tmpA/B dead after ln1)
    unsigned short* ff2a    = (unsigned short*)(ws);               // 0-8   (W1b dead after ff1)
    unsigned short* ff2b    = (unsigned short*)(ws + (24u << 20)); // 24-32 (Wqkvb/Wob dead)
    unsigned short* attb    = (unsigned short*)d_out;              // d_out scratch (proven)

    // ---- conversions / tables ----
    cvt_all_kernel<<<16384, blk, 0, stream>>>(x, Wq, Wk, Wv, Wo, W1, W2,
                                              xb, Wqkvb, Wob, W1b, W2b);
    rbias_kernel<<<128, blk, 0, stream>>>(rel, rbias);

    // ---- fused QKV projection: N=3072, routed to qb/kb/vb ----
    mfma_gemm<unsigned short, float, 0, 1><<<dim3(24, 16), gblk, 0, stream>>>(
        xb, D, Wqkvb, D, bq, bk, bv, (const float*)nullptr, qb, kb, vb, D, M, 3072, D);

    vtrans_kernel<<<4096, blk, 0, stream>>>(vb, vt);

    // ---- attention v3: 128-query tiles, bp-major grid, 2 blocks/CU even ----
    attn_mfma_kernel<<<dim3(64, 8), blk, 0, stream>>>(qb, kb, vt, rbias, pmask, attb);

    // ---- Wo projection + residual x, split-K z=2 -> tmpA/tmpB fp32; LN1 -> attoutB ----
    mfma_gemm<float, float, 0, 0><<<dim3(8, 16, 2), gblk, 0, stream>>>(
        attb, D, Wob, D, bo, nullptr, nullptr, x, tmpA, tmpB, nullptr, D, M, D, 512);
    ln_kernel<float><<<4096, blk, 0, stream>>>(tmpA, tmpB, nullptr, attoutB);

    // ---- FFN: ff1 full N=4096; ff2 split-K z=2 (res = attoutB bf16); LN2 sums ----
    mfma_gemm<unsigned short, float, 1, 0><<<dim3(32, 16), gblk, 0, stream>>>(
        attoutB, D, W1b, D, b1, nullptr, nullptr, (const float*)nullptr,
        ff1, nullptr, nullptr, 4096, M, 4096, D);
    mfma_gemm<unsigned short, unsigned short, 0, 0><<<dim3(8, 16, 2), gblk, 0, stream>>>(
        ff1, 4096, W2b, 4096, b2, nullptr, nullptr, attoutB, ff2a, ff2b, nullptr, D, M, D, 2048);
    ln_kernel<unsigned short><<<4096, blk, 0, stream>>>(ff2a, ff2b, (float*)d_out, nullptr);
}

// Round 8
// 383.385 us; speedup vs baseline: 1.0649x; 1.0333x over previous
//
#include <hip/hip_runtime.h>
#include <hip/hip_bf16.h>

typedef __hip_bfloat16 bf16;
typedef __attribute__((ext_vector_type(8))) short s8v;      // 8 bf16 (4 VGPRs) MFMA A/B frag
typedef __attribute__((ext_vector_type(4))) float f32x4;    // MFMA C/D frag

__device__ __forceinline__ float bits2f(unsigned short u) {
    return __uint_as_float(((unsigned)u) << 16);
}
__device__ __forceinline__ unsigned short f2b(float f) {   // fp32 -> bf16 RNE
    union { float f; unsigned u; } x{f};
    return (unsigned short)((x.u + 0x7fff + ((x.u >> 16) & 1)) >> 16);
}
__device__ __forceinline__ float to_f(float x) { return x; }
__device__ __forceinline__ float to_f(unsigned short x) { return bits2f(x); }

__device__ __forceinline__ void load4(const float* p, float* a) {
    float4 t = *(const float4*)p;
    a[0] = t.x; a[1] = t.y; a[2] = t.z; a[3] = t.w;
}
__device__ __forceinline__ void load4(const unsigned short* p, float* a) {
    ushort4 t = *(const ushort4*)p;
    a[0] = bits2f(t.x); a[1] = bits2f(t.y); a[2] = bits2f(t.z); a[3] = bits2f(t.w);
}

// ---------------- fused fp32 -> bf16 convert of x + all weights ----------------
__global__ __launch_bounds__(256)
void cvt_all_kernel(const float* __restrict__ x,
                    const float* __restrict__ Wq, const float* __restrict__ Wk,
                    const float* __restrict__ Wv, const float* __restrict__ Wo,
                    const float* __restrict__ W1, const float* __restrict__ W2,
                    unsigned short* __restrict__ xb, unsigned short* __restrict__ Wqkvb,
                    unsigned short* __restrict__ Wob,
                    unsigned short* __restrict__ W1b, unsigned short* __restrict__ W2b)
{
    int i = blockIdx.x * 256 + threadIdx.x;
    const float* src; unsigned short* dst; int off;
    if (i < (1 << 20))      { src = x;  dst = xb;  off = i; }
    else if (i < (2 << 20)) { src = W1; dst = W1b; off = i - (1 << 20); }
    else if (i < (3 << 20)) { src = W2; dst = W2b; off = i - (2 << 20); }
    else {
        int j = i - (3 << 20);
        int sel = j >> 18;
        off = j & ((1 << 18) - 1);
        src = sel == 0 ? Wq : sel == 1 ? Wk : sel == 2 ? Wv : Wo;
        dst = sel == 3 ? Wob : Wqkvb + ((size_t)sel << 20);
    }
    float4 v = ((const float4*)src)[off];
    ushort4 o = { f2b(v.x), f2b(v.y), f2b(v.z), f2b(v.w) };
    ((ushort4*)dst)[off] = o;
}

// ---------------- per-head relative-position bias by delta (T5 buckets, double math) ----------------
__global__ void rbias_kernel(const float* __restrict__ rel_emb, unsigned short* __restrict__ rbias)
{
    int idx = blockIdx.x * 256 + threadIdx.x;   // 16 * 2048
    if (idx >= 16 * 2048) return;
    int h = idx >> 11, q = idx & 2047;
    int n = q - 1023, ret = 0;                  // n = j - i
    if (n < 0) { ret = 16; n = -n; }
    int b;
    if (n < 8) b = n;
    else {
        double t = log((double)n / 8.0) / log(16.0) * 8.0;
        int v = 8 + (int)t;
        b = v < 15 ? v : 15;
    }
    rbias[idx] = f2b(rel_emb[(ret + b) * 16 + h]);
}

// ============ 128x128 MFMA GEMM, BK=32 dbuf (verified R6) ============
// Used for QKV / Wo / ff2 — the shapes whose grids stay >=2 blocks/CU at 128².
// R7 measured: these shapes regress at 256-tile (1 block/CU kills the
// inter-block overlap that is the only latency hiding in this structure).
template<typename TC, typename TR, int RELU, int QKV>
__global__ __launch_bounds__(256)
void mfma_gemm128(const unsigned short* __restrict__ A, int lda,
                  const unsigned short* __restrict__ W, int ldw,
                  const float* __restrict__ b0, const float* __restrict__ b1,
                  const float* __restrict__ b2,
                  const TR* __restrict__ res,
                  void* __restrict__ C0, void* __restrict__ C1, void* __restrict__ C2,
                  int ldc, int M, int N, int Ksplit)
{
    __shared__ unsigned short sm[4 * 128 * 32];   // 32KB: As[2] + Ws[2], [128][32] each
    const int tid = threadIdx.x;
    const int w = tid >> 6, lane = tid & 63;
    const int quad = lane >> 4, col = lane & 15;

    // XCD-bijective swizzle over the x-y grid (nwg % 8 == 0 for all launches here)
    const int bid = blockIdx.x + gridDim.x * blockIdx.y;
    const int nwg = gridDim.x * gridDim.y;
    const int swz = (bid & 7) * (nwg >> 3) + (bid >> 3);
    const int m0 = (swz / gridDim.x) * 128;
    const int n0 = (swz % gridDim.x) * 128;

    const int wrow = (w & 1) * 64, wcol = (w >> 1) * 64;
    const int kz = blockIdx.z * Ksplit;
    const int NT = Ksplit >> 5;

    int sr0, sq0, sr1, sq1;
    {
        const int i0_ = tid;
        int sp = i0_ & 63, rl = ((sp >> 2) ^ (sp >> 4)) & 1;
        sr0 = ((i0_ >> 6) << 4) | ((sp >> 2) & 0xE) | rl;
        sq0 = (sp & 3) ^ ((((sp >> 3) & 1) << 1) | rl);
        const int i1_ = 256 + tid;
        sp = i1_ & 63; rl = ((sp >> 2) ^ (sp >> 4)) & 1;
        sr1 = ((i1_ >> 6) << 4) | ((sp >> 2) & 0xE) | rl;
        sq1 = (sp & 3) ^ ((((sp >> 3) & 1) << 1) | rl);
    }
    const unsigned off0 = (unsigned)__builtin_amdgcn_readfirstlane((unsigned)((0 * 256 + (tid & 192)) * 16));
    const unsigned off1 = (unsigned)__builtin_amdgcn_readfirstlane((unsigned)((1 * 256 + (tid & 192)) * 16));

#define STAGE32(buf, k0)                                                                     \
    {                                                                                        \
        unsigned short* As_ = sm + (buf) * 4096;                                             \
        unsigned short* Ws_ = sm + 8192 + (buf) * 4096;                                      \
        const unsigned short* ga0 = A + (size_t)(m0 + sr0) * lda + (k0) + sq0 * 8;           \
        __builtin_amdgcn_global_load_lds(                                                    \
            (const __attribute__((address_space(1))) unsigned int*)ga0,                      \
            (__attribute__((address_space(3))) unsigned int*)((char*)As_ + off0), 16, 0, 0); \
        const unsigned short* ga1 = A + (size_t)(m0 + sr1) * lda + (k0) + sq1 * 8;           \
        __builtin_amdgcn_global_load_lds(                                                    \
            (const __attribute__((address_space(1))) unsigned int*)ga1,                      \
            (__attribute__((address_space(3))) unsigned int*)((char*)As_ + off1), 16, 0, 0); \
        const unsigned short* gw0 = W + (size_t)(n0 + sr0) * ldw + (k0) + sq0 * 8;           \
        __builtin_amdgcn_global_load_lds(                                                    \
            (const __attribute__((address_space(1))) unsigned int*)gw0,                      \
            (__attribute__((address_space(3))) unsigned int*)((char*)Ws_ + off0), 16, 0, 0); \
        const unsigned short* gw1 = W + (size_t)(n0 + sr1) * ldw + (k0) + sq1 * 8;           \
        __builtin_amdgcn_global_load_lds(                                                    \
            (const __attribute__((address_space(1))) unsigned int*)gw1,                      \
            (__attribute__((address_space(3))) unsigned int*)((char*)Ws_ + off1), 16, 0, 0); \
    }

    f32x4 acc[4][4] = {};

    STAGE32(0, kz);                      // prologue: tile 0 -> buf 0

    for (int t = 0; t < NT; ++t) {
        __syncthreads();                 // drains buf[cur] staging (issued one phase ago)
        const int cur = t & 1;
        if (t + 1 < NT) STAGE32(cur ^ 1, kz + (t + 1) * 32);   // issue-early (T3)

        const unsigned short* As = sm + cur * 4096;
        const unsigned short* Ws = sm + 8192 + cur * 4096;
        s8v af[4], bfr[4];
        #pragma unroll
        for (int mt = 0; mt < 4; ++mt) {
            int rr = wrow + mt * 16 + col;
            af[mt] = *(const s8v*)(As + ((rr * 32 + ((quad ^ (rr & 3)) << 3)) ^ (((rr >> 2) & 1) << 5)));
        }
        #pragma unroll
        for (int nt = 0; nt < 4; ++nt) {
            int rr = wcol + nt * 16 + col;
            bfr[nt] = *(const s8v*)(Ws + ((rr * 32 + ((quad ^ (rr & 3)) << 3)) ^ (((rr >> 2) & 1) << 5)));
        }
        __builtin_amdgcn_s_setprio(1);
        #pragma unroll
        for (int mt = 0; mt < 4; ++mt)
            #pragma unroll
            for (int nt = 0; nt < 4; ++nt)
                acc[mt][nt] = __builtin_amdgcn_mfma_f32_16x16x32_bf16(af[mt], bfr[nt], acc[mt][nt], 0, 0, 0);
        __builtin_amdgcn_s_setprio(0);
    }
#undef STAGE32

    if (QKV) {
        const int sel = n0 >> 10;
        unsigned short* Cb = (unsigned short*)(sel == 0 ? C0 : sel == 1 ? C1 : C2);
        const float* bs = sel == 0 ? b0 : sel == 1 ? b1 : b2;
        #pragma unroll
        for (int mt = 0; mt < 4; ++mt)
            #pragma unroll
            for (int rg = 0; rg < 4; ++rg) {
                int gm = m0 + wrow + mt * 16 + quad * 4 + rg;
                #pragma unroll
                for (int nt = 0; nt < 4; ++nt) {
                    int gnc = (n0 + wcol + nt * 16 + col) & 1023;
                    Cb[(size_t)gm * 1024 + gnc] = f2b(acc[mt][nt][rg] + bs[gnc]);
                }
            }
    } else {
        void* Cv = blockIdx.z ? C1 : C0;
        const bool z0 = (blockIdx.z == 0);
        #pragma unroll
        for (int mt = 0; mt < 4; ++mt)
            #pragma unroll
            for (int rg = 0; rg < 4; ++rg) {
                int gm = m0 + wrow + mt * 16 + quad * 4 + rg;
                #pragma unroll
                for (int nt = 0; nt < 4; ++nt) {
                    int gn = n0 + wcol + nt * 16 + col;
                    float c = acc[mt][nt][rg];
                    if (z0) {
                        if (b0)  c += b0[gn];
                        if (res) c += to_f(res[(size_t)gm * ldc + gn]);
                    }
                    if (RELU) c = fmaxf(c, 0.f);
                    if (sizeof(TC) == 2) ((unsigned short*)Cv)[(size_t)gm * ldc + gn] = f2b(c);
                    else                 ((float*)Cv)[(size_t)gm * ldc + gn] = c;
                }
            }
    }
}

// ============ 256x128 MFMA GEMM, 8 waves, BK=32 dbuf (verified R7) ============
// Used for ff1 only: (32,16) grid = 512 blocks = 2/CU even — measured faster
// than 128² on this shape (dropped out of the top-5 at R7).
template<typename TC, typename TR, int RELU, int QKV>
__global__ __launch_bounds__(512)
void mfma_gemm256(const unsigned short* __restrict__ A, int lda,
                  const unsigned short* __restrict__ W, int ldw,
                  const float* __restrict__ b0, const float* __restrict__ b1,
                  const float* __restrict__ b2,
                  const TR* __restrict__ res,
                  void* __restrict__ C0, void* __restrict__ C1, void* __restrict__ C2,
                  int ldc, int M, int N, int Ksplit)
{
    __shared__ unsigned short sm[2 * 8192 + 2 * 4096];   // 48KB: A dbuf [2][256][32], W dbuf [2][128][32]
    const int tid = threadIdx.x;
    const int w = tid >> 6, lane = tid & 63;
    const int quad = lane >> 4, col = lane & 15;

    const int bid = blockIdx.x + gridDim.x * blockIdx.y;
    const int xcd = bid & 7, j = bid >> 3;
    const int rh = gridDim.y >> 1, cw = gridDim.x >> 2;
    const int m0 = (((xcd & 1) * rh) + (j % rh)) * 256;
    const int n0 = (((xcd >> 1) * cw) + (j / rh)) * 128;

    const int wrow = (w & 3) * 64, wcol = (w >> 2) * 64;
    const int kz = blockIdx.z * Ksplit;
    const int NT = Ksplit >> 5;

    int sr0, sq0, sr1, sq1, sr2, sq2;
    {
        int idx = tid;
        int sp = idx & 63, rl = ((sp >> 2) ^ (sp >> 4)) & 1;
        sr0 = ((idx >> 6) << 4) | ((sp >> 2) & 0xE) | rl;
        sq0 = (sp & 3) ^ ((((sp >> 3) & 1) << 1) | rl);
        idx = 512 + tid;
        sp = idx & 63; rl = ((sp >> 2) ^ (sp >> 4)) & 1;
        sr1 = ((idx >> 6) << 4) | ((sp >> 2) & 0xE) | rl;
        sq1 = (sp & 3) ^ ((((sp >> 3) & 1) << 1) | rl);
        sr2 = sr0; sq2 = sq0;
    }
    const unsigned offA0 = (unsigned)__builtin_amdgcn_readfirstlane((unsigned)((tid & 448) * 16));
    const unsigned offA1 = (unsigned)__builtin_amdgcn_readfirstlane((unsigned)((512 + (tid & 448)) * 16));
    const unsigned offW0 = offA0;

#define STAGE(buf, k0)                                                                       \
    {                                                                                        \
        unsigned short* As_ = sm + (buf) * 8192;                                             \
        unsigned short* Ws_ = sm + 16384 + (buf) * 4096;                                     \
        const unsigned short* ga0 = A + (size_t)(m0 + sr0) * lda + (k0) + sq0 * 8;           \
        __builtin_amdgcn_global_load_lds(                                                    \
            (const __attribute__((address_space(1))) unsigned int*)ga0,                      \
            (__attribute__((address_space(3))) unsigned int*)((char*)As_ + offA0), 16, 0, 0);\
        const unsigned short* ga1 = A + (size_t)(m0 + sr1) * lda + (k0) + sq1 * 8;           \
        __builtin_amdgcn_global_load_lds(                                                    \
            (const __attribute__((address_space(1))) unsigned int*)ga1,                      \
            (__attribute__((address_space(3))) unsigned int*)((char*)As_ + offA1), 16, 0, 0);\
        const unsigned short* gw0 = W + (size_t)(n0 + sr2) * ldw + (k0) + sq2 * 8;           \
        __builtin_amdgcn_global_load_lds(                                                    \
            (const __attribute__((address_space(1))) unsigned int*)gw0,                      \
            (__attribute__((address_space(3))) unsigned int*)((char*)Ws_ + offW0), 16, 0, 0);\
    }

    f32x4 acc[4][4] = {};

    STAGE(0, kz);

    for (int t = 0; t < NT; ++t) {
        __syncthreads();
        const int cur = t & 1;
        if (t + 1 < NT) STAGE(cur ^ 1, kz + (t + 1) * 32);

        const unsigned short* As = sm + cur * 8192;
        const unsigned short* Ws = sm + 16384 + cur * 4096;
        s8v af[4], bfr[4];
        #pragma unroll
        for (int mt = 0; mt < 4; ++mt) {
            int rr = wrow + mt * 16 + col;
            af[mt] = *(const s8v*)(As + ((rr * 32 + ((quad ^ (rr & 3)) << 3)) ^ (((rr >> 2) & 1) << 5)));
        }
        #pragma unroll
        for (int nt = 0; nt < 4; ++nt) {
            int rr = wcol + nt * 16 + col;
            bfr[nt] = *(const s8v*)(Ws + ((rr * 32 + ((quad ^ (rr & 3)) << 3)) ^ (((rr >> 2) & 1) << 5)));
        }
        __builtin_amdgcn_s_setprio(1);
        #pragma unroll
        for (int mt = 0; mt < 4; ++mt)
            #pragma unroll
            for (int nt = 0; nt < 4; ++nt)
                acc[mt][nt] = __builtin_amdgcn_mfma_f32_16x16x32_bf16(af[mt], bfr[nt], acc[mt][nt], 0, 0, 0);
        __builtin_amdgcn_s_setprio(0);
    }
#undef STAGE

    if (QKV) {
        const int sel = n0 >> 10;
        unsigned short* Cb = (unsigned short*)(sel == 0 ? C0 : sel == 1 ? C1 : C2);
        const float* bs = sel == 0 ? b0 : sel == 1 ? b1 : b2;
        #pragma unroll
        for (int mt = 0; mt < 4; ++mt)
            #pragma unroll
            for (int rg = 0; rg < 4; ++rg) {
                int gm = m0 + wrow + mt * 16 + quad * 4 + rg;
                #pragma unroll
                for (int nt = 0; nt < 4; ++nt) {
                    int gnc = (n0 + wcol + nt * 16 + col) & 1023;
                    Cb[(size_t)gm * 1024 + gnc] = f2b(acc[mt][nt][rg] + bs[gnc]);
                }
            }
    } else {
        void* Cv = blockIdx.z ? C1 : C0;
        const bool z0 = (blockIdx.z == 0);
        #pragma unroll
        for (int mt = 0; mt < 4; ++mt)
            #pragma unroll
            for (int rg = 0; rg < 4; ++rg) {
                int gm = m0 + wrow + mt * 16 + quad * 4 + rg;
                #pragma unroll
                for (int nt = 0; nt < 4; ++nt) {
                    int gn = n0 + wcol + nt * 16 + col;
                    float c = acc[mt][nt][rg];
                    if (z0) {
                        if (b0)  c += b0[gn];
                        if (res) c += to_f(res[(size_t)gm * ldc + gn]);
                    }
                    if (RELU) c = fmaxf(c, 0.f);
                    if (sizeof(TC) == 2) ((unsigned short*)Cv)[(size_t)gm * ldc + gn] = f2b(c);
                    else                 ((float*)Cv)[(size_t)gm * ldc + gn] = c;
                }
            }
    }
}

// ---------------- V transpose: vb bf16 [4096][1024] -> vt bf16 [bp][d][j] ----------------
__global__ __launch_bounds__(256)
void vtrans_kernel(const unsigned short* __restrict__ v, unsigned short* __restrict__ vt)
{
    __shared__ unsigned short t[64][68];
    const int bpmm = blockIdx.x;
    const int bp = bpmm >> 6, mm = bpmm & 63;
    const unsigned short* vr = v + (size_t)(bp * 64 + mm) * 1024;
    const int tid = threadIdx.x;
    #pragma unroll
    for (int it = 0; it < 4; ++it) {
        int c = (tid >> 6) + it * 4;
        int d = tid & 63;
        t[d][c] = vr[c * 64 + d];
    }
    __syncthreads();
    int d = tid >> 2, qq = tid & 3;
    ushort4 o = { t[d][qq * 4 + 0], t[d][qq * 4 + 1], t[d][qq * 4 + 2], t[d][qq * 4 + 3] };
    *(ushort4*)(vt + (size_t)bp * 65536 + (size_t)d * 1024 + mm * 16 + qq * 4) = o;
}

// ---------------- MFMA attention v3 (unchanged, proven) ----------------
__global__ __launch_bounds__(256, 2)
void attn_mfma_kernel(const unsigned short* __restrict__ qb,
                      const unsigned short* __restrict__ kb,
                      const unsigned short* __restrict__ vt,
                      const unsigned short* __restrict__ rbias,
                      const int* __restrict__ pmask,
                      unsigned short* __restrict__ att)
{
    __shared__ unsigned short Qs[128 * 64];
    __shared__ unsigned short KP[128 * 64];
    __shared__ unsigned short Vt[64 * 128];
    __shared__ unsigned short rbs[2048];
    __shared__ unsigned short pmls[1024];

    const int tid = threadIdx.x;
    const int w = tid >> 6, lane = tid & 63;
    const int quad = lane >> 4, col = lane & 15;
    const int bp = blockIdx.x, i0 = blockIdx.y * 128;
    const int h = bp & 15, bb = bp >> 4;
    const size_t base = (size_t)bp << 16;
    const int myrow0 = w * 32, myrow1 = w * 32 + 16;

    {
        const unsigned short* qg = qb + base + (size_t)i0 * 64;
        #pragma unroll
        for (int it = 0; it < 4; ++it) {
            int idx = it * 256 + tid;
            int r = idx >> 3, c = idx & 7;
            s8v d = *(const s8v*)(qg + (size_t)r * 64 + (c ^ (r & 7)) * 8);
            *(s8v*)(Qs + r * 64 + c * 8) = d;
        }
    }
    {
        const unsigned short* rg = rbias + h * 2048;
        #pragma unroll
        for (int it = 0; it < 8; ++it) rbs[it * 256 + tid] = rg[it * 256 + tid];
    }
    #pragma unroll
    for (int it = 0; it < 4; ++it) {
        int j = it * 256 + tid;
        pmls[j] = f2b(__logf((float)pmask[bb * 1024 + j]));
    }

    f32x4 O0[4] = {}, O1[4] = {};
    float lrow0[4] = {0.f, 0.f, 0.f, 0.f};
    float lrow1[4] = {0.f, 0.f, 0.f, 0.f};

    unsigned short* Pw = KP + w * 2048;

    for (int jt = 0; jt < 8; ++jt) {
        const int j0 = jt * 128;
        __syncthreads();
        {
            const unsigned short* kg = kb + base + (size_t)j0 * 64;
            #pragma unroll
            for (int it = 0; it < 4; ++it) {
                int idx = it * 256 + tid;
                int r = idx >> 3, c = idx & 7;
                s8v d = *(const s8v*)(kg + (size_t)r * 64 + (c ^ (r & 7)) * 8);
                *(s8v*)(KP + r * 64 + c * 8) = d;
            }
            const unsigned short* vg = vt + base + j0;
            #pragma unroll
            for (int it = 0; it < 4; ++it) {
                int idx = it * 256 + tid;
                int r = idx >> 4, c = idx & 15;
                s8v d = *(const s8v*)(vg + (size_t)r * 1024 + (c ^ (r & 15)) * 8);
                *(s8v*)(Vt + r * 128 + c * 8) = d;
            }
        }
        __syncthreads();

        f32x4 S0[8] = {}, S1[8] = {};
        #pragma unroll
        for (int ks = 0; ks < 2; ++ks) {
            int ar0 = myrow0 + col, ar1 = myrow1 + col;
            s8v a0 = *(const s8v*)(Qs + ar0 * 64 + (((ks * 4 + quad) ^ (ar0 & 7)) * 8));
            s8v a1 = *(const s8v*)(Qs + ar1 * 64 + (((ks * 4 + quad) ^ (ar1 & 7)) * 8));
            #pragma unroll
            for (int ct = 0; ct < 8; ++ct) {
                int br = ct * 16 + col;
                s8v b = *(const s8v*)(KP + br * 64 + (((ks * 4 + quad) ^ (br & 7)) * 8));
                S0[ct] = __builtin_amdgcn_mfma_f32_16x16x32_bf16(a0, b, S0[ct], 0, 0, 0);
                S1[ct] = __builtin_amdgcn_mfma_f32_16x16x32_bf16(a1, b, S1[ct], 0, 0, 0);
            }
        }

        #pragma unroll
        for (int ct = 0; ct < 8; ++ct) {
            int gj = j0 + ct * 16 + col;
            float pmv = bits2f(pmls[gj]);
            int d0 = gj - (i0 + myrow0 + quad * 4) + 1023;
            int d1 = gj - (i0 + myrow1 + quad * 4) + 1023;
            #pragma unroll
            for (int r = 0; r < 4; ++r) {
                float e0 = __expf(S0[ct][r] + bits2f(rbs[d0 - r]) + pmv);
                float e1 = __expf(S1[ct][r] + bits2f(rbs[d1 - r]) + pmv);
                S0[ct][r] = e0; lrow0[r] += e0;
                S1[ct][r] = e1; lrow1[r] += e1;
            }
        }

        __syncthreads();

        #pragma unroll
        for (int ct = 0; ct < 8; ++ct)
            #pragma unroll
            for (int r = 0; r < 4; ++r) {
                int lr = quad * 4 + r;
                int j = ct * 16 + col;
                Pw[lr * 128 + (((j >> 3) ^ lr) << 3) + (j & 7)] = f2b(S0[ct][r]);
            }
        #pragma unroll
        for (int kt = 0; kt < 4; ++kt) {
            int pr = col;
            s8v a = *(const s8v*)(Pw + pr * 128 + (((kt * 4 + quad) ^ pr) * 8));
            #pragma unroll
            for (int nt = 0; nt < 4; ++nt) {
                int vr = nt * 16 + col;
                s8v b = *(const s8v*)(Vt + vr * 128 + (((kt * 4 + quad) ^ (vr & 15)) * 8));
                O0[nt] = __builtin_amdgcn_mfma_f32_16x16x32_bf16(a, b, O0[nt], 0, 0, 0);
            }
        }

        #pragma unroll
        for (int ct = 0; ct < 8; ++ct)
            #pragma unroll
            for (int r = 0; r < 4; ++r) {
                int lr = quad * 4 + r;
                int j = ct * 16 + col;
                Pw[lr * 128 + (((j >> 3) ^ lr) << 3) + (j & 7)] = f2b(S1[ct][r]);
            }
        #pragma unroll
        for (int kt = 0; kt < 4; ++kt) {
            int pr = col;
            s8v a = *(const s8v*)(Pw + pr * 128 + (((kt * 4 + quad) ^ pr) * 8));
            #pragma unroll
            for (int nt = 0; nt < 4; ++nt) {
                int vr = nt * 16 + col;
                s8v b = *(const s8v*)(Vt + vr * 128 + (((kt * 4 + quad) ^ (vr & 15)) * 8));
                O1[nt] = __builtin_amdgcn_mfma_f32_16x16x32_bf16(a, b, O1[nt], 0, 0, 0);
            }
        }
    }

    #pragma unroll
    for (int off = 1; off < 16; off <<= 1)
        #pragma unroll
        for (int r = 0; r < 4; ++r) {
            lrow0[r] += __shfl_xor(lrow0[r], off);
            lrow1[r] += __shfl_xor(lrow1[r], off);
        }
    #pragma unroll
    for (int r = 0; r < 4; ++r) {
        lrow0[r] = 1.f / lrow0[r];
        lrow1[r] = 1.f / lrow1[r];
    }

    unsigned short* ag0 = att + base + (size_t)(i0 + myrow0) * 64;
    unsigned short* ag1 = att + base + (size_t)(i0 + myrow1) * 64;
    #pragma unroll
    for (int nt = 0; nt < 4; ++nt)
        #pragma unroll
        for (int r = 0; r < 4; ++r) {
            ag0[(size_t)(quad * 4 + r) * 64 + nt * 16 + col] = f2b(O0[nt][r] * lrow0[r]);
            ag1[(size_t)(quad * 4 + r) * 64 + nt * 16 + col] = f2b(O1[nt][r] * lrow1[r]);
        }
}

// ---------------- layernorm over rows of 1024: in1+in2 -> (outF fp32, outB bf16) ----------------
template<typename TIN>
__global__ __launch_bounds__(256)
void ln_kernel(const TIN* __restrict__ in1, const TIN* __restrict__ in2,
               float* __restrict__ outF, unsigned short* __restrict__ outB)
{
    __shared__ float sred[8];
    const int row = blockIdx.x;
    const int tid = threadIdx.x;
    const size_t off = (size_t)row * 1024 + tid * 4;
    float a[4];
    load4(in1 + off, a);
    if (in2) {
        float b[4];
        load4(in2 + off, b);
        #pragma unroll
        for (int i = 0; i < 4; ++i) a[i] += b[i];
    }

    float lsum = a[0] + a[1] + a[2] + a[3];
    #pragma unroll
    for (int o = 32; o; o >>= 1) lsum += __shfl_down(lsum, o);
    const int lane = tid & 63, wid = tid >> 6;
    if (lane == 0) sred[wid] = lsum;
    __syncthreads();
    if (tid == 0) sred[4] = (sred[0] + sred[1] + sred[2] + sred[3]) * (1.f / 1024.f);
    __syncthreads();
    const float mean = sred[4];

    float d0 = a[0] - mean, d1 = a[1] - mean, d2 = a[2] - mean, d3 = a[3] - mean;
    float lsq = d0 * d0 + d1 * d1 + d2 * d2 + d3 * d3;
    #pragma unroll
    for (int o = 32; o; o >>= 1) lsq += __shfl_down(lsq, o);
    __syncthreads();
    if (lane == 0) sred[wid] = lsq;
    __syncthreads();
    if (tid == 0) sred[5] = rsqrtf((sred[0] + sred[1] + sred[2] + sred[3]) * (1.f / 1024.f));
    __syncthreads();
    const float r = sred[5];

    float o0 = d0 * r, o1 = d1 * r, o2 = d2 * r, o3 = d3 * r;
    if (outF) {
        float4 o = {o0, o1, o2, o3};
        *(float4*)&outF[off] = o;
    }
    if (outB) {
        ushort4 o = { f2b(o0), f2b(o1), f2b(o2), f2b(o3) };
        *(ushort4*)&outB[off] = o;
    }
}

extern "C" void kernel_launch(void* const* d_in, const int* in_sizes, int n_in,
                              void* d_out, int out_size, void* d_ws, size_t ws_size,
                              hipStream_t stream)
{
    const float* x     = (const float*)d_in[0];
    const int*   pmask = (const int*)  d_in[1];
    const float* Wq    = (const float*)d_in[2];
    const float* bq    = (const float*)d_in[3];
    const float* Wk    = (const float*)d_in[4];
    const float* bk    = (const float*)d_in[5];
    const float* Wv    = (const float*)d_in[6];
    const float* bv    = (const float*)d_in[7];
    const float* Wo    = (const float*)d_in[8];
    const float* bo    = (const float*)d_in[9];
    const float* rel   = (const float*)d_in[10];
    const float* W1    = (const float*)d_in[11];
    const float* b1    = (const float*)d_in[12];
    const float* W2    = (const float*)d_in[13];
    const float* b2    = (const float*)d_in[14];

    const int M = 4096, D = 1024;
    dim3 blk(256);
    dim3 gblk(512);

    // ---- workspace map (identical to round-7/8-proven; peak write 64MB+64KB) ----
    char* ws = (char*)d_ws;
    unsigned short* W1b   = (unsigned short*)(ws);                 // 0-8
    unsigned short* W2b   = (unsigned short*)(ws + ( 8u << 20));   // 8-16
    unsigned short* xb    = (unsigned short*)(ws + (16u << 20));   // 16-24
    unsigned short* Wqkvb = (unsigned short*)(ws + (24u << 20));   // 24-30
    unsigned short* Wob   = (unsigned short*)(ws + (30u << 20));   // 30-32
    unsigned short* qb    = (unsigned short*)(ws + (32u << 20));   // 32-40
    unsigned short* kb    = (unsigned short*)(ws + (40u << 20));   // 40-48
    unsigned short* vb    = (unsigned short*)(ws + (48u << 20));   // 48-56
    unsigned short* vt    = (unsigned short*)(ws + (56u << 20));   // 56-64
    unsigned short* rbias = (unsigned short*)(ws + (64u << 20));   // 64-64.0625
    float*          tmpA    = (float*)(ws + (32u << 20));          // 32-48 (qb/kb dead after attn)
    float*          tmpB    = (float*)(ws + (48u << 20));          // 48-64 (vb/vt dead after attn)
    unsigned short* attoutB = (unsigned short*)(ws + (16u << 20)); // 16-24 (xb dead after qkv)
    unsigned short* ff1     = (unsigned short*)(ws + (32u << 20)); // 32-64 (tmpA/B dead after ln1)
    unsigned short* ff2a    = (unsigned short*)(ws);               // 0-8   (W1b dead after ff1)
    unsigned short* ff2b    = (unsigned short*)(ws + (24u << 20)); // 24-32 (Wqkvb/Wob dead)
    unsigned short* attb    = (unsigned short*)d_out;              // d_out scratch (proven)

    // ---- conversions / tables ----
    cvt_all_kernel<<<16384, blk, 0, stream>>>(x, Wq, Wk, Wv, Wo, W1, W2,
                                              xb, Wqkvb, Wob, W1b, W2b);
    rbias_kernel<<<128, blk, 0, stream>>>(rel, rbias);

    // ---- fused QKV projection: 128² kernel (768 blocks = 3/CU) ----
    mfma_gemm128<unsigned short, float, 0, 1><<<dim3(24, 32), blk, 0, stream>>>(
        xb, D, Wqkvb, D, bq, bk, bv, (const float*)nullptr, qb, kb, vb, D, M, 3072, D);

    vtrans_kernel<<<4096, blk, 0, stream>>>(vb, vt);

    // ---- attention v3: 128-query tiles, bp-major grid, 2 blocks/CU even ----
    attn_mfma_kernel<<<dim3(64, 8), blk, 0, stream>>>(qb, kb, vt, rbias, pmask, attb);

    // ---- Wo projection + residual x: 128² split-K z=2 (512 blocks = 2/CU); LN1 ----
    mfma_gemm128<float, float, 0, 0><<<dim3(8, 32, 2), blk, 0, stream>>>(
        attb, D, Wob, D, bo, nullptr, nullptr, x, tmpA, tmpB, nullptr, D, M, D, 512);
    ln_kernel<float><<<4096, blk, 0, stream>>>(tmpA, tmpB, nullptr, attoutB);

    // ---- FFN: ff1 256-tile (512 blocks = 2/CU even); ff2 128² split-K z=2; LN2 ----
    mfma_gemm256<unsigned short, float, 1, 0><<<dim3(32, 16), gblk, 0, stream>>>(
        attoutB, D, W1b, D, b1, nullptr, nullptr, (const float*)nullptr,
        ff1, nullptr, nullptr, 4096, M, 4096, D);
    mfma_gemm128<unsigned short, unsigned short, 0, 0><<<dim3(8, 32, 2), blk, 0, stream>>>(
        ff1, 4096, W2b, 4096, b2, nullptr, nullptr, attoutB, ff2a, ff2b, nullptr, D, M, D, 2048);
    ln_kernel<unsigned short><<<4096, blk, 0, stream>>>(ff2a, ff2b, (float*)d_out, nullptr);
}

// Round 10
// 378.228 us; speedup vs baseline: 1.0795x; 1.0136x over previous
//
#include <hip/hip_runtime.h>
#include <hip/hip_bf16.h>

typedef __hip_bfloat16 bf16;
typedef __attribute__((ext_vector_type(8))) short s8v;      // 8 bf16 (4 VGPRs) MFMA A/B frag
typedef __attribute__((ext_vector_type(4))) float f32x4;    // MFMA C/D frag

__device__ __forceinline__ float bits2f(unsigned short u) {
    return __uint_as_float(((unsigned)u) << 16);
}
__device__ __forceinline__ unsigned short f2b(float f) {   // fp32 -> bf16 RNE
    union { float f; unsigned u; } x{f};
    return (unsigned short)((x.u + 0x7fff + ((x.u >> 16) & 1)) >> 16);
}
__device__ __forceinline__ float to_f(float x) { return x; }
__device__ __forceinline__ float to_f(unsigned short x) { return bits2f(x); }

__device__ __forceinline__ void load4(const float* p, float* a) {
    float4 t = *(const float4*)p;
    a[0] = t.x; a[1] = t.y; a[2] = t.z; a[3] = t.w;
}
__device__ __forceinline__ void load4(const unsigned short* p, float* a) {
    ushort4 t = *(const ushort4*)p;
    a[0] = bits2f(t.x); a[1] = bits2f(t.y); a[2] = bits2f(t.z); a[3] = bits2f(t.w);
}

// ---------------- fused fp32 -> bf16 convert of x + all weights ----------------
__global__ __launch_bounds__(256)
void cvt_all_kernel(const float* __restrict__ x,
                    const float* __restrict__ Wq, const float* __restrict__ Wk,
                    const float* __restrict__ Wv, const float* __restrict__ Wo,
                    const float* __restrict__ W1, const float* __restrict__ W2,
                    unsigned short* __restrict__ xb, unsigned short* __restrict__ Wqkvb,
                    unsigned short* __restrict__ Wob,
                    unsigned short* __restrict__ W1b, unsigned short* __restrict__ W2b)
{
    int i = blockIdx.x * 256 + threadIdx.x;
    const float* src; unsigned short* dst; int off;
    if (i < (1 << 20))      { src = x;  dst = xb;  off = i; }
    else if (i < (2 << 20)) { src = W1; dst = W1b; off = i - (1 << 20); }
    else if (i < (3 << 20)) { src = W2; dst = W2b; off = i - (2 << 20); }
    else {
        int j = i - (3 << 20);
        int sel = j >> 18;
        off = j & ((1 << 18) - 1);
        src = sel == 0 ? Wq : sel == 1 ? Wk : sel == 2 ? Wv : Wo;
        dst = sel == 3 ? Wob : Wqkvb + ((size_t)sel << 20);
    }
    float4 v = ((const float4*)src)[off];
    ushort4 o = { f2b(v.x), f2b(v.y), f2b(v.z), f2b(v.w) };
    ((ushort4*)dst)[off] = o;
}

// ---------------- per-head relative-position bias by delta (T5 buckets, double math) ----------------
__global__ void rbias_kernel(const float* __restrict__ rel_emb, unsigned short* __restrict__ rbias)
{
    int idx = blockIdx.x * 256 + threadIdx.x;   // 16 * 2048
    if (idx >= 16 * 2048) return;
    int h = idx >> 11, q = idx & 2047;
    int n = q - 1023, ret = 0;                  // n = j - i
    if (n < 0) { ret = 16; n = -n; }
    int b;
    if (n < 8) b = n;
    else {
        double t = log((double)n / 8.0) / log(16.0) * 8.0;
        int v = 8 + (int)t;
        b = v < 15 ? v : 15;
    }
    rbias[idx] = f2b(rel_emb[(ret + b) * 16 + h]);
}

// ============ 128x128 MFMA GEMM, BK=32 dbuf (verified R6/R8) — QKV ============
template<typename TC, typename TR, int RELU, int QKV>
__global__ __launch_bounds__(256)
void mfma_gemm128(const unsigned short* __restrict__ A, int lda,
                  const unsigned short* __restrict__ W, int ldw,
                  const float* __restrict__ b0, const float* __restrict__ b1,
                  const float* __restrict__ b2,
                  const TR* __restrict__ res,
                  void* __restrict__ C0, void* __restrict__ C1, void* __restrict__ C2,
                  int ldc, int M, int N, int Ksplit)
{
    __shared__ unsigned short sm[4 * 128 * 32];   // 32KB: As[2] + Ws[2], [128][32] each
    const int tid = threadIdx.x;
    const int w = tid >> 6, lane = tid & 63;
    const int quad = lane >> 4, col = lane & 15;

    const int bid = blockIdx.x + gridDim.x * blockIdx.y;
    const int nwg = gridDim.x * gridDim.y;
    const int swz = (bid & 7) * (nwg >> 3) + (bid >> 3);
    const int m0 = (swz / gridDim.x) * 128;
    const int n0 = (swz % gridDim.x) * 128;

    const int wrow = (w & 1) * 64, wcol = (w >> 1) * 64;
    const int kz = blockIdx.z * Ksplit;
    const int NT = Ksplit >> 5;

    int sr0, sq0, sr1, sq1;
    {
        const int i0_ = tid;
        int sp = i0_ & 63, rl = ((sp >> 2) ^ (sp >> 4)) & 1;
        sr0 = ((i0_ >> 6) << 4) | ((sp >> 2) & 0xE) | rl;
        sq0 = (sp & 3) ^ ((((sp >> 3) & 1) << 1) | rl);
        const int i1_ = 256 + tid;
        sp = i1_ & 63; rl = ((sp >> 2) ^ (sp >> 4)) & 1;
        sr1 = ((i1_ >> 6) << 4) | ((sp >> 2) & 0xE) | rl;
        sq1 = (sp & 3) ^ ((((sp >> 3) & 1) << 1) | rl);
    }
    const unsigned off0 = (unsigned)__builtin_amdgcn_readfirstlane((unsigned)((0 * 256 + (tid & 192)) * 16));
    const unsigned off1 = (unsigned)__builtin_amdgcn_readfirstlane((unsigned)((1 * 256 + (tid & 192)) * 16));

#define STAGE32(buf, k0)                                                                     \
    {                                                                                        \
        unsigned short* As_ = sm + (buf) * 4096;                                             \
        unsigned short* Ws_ = sm + 8192 + (buf) * 4096;                                      \
        const unsigned short* ga0 = A + (size_t)(m0 + sr0) * lda + (k0) + sq0 * 8;           \
        __builtin_amdgcn_global_load_lds(                                                    \
            (const __attribute__((address_space(1))) unsigned int*)ga0,                      \
            (__attribute__((address_space(3))) unsigned int*)((char*)As_ + off0), 16, 0, 0); \
        const unsigned short* ga1 = A + (size_t)(m0 + sr1) * lda + (k0) + sq1 * 8;           \
        __builtin_amdgcn_global_load_lds(                                                    \
            (const __attribute__((address_space(1))) unsigned int*)ga1,                      \
            (__attribute__((address_space(3))) unsigned int*)((char*)As_ + off1), 16, 0, 0); \
        const unsigned short* gw0 = W + (size_t)(n0 + sr0) * ldw + (k0) + sq0 * 8;           \
        __builtin_amdgcn_global_load_lds(                                                    \
            (const __attribute__((address_space(1))) unsigned int*)gw0,                      \
            (__attribute__((address_space(3))) unsigned int*)((char*)Ws_ + off0), 16, 0, 0); \
        const unsigned short* gw1 = W + (size_t)(n0 + sr1) * ldw + (k0) + sq1 * 8;           \
        __builtin_amdgcn_global_load_lds(                                                    \
            (const __attribute__((address_space(1))) unsigned int*)gw1,                      \
            (__attribute__((address_space(3))) unsigned int*)((char*)Ws_ + off1), 16, 0, 0); \
    }

    f32x4 acc[4][4] = {};

    STAGE32(0, kz);

    for (int t = 0; t < NT; ++t) {
        __syncthreads();
        const int cur = t & 1;
        if (t + 1 < NT) STAGE32(cur ^ 1, kz + (t + 1) * 32);

        const unsigned short* As = sm + cur * 4096;
        const unsigned short* Ws = sm + 8192 + cur * 4096;
        s8v af[4], bfr[4];
        #pragma unroll
        for (int mt = 0; mt < 4; ++mt) {
            int rr = wrow + mt * 16 + col;
            af[mt] = *(const s8v*)(As + ((rr * 32 + ((quad ^ (rr & 3)) << 3)) ^ (((rr >> 2) & 1) << 5)));
        }
        #pragma unroll
        for (int nt = 0; nt < 4; ++nt) {
            int rr = wcol + nt * 16 + col;
            bfr[nt] = *(const s8v*)(Ws + ((rr * 32 + ((quad ^ (rr & 3)) << 3)) ^ (((rr >> 2) & 1) << 5)));
        }
        __builtin_amdgcn_s_setprio(1);
        #pragma unroll
        for (int mt = 0; mt < 4; ++mt)
            #pragma unroll
            for (int nt = 0; nt < 4; ++nt)
                acc[mt][nt] = __builtin_amdgcn_mfma_f32_16x16x32_bf16(af[mt], bfr[nt], acc[mt][nt], 0, 0, 0);
        __builtin_amdgcn_s_setprio(0);
    }
#undef STAGE32

    if (QKV) {
        const int sel = n0 >> 10;
        unsigned short* Cb = (unsigned short*)(sel == 0 ? C0 : sel == 1 ? C1 : C2);
        const float* bs = sel == 0 ? b0 : sel == 1 ? b1 : b2;
        #pragma unroll
        for (int mt = 0; mt < 4; ++mt)
            #pragma unroll
            for (int rg = 0; rg < 4; ++rg) {
                int gm = m0 + wrow + mt * 16 + quad * 4 + rg;
                #pragma unroll
                for (int nt = 0; nt < 4; ++nt) {
                    int gnc = (n0 + wcol + nt * 16 + col) & 1023;
                    Cb[(size_t)gm * 1024 + gnc] = f2b(acc[mt][nt][rg] + bs[gnc]);
                }
            }
    } else {
        void* Cv = blockIdx.z ? C1 : C0;
        const bool z0 = (blockIdx.z == 0);
        #pragma unroll
        for (int mt = 0; mt < 4; ++mt)
            #pragma unroll
            for (int rg = 0; rg < 4; ++rg) {
                int gm = m0 + wrow + mt * 16 + quad * 4 + rg;
                #pragma unroll
                for (int nt = 0; nt < 4; ++nt) {
                    int gn = n0 + wcol + nt * 16 + col;
                    float c = acc[mt][nt][rg];
                    if (z0) {
                        if (b0)  c += b0[gn];
                        if (res) c += to_f(res[(size_t)gm * ldc + gn]);
                    }
                    if (RELU) c = fmaxf(c, 0.f);
                    if (sizeof(TC) == 2) ((unsigned short*)Cv)[(size_t)gm * ldc + gn] = f2b(c);
                    else                 ((float*)Cv)[(size_t)gm * ldc + gn] = c;
                }
            }
    }
}

// ============ 128x64 MFMA GEMM, BK=32 dbuf — Wo / ff2 (4 blocks/CU) ============
// R9 bug fixed: A's second staging issue writes slots 256..511 → dest offset
// (256 + (tid&192))*16, NOT (512 + ...)*16 (that constant belongs to the
// 512-thread 256-tile kernel and overflowed the A buffer into W/dbuf regions).
template<typename TC, typename TR, int RELU>
__global__ __launch_bounds__(256)
void mfma_gemm64n(const unsigned short* __restrict__ A, int lda,
                  const unsigned short* __restrict__ W, int ldw,
                  const float* __restrict__ b0,
                  const TR* __restrict__ res,
                  void* __restrict__ C0, void* __restrict__ C1,
                  int ldc, int M, int N, int Ksplit)
{
    __shared__ unsigned short sm[2 * 4096 + 2 * 2048];   // 24KB: As[2][128][32], Ws[2][64][32]
    const int tid = threadIdx.x;
    const int w = tid >> 6, lane = tid & 63;
    const int quad = lane >> 4, col = lane & 15;

    const int bid = blockIdx.x + gridDim.x * blockIdx.y;
    const int nwg = gridDim.x * gridDim.y;
    const int swz = (bid & 7) * (nwg >> 3) + (bid >> 3);
    const int m0 = (swz / gridDim.x) * 128;
    const int n0 = (swz % gridDim.x) * 64;

    const int wrow = (w & 1) * 64, wcol = (w >> 1) * 32;
    const int kz = blockIdx.z * Ksplit;
    const int NT = Ksplit >> 5;

    int sr0, sq0, sr1, sq1;
    {
        const int i0_ = tid;
        int sp = i0_ & 63, rl = ((sp >> 2) ^ (sp >> 4)) & 1;
        sr0 = ((i0_ >> 6) << 4) | ((sp >> 2) & 0xE) | rl;
        sq0 = (sp & 3) ^ ((((sp >> 3) & 1) << 1) | rl);
        const int i1_ = 256 + tid;
        sp = i1_ & 63; rl = ((sp >> 2) ^ (sp >> 4)) & 1;
        sr1 = ((i1_ >> 6) << 4) | ((sp >> 2) & 0xE) | rl;
        sq1 = (sp & 3) ^ ((((sp >> 3) & 1) << 1) | rl);
    }
    const unsigned off0 = (unsigned)__builtin_amdgcn_readfirstlane((unsigned)((tid & 192) * 16));
    const unsigned off1 = (unsigned)__builtin_amdgcn_readfirstlane((unsigned)((256 + (tid & 192)) * 16));

#define STAGE64N(buf, k0)                                                                    \
    {                                                                                        \
        unsigned short* As_ = sm + (buf) * 4096;                                             \
        unsigned short* Ws_ = sm + 8192 + (buf) * 2048;                                      \
        const unsigned short* ga0 = A + (size_t)(m0 + sr0) * lda + (k0) + sq0 * 8;           \
        __builtin_amdgcn_global_load_lds(                                                    \
            (const __attribute__((address_space(1))) unsigned int*)ga0,                      \
            (__attribute__((address_space(3))) unsigned int*)((char*)As_ + off0), 16, 0, 0); \
        const unsigned short* ga1 = A + (size_t)(m0 + sr1) * lda + (k0) + sq1 * 8;           \
        __builtin_amdgcn_global_load_lds(                                                    \
            (const __attribute__((address_space(1))) unsigned int*)ga1,                      \
            (__attribute__((address_space(3))) unsigned int*)((char*)As_ + off1), 16, 0, 0); \
        const unsigned short* gw0 = W + (size_t)(n0 + sr0) * ldw + (k0) + sq0 * 8;           \
        __builtin_amdgcn_global_load_lds(                                                    \
            (const __attribute__((address_space(1))) unsigned int*)gw0,                      \
            (__attribute__((address_space(3))) unsigned int*)((char*)Ws_ + off0), 16, 0, 0); \
    }

    f32x4 acc[4][2] = {};

    STAGE64N(0, kz);

    for (int t = 0; t < NT; ++t) {
        __syncthreads();
        const int cur = t & 1;
        if (t + 1 < NT) STAGE64N(cur ^ 1, kz + (t + 1) * 32);

        const unsigned short* As = sm + cur * 4096;
        const unsigned short* Ws = sm + 8192 + cur * 2048;
        s8v af[4], bfr[2];
        #pragma unroll
        for (int mt = 0; mt < 4; ++mt) {
            int rr = wrow + mt * 16 + col;
            af[mt] = *(const s8v*)(As + ((rr * 32 + ((quad ^ (rr & 3)) << 3)) ^ (((rr >> 2) & 1) << 5)));
        }
        #pragma unroll
        for (int nt = 0; nt < 2; ++nt) {
            int rr = wcol + nt * 16 + col;
            bfr[nt] = *(const s8v*)(Ws + ((rr * 32 + ((quad ^ (rr & 3)) << 3)) ^ (((rr >> 2) & 1) << 5)));
        }
        __builtin_amdgcn_s_setprio(1);
        #pragma unroll
        for (int mt = 0; mt < 4; ++mt)
            #pragma unroll
            for (int nt = 0; nt < 2; ++nt)
                acc[mt][nt] = __builtin_amdgcn_mfma_f32_16x16x32_bf16(af[mt], bfr[nt], acc[mt][nt], 0, 0, 0);
        __builtin_amdgcn_s_setprio(0);
    }
#undef STAGE64N

    void* Cv = blockIdx.z ? C1 : C0;
    const bool z0 = (blockIdx.z == 0);
    #pragma unroll
    for (int mt = 0; mt < 4; ++mt)
        #pragma unroll
        for (int rg = 0; rg < 4; ++rg) {
            int gm = m0 + wrow + mt * 16 + quad * 4 + rg;
            #pragma unroll
            for (int nt = 0; nt < 2; ++nt) {
                int gn = n0 + wcol + nt * 16 + col;
                float c = acc[mt][nt][rg];
                if (z0) {
                    if (b0)  c += b0[gn];
                    if (res) c += to_f(res[(size_t)gm * ldc + gn]);
                }
                if (RELU) c = fmaxf(c, 0.f);
                if (sizeof(TC) == 2) ((unsigned short*)Cv)[(size_t)gm * ldc + gn] = f2b(c);
                else                 ((float*)Cv)[(size_t)gm * ldc + gn] = c;
            }
        }
}

// ============ 256x128 MFMA GEMM, 8 waves, BK=32 dbuf (verified R7) — ff1 ============
template<typename TC, typename TR, int RELU, int QKV>
__global__ __launch_bounds__(512)
void mfma_gemm256(const unsigned short* __restrict__ A, int lda,
                  const unsigned short* __restrict__ W, int ldw,
                  const float* __restrict__ b0, const float* __restrict__ b1,
                  const float* __restrict__ b2,
                  const TR* __restrict__ res,
                  void* __restrict__ C0, void* __restrict__ C1, void* __restrict__ C2,
                  int ldc, int M, int N, int Ksplit)
{
    __shared__ unsigned short sm[2 * 8192 + 2 * 4096];   // 48KB: A dbuf [2][256][32], W dbuf [2][128][32]
    const int tid = threadIdx.x;
    const int w = tid >> 6, lane = tid & 63;
    const int quad = lane >> 4, col = lane & 15;

    const int bid = blockIdx.x + gridDim.x * blockIdx.y;
    const int xcd = bid & 7, j = bid >> 3;
    const int rh = gridDim.y >> 1, cw = gridDim.x >> 2;
    const int m0 = (((xcd & 1) * rh) + (j % rh)) * 256;
    const int n0 = (((xcd >> 1) * cw) + (j / rh)) * 128;

    const int wrow = (w & 3) * 64, wcol = (w >> 2) * 64;
    const int kz = blockIdx.z * Ksplit;
    const int NT = Ksplit >> 5;

    int sr0, sq0, sr1, sq1, sr2, sq2;
    {
        int idx = tid;
        int sp = idx & 63, rl = ((sp >> 2) ^ (sp >> 4)) & 1;
        sr0 = ((idx >> 6) << 4) | ((sp >> 2) & 0xE) | rl;
        sq0 = (sp & 3) ^ ((((sp >> 3) & 1) << 1) | rl);
        idx = 512 + tid;
        sp = idx & 63; rl = ((sp >> 2) ^ (sp >> 4)) & 1;
        sr1 = ((idx >> 6) << 4) | ((sp >> 2) & 0xE) | rl;
        sq1 = (sp & 3) ^ ((((sp >> 3) & 1) << 1) | rl);
        sr2 = sr0; sq2 = sq0;
    }
    const unsigned offA0 = (unsigned)__builtin_amdgcn_readfirstlane((unsigned)((tid & 448) * 16));
    const unsigned offA1 = (unsigned)__builtin_amdgcn_readfirstlane((unsigned)((512 + (tid & 448)) * 16));
    const unsigned offW0 = offA0;

#define STAGE(buf, k0)                                                                       \
    {                                                                                        \
        unsigned short* As_ = sm + (buf) * 8192;                                             \
        unsigned short* Ws_ = sm + 16384 + (buf) * 4096;                                     \
        const unsigned short* ga0 = A + (size_t)(m0 + sr0) * lda + (k0) + sq0 * 8;           \
        __builtin_amdgcn_global_load_lds(                                                    \
            (const __attribute__((address_space(1))) unsigned int*)ga0,                      \
            (__attribute__((address_space(3))) unsigned int*)((char*)As_ + offA0), 16, 0, 0);\
        const unsigned short* ga1 = A + (size_t)(m0 + sr1) * lda + (k0) + sq1 * 8;           \
        __builtin_amdgcn_global_load_lds(                                                    \
            (const __attribute__((address_space(1))) unsigned int*)ga1,                      \
            (__attribute__((address_space(3))) unsigned int*)((char*)As_ + offA1), 16, 0, 0);\
        const unsigned short* gw0 = W + (size_t)(n0 + sr2) * ldw + (k0) + sq2 * 8;           \
        __builtin_amdgcn_global_load_lds(                                                    \
            (const __attribute__((address_space(1))) unsigned int*)gw0,                      \
            (__attribute__((address_space(3))) unsigned int*)((char*)Ws_ + offW0), 16, 0, 0);\
    }

    f32x4 acc[4][4] = {};

    STAGE(0, kz);

    for (int t = 0; t < NT; ++t) {
        __syncthreads();
        const int cur = t & 1;
        if (t + 1 < NT) STAGE(cur ^ 1, kz + (t + 1) * 32);

        const unsigned short* As = sm + cur * 8192;
        const unsigned short* Ws = sm + 16384 + cur * 4096;
        s8v af[4], bfr[4];
        #pragma unroll
        for (int mt = 0; mt < 4; ++mt) {
            int rr = wrow + mt * 16 + col;
            af[mt] = *(const s8v*)(As + ((rr * 32 + ((quad ^ (rr & 3)) << 3)) ^ (((rr >> 2) & 1) << 5)));
        }
        #pragma unroll
        for (int nt = 0; nt < 4; ++nt) {
            int rr = wcol + nt * 16 + col;
            bfr[nt] = *(const s8v*)(Ws + ((rr * 32 + ((quad ^ (rr & 3)) << 3)) ^ (((rr >> 2) & 1) << 5)));
        }
        __builtin_amdgcn_s_setprio(1);
        #pragma unroll
        for (int mt = 0; mt < 4; ++mt)
            #pragma unroll
            for (int nt = 0; nt < 4; ++nt)
                acc[mt][nt] = __builtin_amdgcn_mfma_f32_16x16x32_bf16(af[mt], bfr[nt], acc[mt][nt], 0, 0, 0);
        __builtin_amdgcn_s_setprio(0);
    }
#undef STAGE

    if (QKV) {
        const int sel = n0 >> 10;
        unsigned short* Cb = (unsigned short*)(sel == 0 ? C0 : sel == 1 ? C1 : C2);
        const float* bs = sel == 0 ? b0 : sel == 1 ? b1 : b2;
        #pragma unroll
        for (int mt = 0; mt < 4; ++mt)
            #pragma unroll
            for (int rg = 0; rg < 4; ++rg) {
                int gm = m0 + wrow + mt * 16 + quad * 4 + rg;
                #pragma unroll
                for (int nt = 0; nt < 4; ++nt) {
                    int gnc = (n0 + wcol + nt * 16 + col) & 1023;
                    Cb[(size_t)gm * 1024 + gnc] = f2b(acc[mt][nt][rg] + bs[gnc]);
                }
            }
    } else {
        void* Cv = blockIdx.z ? C1 : C0;
        const bool z0 = (blockIdx.z == 0);
        #pragma unroll
        for (int mt = 0; mt < 4; ++mt)
            #pragma unroll
            for (int rg = 0; rg < 4; ++rg) {
                int gm = m0 + wrow + mt * 16 + quad * 4 + rg;
                #pragma unroll
                for (int nt = 0; nt < 4; ++nt) {
                    int gn = n0 + wcol + nt * 16 + col;
                    float c = acc[mt][nt][rg];
                    if (z0) {
                        if (b0)  c += b0[gn];
                        if (res) c += to_f(res[(size_t)gm * ldc + gn]);
                    }
                    if (RELU) c = fmaxf(c, 0.f);
                    if (sizeof(TC) == 2) ((unsigned short*)Cv)[(size_t)gm * ldc + gn] = f2b(c);
                    else                 ((float*)Cv)[(size_t)gm * ldc + gn] = c;
                }
            }
    }
}

// ---------------- V transpose: vb bf16 [4096][1024] -> vt bf16 [bp][d][j] ----------------
__global__ __launch_bounds__(256)
void vtrans_kernel(const unsigned short* __restrict__ v, unsigned short* __restrict__ vt)
{
    __shared__ unsigned short t[64][68];
    const int bpmm = blockIdx.x;
    const int bp = bpmm >> 6, mm = bpmm & 63;
    const unsigned short* vr = v + (size_t)(bp * 64 + mm) * 1024;
    const int tid = threadIdx.x;
    #pragma unroll
    for (int it = 0; it < 4; ++it) {
        int c = (tid >> 6) + it * 4;
        int d = tid & 63;
        t[d][c] = vr[c * 64 + d];
    }
    __syncthreads();
    int d = tid >> 2, qq = tid & 3;
    ushort4 o = { t[d][qq * 4 + 0], t[d][qq * 4 + 1], t[d][qq * 4 + 2], t[d][qq * 4 + 3] };
    *(ushort4*)(vt + (size_t)bp * 65536 + (size_t)d * 1024 + mm * 16 + qq * 4) = o;
}

// ---------------- MFMA attention v3 (unchanged, proven) ----------------
__global__ __launch_bounds__(256, 2)
void attn_mfma_kernel(const unsigned short* __restrict__ qb,
                      const unsigned short* __restrict__ kb,
                      const unsigned short* __restrict__ vt,
                      const unsigned short* __restrict__ rbias,
                      const int* __restrict__ pmask,
                      unsigned short* __restrict__ att)
{
    __shared__ unsigned short Qs[128 * 64];
    __shared__ unsigned short KP[128 * 64];
    __shared__ unsigned short Vt[64 * 128];
    __shared__ unsigned short rbs[2048];
    __shared__ unsigned short pmls[1024];

    const int tid = threadIdx.x;
    const int w = tid >> 6, lane = tid & 63;
    const int quad = lane >> 4, col = lane & 15;
    const int bp = blockIdx.x, i0 = blockIdx.y * 128;
    const int h = bp & 15, bb = bp >> 4;
    const size_t base = (size_t)bp << 16;
    const int myrow0 = w * 32, myrow1 = w * 32 + 16;

    {
        const unsigned short* qg = qb + base + (size_t)i0 * 64;
        #pragma unroll
        for (int it = 0; it < 4; ++it) {
            int idx = it * 256 + tid;
            int r = idx >> 3, c = idx & 7;
            s8v d = *(const s8v*)(qg + (size_t)r * 64 + (c ^ (r & 7)) * 8);
            *(s8v*)(Qs + r * 64 + c * 8) = d;
        }
    }
    {
        const unsigned short* rg = rbias + h * 2048;
        #pragma unroll
        for (int it = 0; it < 8; ++it) rbs[it * 256 + tid] = rg[it * 256 + tid];
    }
    #pragma unroll
    for (int it = 0; it < 4; ++it) {
        int j = it * 256 + tid;
        pmls[j] = f2b(__logf((float)pmask[bb * 1024 + j]));
    }

    f32x4 O0[4] = {}, O1[4] = {};
    float lrow0[4] = {0.f, 0.f, 0.f, 0.f};
    float lrow1[4] = {0.f, 0.f, 0.f, 0.f};

    unsigned short* Pw = KP + w * 2048;

    for (int jt = 0; jt < 8; ++jt) {
        const int j0 = jt * 128;
        __syncthreads();
        {
            const unsigned short* kg = kb + base + (size_t)j0 * 64;
            #pragma unroll
            for (int it = 0; it < 4; ++it) {
                int idx = it * 256 + tid;
                int r = idx >> 3, c = idx & 7;
                s8v d = *(const s8v*)(kg + (size_t)r * 64 + (c ^ (r & 7)) * 8);
                *(s8v*)(KP + r * 64 + c * 8) = d;
            }
            const unsigned short* vg = vt + base + j0;
            #pragma unroll
            for (int it = 0; it < 4; ++it) {
                int idx = it * 256 + tid;
                int r = idx >> 4, c = idx & 15;
                s8v d = *(const s8v*)(vg + (size_t)r * 1024 + (c ^ (r & 15)) * 8);
                *(s8v*)(Vt + r * 128 + c * 8) = d;
            }
        }
        __syncthreads();

        f32x4 S0[8] = {}, S1[8] = {};
        #pragma unroll
        for (int ks = 0; ks < 2; ++ks) {
            int ar0 = myrow0 + col, ar1 = myrow1 + col;
            s8v a0 = *(const s8v*)(Qs + ar0 * 64 + (((ks * 4 + quad) ^ (ar0 & 7)) * 8));
            s8v a1 = *(const s8v*)(Qs + ar1 * 64 + (((ks * 4 + quad) ^ (ar1 & 7)) * 8));
            #pragma unroll
            for (int ct = 0; ct < 8; ++ct) {
                int br = ct * 16 + col;
                s8v b = *(const s8v*)(KP + br * 64 + (((ks * 4 + quad) ^ (br & 7)) * 8));
                S0[ct] = __builtin_amdgcn_mfma_f32_16x16x32_bf16(a0, b, S0[ct], 0, 0, 0);
                S1[ct] = __builtin_amdgcn_mfma_f32_16x16x32_bf16(a1, b, S1[ct], 0, 0, 0);
            }
        }

        #pragma unroll
        for (int ct = 0; ct < 8; ++ct) {
            int gj = j0 + ct * 16 + col;
            float pmv = bits2f(pmls[gj]);
            int d0 = gj - (i0 + myrow0 + quad * 4) + 1023;
            int d1 = gj - (i0 + myrow1 + quad * 4) + 1023;
            #pragma unroll
            for (int r = 0; r < 4; ++r) {
                float e0 = __expf(S0[ct][r] + bits2f(rbs[d0 - r]) + pmv);
                float e1 = __expf(S1[ct][r] + bits2f(rbs[d1 - r]) + pmv);
                S0[ct][r] = e0; lrow0[r] += e0;
                S1[ct][r] = e1; lrow1[r] += e1;
            }
        }

        __syncthreads();

        #pragma unroll
        for (int ct = 0; ct < 8; ++ct)
            #pragma unroll
            for (int r = 0; r < 4; ++r) {
                int lr = quad * 4 + r;
                int j = ct * 16 + col;
                Pw[lr * 128 + (((j >> 3) ^ lr) << 3) + (j & 7)] = f2b(S0[ct][r]);
            }
        #pragma unroll
        for (int kt = 0; kt < 4; ++kt) {
            int pr = col;
            s8v a = *(const s8v*)(Pw + pr * 128 + (((kt * 4 + quad) ^ pr) * 8));
            #pragma unroll
            for (int nt = 0; nt < 4; ++nt) {
                int vr = nt * 16 + col;
                s8v b = *(const s8v*)(Vt + vr * 128 + (((kt * 4 + quad) ^ (vr & 15)) * 8));
                O0[nt] = __builtin_amdgcn_mfma_f32_16x16x32_bf16(a, b, O0[nt], 0, 0, 0);
            }
        }

        #pragma unroll
        for (int ct = 0; ct < 8; ++ct)
            #pragma unroll
            for (int r = 0; r < 4; ++r) {
                int lr = quad * 4 + r;
                int j = ct * 16 + col;
                Pw[lr * 128 + (((j >> 3) ^ lr) << 3) + (j & 7)] = f2b(S1[ct][r]);
            }
        #pragma unroll
        for (int kt = 0; kt < 4; ++kt) {
            int pr = col;
            s8v a = *(const s8v*)(Pw + pr * 128 + (((kt * 4 + quad) ^ pr) * 8));
            #pragma unroll
            for (int nt = 0; nt < 4; ++nt) {
                int vr = nt * 16 + col;
                s8v b = *(const s8v*)(Vt + vr * 128 + (((kt * 4 + quad) ^ (vr & 15)) * 8));
                O1[nt] = __builtin_amdgcn_mfma_f32_16x16x32_bf16(a, b, O1[nt], 0, 0, 0);
            }
        }
    }

    #pragma unroll
    for (int off = 1; off < 16; off <<= 1)
        #pragma unroll
        for (int r = 0; r < 4; ++r) {
            lrow0[r] += __shfl_xor(lrow0[r], off);
            lrow1[r] += __shfl_xor(lrow1[r], off);
        }
    #pragma unroll
    for (int r = 0; r < 4; ++r) {
        lrow0[r] = 1.f / lrow0[r];
        lrow1[r] = 1.f / lrow1[r];
    }

    unsigned short* ag0 = att + base + (size_t)(i0 + myrow0) * 64;
    unsigned short* ag1 = att + base + (size_t)(i0 + myrow1) * 64;
    #pragma unroll
    for (int nt = 0; nt < 4; ++nt)
        #pragma unroll
        for (int r = 0; r < 4; ++r) {
            ag0[(size_t)(quad * 4 + r) * 64 + nt * 16 + col] = f2b(O0[nt][r] * lrow0[r]);
            ag1[(size_t)(quad * 4 + r) * 64 + nt * 16 + col] = f2b(O1[nt][r] * lrow1[r]);
        }
}

// ---------------- layernorm over rows of 1024: in1+in2 -> (outF fp32, outB bf16) ----------------
template<typename TIN>
__global__ __launch_bounds__(256)
void ln_kernel(const TIN* __restrict__ in1, const TIN* __restrict__ in2,
               float* __restrict__ outF, unsigned short* __restrict__ outB)
{
    __shared__ float sred[8];
    const int row = blockIdx.x;
    const int tid = threadIdx.x;
    const size_t off = (size_t)row * 1024 + tid * 4;
    float a[4];
    load4(in1 + off, a);
    if (in2) {
        float b[4];
        load4(in2 + off, b);
        #pragma unroll
        for (int i = 0; i < 4; ++i) a[i] += b[i];
    }

    float lsum = a[0] + a[1] + a[2] + a[3];
    #pragma unroll
    for (int o = 32; o; o >>= 1) lsum += __shfl_down(lsum, o);
    const int lane = tid & 63, wid = tid >> 6;
    if (lane == 0) sred[wid] = lsum;
    __syncthreads();
    if (tid == 0) sred[4] = (sred[0] + sred[1] + sred[2] + sred[3]) * (1.f / 1024.f);
    __syncthreads();
    const float mean = sred[4];

    float d0 = a[0] - mean, d1 = a[1] - mean, d2 = a[2] - mean, d3 = a[3] - mean;
    float lsq = d0 * d0 + d1 * d1 + d2 * d2 + d3 * d3;
    #pragma unroll
    for (int o = 32; o; o >>= 1) lsq += __shfl_down(lsq, o);
    __syncthreads();
    if (lane == 0) sred[wid] = lsq;
    __syncthreads();
    if (tid == 0) sred[5] = rsqrtf((sred[0] + sred[1] + sred[2] + sred[3]) * (1.f / 1024.f));
    __syncthreads();
    const float r = sred[5];

    float o0 = d0 * r, o1 = d1 * r, o2 = d2 * r, o3 = d3 * r;
    if (outF) {
        float4 o = {o0, o1, o2, o3};
        *(float4*)&outF[off] = o;
    }
    if (outB) {
        ushort4 o = { f2b(o0), f2b(o1), f2b(o2), f2b(o3) };
        *(ushort4*)&outB[off] = o;
    }
}

extern "C" void kernel_launch(void* const* d_in, const int* in_sizes, int n_in,
                              void* d_out, int out_size, void* d_ws, size_t ws_size,
                              hipStream_t stream)
{
    const float* x     = (const float*)d_in[0];
    const int*   pmask = (const int*)  d_in[1];
    const float* Wq    = (const float*)d_in[2];
    const float* bq    = (const float*)d_in[3];
    const float* Wk    = (const float*)d_in[4];
    const float* bk    = (const float*)d_in[5];
    const float* Wv    = (const float*)d_in[6];
    const float* bv    = (const float*)d_in[7];
    const float* Wo    = (const float*)d_in[8];
    const float* bo    = (const float*)d_in[9];
    const float* rel   = (const float*)d_in[10];
    const float* W1    = (const float*)d_in[11];
    const float* b1    = (const float*)d_in[12];
    const float* W2    = (const float*)d_in[13];
    const float* b2    = (const float*)d_in[14];

    const int M = 4096, D = 1024;
    dim3 blk(256);
    dim3 gblk(512);

    // ---- workspace map (identical to round-7/8-proven; peak write 64MB+64KB) ----
    char* ws = (char*)d_ws;
    unsigned short* W1b   = (unsigned short*)(ws);                 // 0-8
    unsigned short* W2b   = (unsigned short*)(ws + ( 8u << 20));   // 8-16
    unsigned short* xb    = (unsigned short*)(ws + (16u << 20));   // 16-24
    unsigned short* Wqkvb = (unsigned short*)(ws + (24u << 20));   // 24-30
    unsigned short* Wob   = (unsigned short*)(ws + (30u << 20));   // 30-32
    unsigned short* qb    = (unsigned short*)(ws + (32u << 20));   // 32-40
    unsigned short* kb    = (unsigned short*)(ws + (40u << 20));   // 40-48
    unsigned short* vb    = (unsigned short*)(ws + (48u << 20));   // 48-56
    unsigned short* vt    = (unsigned short*)(ws + (56u << 20));   // 56-64
    unsigned short* rbias = (unsigned short*)(ws + (64u << 20));   // 64-64.0625
    float*          tmpA    = (float*)(ws + (32u << 20));          // 32-48 (qb/kb dead after attn)
    float*          tmpB    = (float*)(ws + (48u << 20));          // 48-64 (vb/vt dead after attn)
    unsigned short* attoutB = (unsigned short*)(ws + (16u << 20)); // 16-24 (xb dead after qkv)
    unsigned short* ff1     = (unsigned short*)(ws + (32u << 20)); // 32-64 (tmpA/B dead after ln1)
    unsigned short* ff2a    = (unsigned short*)(ws);               // 0-8   (W1b dead after ff1)
    unsigned short* ff2b    = (unsigned short*)(ws + (24u << 20)); // 24-32 (Wqkvb/Wob dead)
    unsigned short* attb    = (unsigned short*)d_out;              // d_out scratch (proven)

    // ---- conversions / tables ----
    cvt_all_kernel<<<16384, blk, 0, stream>>>(x, Wq, Wk, Wv, Wo, W1, W2,
                                              xb, Wqkvb, Wob, W1b, W2b);
    rbias_kernel<<<128, blk, 0, stream>>>(rel, rbias);

    // ---- fused QKV projection: 128² kernel (768 blocks = 3/CU) ----
    mfma_gemm128<unsigned short, float, 0, 1><<<dim3(24, 32), blk, 0, stream>>>(
        xb, D, Wqkvb, D, bq, bk, bv, (const float*)nullptr, qb, kb, vb, D, M, 3072, D);

    vtrans_kernel<<<4096, blk, 0, stream>>>(vb, vt);

    // ---- attention v3: 128-query tiles, bp-major grid, 2 blocks/CU even ----
    attn_mfma_kernel<<<dim3(64, 8), blk, 0, stream>>>(qb, kb, vt, rbias, pmask, attb);

    // ---- Wo projection + residual x: 128x64 tile split-K z=2 (1024 blocks = 4/CU); LN1 ----
    mfma_gemm64n<float, float, 0><<<dim3(16, 32, 2), blk, 0, stream>>>(
        attb, D, Wob, D, bo, x, tmpA, tmpB, D, M, D, 512);
    ln_kernel<float><<<4096, blk, 0, stream>>>(tmpA, tmpB, nullptr, attoutB);

    // ---- FFN: ff1 256-tile (512 = 2/CU even); ff2 128x64 split-K z=2 (1024 = 4/CU); LN2 ----
    mfma_gemm256<unsigned short, float, 1, 0><<<dim3(32, 16), gblk, 0, stream>>>(
        attoutB, D, W1b, D, b1, nullptr, nullptr, (const float*)nullptr,
        ff1, nullptr, nullptr, 4096, M, 4096, D);
    mfma_gemm64n<unsigned short, unsigned short, 0><<<dim3(16, 32, 2), blk, 0, stream>>>(
        ff1, 4096, W2b, 4096, b2, attoutB, ff2a, ff2b, D, M, D, 2048);
    ln_kernel<unsigned short><<<4096, blk, 0, stream>>>(ff2a, ff2b, (float*)d_out, nullptr);
}

// Round 11
// 376.872 us; speedup vs baseline: 1.0833x; 1.0036x over previous
//
#include <hip/hip_runtime.h>
#include <hip/hip_bf16.h>

typedef __hip_bfloat16 bf16;
typedef __attribute__((ext_vector_type(8))) short s8v;      // 8 bf16 (4 VGPRs) MFMA A/B frag
typedef __attribute__((ext_vector_type(4))) float f32x4;    // MFMA C/D frag

__device__ __forceinline__ float bits2f(unsigned short u) {
    return __uint_as_float(((unsigned)u) << 16);
}
__device__ __forceinline__ unsigned short f2b(float f) {   // fp32 -> bf16 RNE
    union { float f; unsigned u; } x{f};
    return (unsigned short)((x.u + 0x7fff + ((x.u >> 16) & 1)) >> 16);
}
__device__ __forceinline__ float to_f(float x) { return x; }
__device__ __forceinline__ float to_f(unsigned short x) { return bits2f(x); }

__device__ __forceinline__ void load4(const float* p, float* a) {
    float4 t = *(const float4*)p;
    a[0] = t.x; a[1] = t.y; a[2] = t.z; a[3] = t.w;
}
__device__ __forceinline__ void load4(const unsigned short* p, float* a) {
    ushort4 t = *(const ushort4*)p;
    a[0] = bits2f(t.x); a[1] = bits2f(t.y); a[2] = bits2f(t.z); a[3] = bits2f(t.w);
}

// ---------------- fused fp32 -> bf16 convert of x + all weights ----------------
__global__ __launch_bounds__(256)
void cvt_all_kernel(const float* __restrict__ x,
                    const float* __restrict__ Wq, const float* __restrict__ Wk,
                    const float* __restrict__ Wv, const float* __restrict__ Wo,
                    const float* __restrict__ W1, const float* __restrict__ W2,
                    unsigned short* __restrict__ xb, unsigned short* __restrict__ Wqkvb,
                    unsigned short* __restrict__ Wob,
                    unsigned short* __restrict__ W1b, unsigned short* __restrict__ W2b)
{
    int i = blockIdx.x * 256 + threadIdx.x;
    const float* src; unsigned short* dst; int off;
    if (i < (1 << 20))      { src = x;  dst = xb;  off = i; }
    else if (i < (2 << 20)) { src = W1; dst = W1b; off = i - (1 << 20); }
    else if (i < (3 << 20)) { src = W2; dst = W2b; off = i - (2 << 20); }
    else {
        int j = i - (3 << 20);
        int sel = j >> 18;
        off = j & ((1 << 18) - 1);
        src = sel == 0 ? Wq : sel == 1 ? Wk : sel == 2 ? Wv : Wo;
        dst = sel == 3 ? Wob : Wqkvb + ((size_t)sel << 20);
    }
    float4 v = ((const float4*)src)[off];
    ushort4 o = { f2b(v.x), f2b(v.y), f2b(v.z), f2b(v.w) };
    ((ushort4*)dst)[off] = o;
}

// ---------------- per-head relative-position bias by delta (T5 buckets, double math) ----------------
__global__ void rbias_kernel(const float* __restrict__ rel_emb, unsigned short* __restrict__ rbias)
{
    int idx = blockIdx.x * 256 + threadIdx.x;   // 16 * 2048
    if (idx >= 16 * 2048) return;
    int h = idx >> 11, q = idx & 2047;
    int n = q - 1023, ret = 0;                  // n = j - i
    if (n < 0) { ret = 16; n = -n; }
    int b;
    if (n < 8) b = n;
    else {
        double t = log((double)n / 8.0) / log(16.0) * 8.0;
        int v = 8 + (int)t;
        b = v < 15 ? v : 15;
    }
    rbias[idx] = f2b(rel_emb[(ret + b) * 16 + h]);
}

// ============ 128x128 MFMA GEMM, BK=32 dbuf (verified R6/R8) — QKV / ff2 ============
template<typename TC, typename TR, int RELU, int QKV>
__global__ __launch_bounds__(256)
void mfma_gemm128(const unsigned short* __restrict__ A, int lda,
                  const unsigned short* __restrict__ W, int ldw,
                  const float* __restrict__ b0, const float* __restrict__ b1,
                  const float* __restrict__ b2,
                  const TR* __restrict__ res,
                  void* __restrict__ C0, void* __restrict__ C1, void* __restrict__ C2,
                  int ldc, int M, int N, int Ksplit)
{
    __shared__ unsigned short sm[4 * 128 * 32];   // 32KB: As[2] + Ws[2], [128][32] each
    const int tid = threadIdx.x;
    const int w = tid >> 6, lane = tid & 63;
    const int quad = lane >> 4, col = lane & 15;

    const int bid = blockIdx.x + gridDim.x * blockIdx.y;
    const int nwg = gridDim.x * gridDim.y;
    const int swz = (bid & 7) * (nwg >> 3) + (bid >> 3);
    const int m0 = (swz / gridDim.x) * 128;
    const int n0 = (swz % gridDim.x) * 128;

    const int wrow = (w & 1) * 64, wcol = (w >> 1) * 64;
    const int kz = blockIdx.z * Ksplit;
    const int NT = Ksplit >> 5;

    int sr0, sq0, sr1, sq1;
    {
        const int i0_ = tid;
        int sp = i0_ & 63, rl = ((sp >> 2) ^ (sp >> 4)) & 1;
        sr0 = ((i0_ >> 6) << 4) | ((sp >> 2) & 0xE) | rl;
        sq0 = (sp & 3) ^ ((((sp >> 3) & 1) << 1) | rl);
        const int i1_ = 256 + tid;
        sp = i1_ & 63; rl = ((sp >> 2) ^ (sp >> 4)) & 1;
        sr1 = ((i1_ >> 6) << 4) | ((sp >> 2) & 0xE) | rl;
        sq1 = (sp & 3) ^ ((((sp >> 3) & 1) << 1) | rl);
    }
    const unsigned off0 = (unsigned)__builtin_amdgcn_readfirstlane((unsigned)((0 * 256 + (tid & 192)) * 16));
    const unsigned off1 = (unsigned)__builtin_amdgcn_readfirstlane((unsigned)((1 * 256 + (tid & 192)) * 16));

#define STAGE32(buf, k0)                                                                     \
    {                                                                                        \
        unsigned short* As_ = sm + (buf) * 4096;                                             \
        unsigned short* Ws_ = sm + 8192 + (buf) * 4096;                                      \
        const unsigned short* ga0 = A + (size_t)(m0 + sr0) * lda + (k0) + sq0 * 8;           \
        __builtin_amdgcn_global_load_lds(                                                    \
            (const __attribute__((address_space(1))) unsigned int*)ga0,                      \
            (__attribute__((address_space(3))) unsigned int*)((char*)As_ + off0), 16, 0, 0); \
        const unsigned short* ga1 = A + (size_t)(m0 + sr1) * lda + (k0) + sq1 * 8;           \
        __builtin_amdgcn_global_load_lds(                                                    \
            (const __attribute__((address_space(1))) unsigned int*)ga1,                      \
            (__attribute__((address_space(3))) unsigned int*)((char*)As_ + off1), 16, 0, 0); \
        const unsigned short* gw0 = W + (size_t)(n0 + sr0) * ldw + (k0) + sq0 * 8;           \
        __builtin_amdgcn_global_load_lds(                                                    \
            (const __attribute__((address_space(1))) unsigned int*)gw0,                      \
            (__attribute__((address_space(3))) unsigned int*)((char*)Ws_ + off0), 16, 0, 0); \
        const unsigned short* gw1 = W + (size_t)(n0 + sr1) * ldw + (k0) + sq1 * 8;           \
        __builtin_amdgcn_global_load_lds(                                                    \
            (const __attribute__((address_space(1))) unsigned int*)gw1,                      \
            (__attribute__((address_space(3))) unsigned int*)((char*)Ws_ + off1), 16, 0, 0); \
    }

    f32x4 acc[4][4] = {};

    STAGE32(0, kz);

    for (int t = 0; t < NT; ++t) {
        __syncthreads();
        const int cur = t & 1;
        if (t + 1 < NT) STAGE32(cur ^ 1, kz + (t + 1) * 32);

        const unsigned short* As = sm + cur * 4096;
        const unsigned short* Ws = sm + 8192 + cur * 4096;
        s8v af[4], bfr[4];
        #pragma unroll
        for (int mt = 0; mt < 4; ++mt) {
            int rr = wrow + mt * 16 + col;
            af[mt] = *(const s8v*)(As + ((rr * 32 + ((quad ^ (rr & 3)) << 3)) ^ (((rr >> 2) & 1) << 5)));
        }
        #pragma unroll
        for (int nt = 0; nt < 4; ++nt) {
            int rr = wcol + nt * 16 + col;
            bfr[nt] = *(const s8v*)(Ws + ((rr * 32 + ((quad ^ (rr & 3)) << 3)) ^ (((rr >> 2) & 1) << 5)));
        }
        __builtin_amdgcn_s_setprio(1);
        #pragma unroll
        for (int mt = 0; mt < 4; ++mt)
            #pragma unroll
            for (int nt = 0; nt < 4; ++nt)
                acc[mt][nt] = __builtin_amdgcn_mfma_f32_16x16x32_bf16(af[mt], bfr[nt], acc[mt][nt], 0, 0, 0);
        __builtin_amdgcn_s_setprio(0);
    }
#undef STAGE32

    if (QKV) {
        const int sel = n0 >> 10;
        unsigned short* Cb = (unsigned short*)(sel == 0 ? C0 : sel == 1 ? C1 : C2);
        const float* bs = sel == 0 ? b0 : sel == 1 ? b1 : b2;
        #pragma unroll
        for (int mt = 0; mt < 4; ++mt)
            #pragma unroll
            for (int rg = 0; rg < 4; ++rg) {
                int gm = m0 + wrow + mt * 16 + quad * 4 + rg;
                #pragma unroll
                for (int nt = 0; nt < 4; ++nt) {
                    int gnc = (n0 + wcol + nt * 16 + col) & 1023;
                    Cb[(size_t)gm * 1024 + gnc] = f2b(acc[mt][nt][rg] + bs[gnc]);
                }
            }
    } else {
        void* Cv = blockIdx.z ? C1 : C0;
        const bool z0 = (blockIdx.z == 0);
        #pragma unroll
        for (int mt = 0; mt < 4; ++mt)
            #pragma unroll
            for (int rg = 0; rg < 4; ++rg) {
                int gm = m0 + wrow + mt * 16 + quad * 4 + rg;
                #pragma unroll
                for (int nt = 0; nt < 4; ++nt) {
                    int gn = n0 + wcol + nt * 16 + col;
                    float c = acc[mt][nt][rg];
                    if (z0) {
                        if (b0)  c += b0[gn];
                        if (res) c += to_f(res[(size_t)gm * ldc + gn]);
                    }
                    if (RELU) c = fmaxf(c, 0.f);
                    if (sizeof(TC) == 2) ((unsigned short*)Cv)[(size_t)gm * ldc + gn] = f2b(c);
                    else                 ((float*)Cv)[(size_t)gm * ldc + gn] = c;
                }
            }
    }
}

// ============ 128x64 MFMA GEMM, BK=32 dbuf (verified R10) — Wo only ============
// R10 measured: Wo (K=512/z, short loop) gains ~11us at 4 blocks/CU; ff2
// (K=2048/z) regresses here (73.2 vs 67.4 at 128²) — so ff2 goes back to 128².
template<typename TC, typename TR, int RELU>
__global__ __launch_bounds__(256)
void mfma_gemm64n(const unsigned short* __restrict__ A, int lda,
                  const unsigned short* __restrict__ W, int ldw,
                  const float* __restrict__ b0,
                  const TR* __restrict__ res,
                  void* __restrict__ C0, void* __restrict__ C1,
                  int ldc, int M, int N, int Ksplit)
{
    __shared__ unsigned short sm[2 * 4096 + 2 * 2048];   // 24KB: As[2][128][32], Ws[2][64][32]
    const int tid = threadIdx.x;
    const int w = tid >> 6, lane = tid & 63;
    const int quad = lane >> 4, col = lane & 15;

    const int bid = blockIdx.x + gridDim.x * blockIdx.y;
    const int nwg = gridDim.x * gridDim.y;
    const int swz = (bid & 7) * (nwg >> 3) + (bid >> 3);
    const int m0 = (swz / gridDim.x) * 128;
    const int n0 = (swz % gridDim.x) * 64;

    const int wrow = (w & 1) * 64, wcol = (w >> 1) * 32;
    const int kz = blockIdx.z * Ksplit;
    const int NT = Ksplit >> 5;

    int sr0, sq0, sr1, sq1;
    {
        const int i0_ = tid;
        int sp = i0_ & 63, rl = ((sp >> 2) ^ (sp >> 4)) & 1;
        sr0 = ((i0_ >> 6) << 4) | ((sp >> 2) & 0xE) | rl;
        sq0 = (sp & 3) ^ ((((sp >> 3) & 1) << 1) | rl);
        const int i1_ = 256 + tid;
        sp = i1_ & 63; rl = ((sp >> 2) ^ (sp >> 4)) & 1;
        sr1 = ((i1_ >> 6) << 4) | ((sp >> 2) & 0xE) | rl;
        sq1 = (sp & 3) ^ ((((sp >> 3) & 1) << 1) | rl);
    }
    const unsigned off0 = (unsigned)__builtin_amdgcn_readfirstlane((unsigned)((tid & 192) * 16));
    const unsigned off1 = (unsigned)__builtin_amdgcn_readfirstlane((unsigned)((256 + (tid & 192)) * 16));

#define STAGE64N(buf, k0)                                                                    \
    {                                                                                        \
        unsigned short* As_ = sm + (buf) * 4096;                                             \
        unsigned short* Ws_ = sm + 8192 + (buf) * 2048;                                      \
        const unsigned short* ga0 = A + (size_t)(m0 + sr0) * lda + (k0) + sq0 * 8;           \
        __builtin_amdgcn_global_load_lds(                                                    \
            (const __attribute__((address_space(1))) unsigned int*)ga0,                      \
            (__attribute__((address_space(3))) unsigned int*)((char*)As_ + off0), 16, 0, 0); \
        const unsigned short* ga1 = A + (size_t)(m0 + sr1) * lda + (k0) + sq1 * 8;           \
        __builtin_amdgcn_global_load_lds(                                                    \
            (const __attribute__((address_space(1))) unsigned int*)ga1,                      \
            (__attribute__((address_space(3))) unsigned int*)((char*)As_ + off1), 16, 0, 0); \
        const unsigned short* gw0 = W + (size_t)(n0 + sr0) * ldw + (k0) + sq0 * 8;           \
        __builtin_amdgcn_global_load_lds(                                                    \
            (const __attribute__((address_space(1))) unsigned int*)gw0,                      \
            (__attribute__((address_space(3))) unsigned int*)((char*)Ws_ + off0), 16, 0, 0); \
    }

    f32x4 acc[4][2] = {};

    STAGE64N(0, kz);

    for (int t = 0; t < NT; ++t) {
        __syncthreads();
        const int cur = t & 1;
        if (t + 1 < NT) STAGE64N(cur ^ 1, kz + (t + 1) * 32);

        const unsigned short* As = sm + cur * 4096;
        const unsigned short* Ws = sm + 8192 + cur * 2048;
        s8v af[4], bfr[2];
        #pragma unroll
        for (int mt = 0; mt < 4; ++mt) {
            int rr = wrow + mt * 16 + col;
            af[mt] = *(const s8v*)(As + ((rr * 32 + ((quad ^ (rr & 3)) << 3)) ^ (((rr >> 2) & 1) << 5)));
        }
        #pragma unroll
        for (int nt = 0; nt < 2; ++nt) {
            int rr = wcol + nt * 16 + col;
            bfr[nt] = *(const s8v*)(Ws + ((rr * 32 + ((quad ^ (rr & 3)) << 3)) ^ (((rr >> 2) & 1) << 5)));
        }
        __builtin_amdgcn_s_setprio(1);
        #pragma unroll
        for (int mt = 0; mt < 4; ++mt)
            #pragma unroll
            for (int nt = 0; nt < 2; ++nt)
                acc[mt][nt] = __builtin_amdgcn_mfma_f32_16x16x32_bf16(af[mt], bfr[nt], acc[mt][nt], 0, 0, 0);
        __builtin_amdgcn_s_setprio(0);
    }
#undef STAGE64N

    void* Cv = blockIdx.z ? C1 : C0;
    const bool z0 = (blockIdx.z == 0);
    #pragma unroll
    for (int mt = 0; mt < 4; ++mt)
        #pragma unroll
        for (int rg = 0; rg < 4; ++rg) {
            int gm = m0 + wrow + mt * 16 + quad * 4 + rg;
            #pragma unroll
            for (int nt = 0; nt < 2; ++nt) {
                int gn = n0 + wcol + nt * 16 + col;
                float c = acc[mt][nt][rg];
                if (z0) {
                    if (b0)  c += b0[gn];
                    if (res) c += to_f(res[(size_t)gm * ldc + gn]);
                }
                if (RELU) c = fmaxf(c, 0.f);
                if (sizeof(TC) == 2) ((unsigned short*)Cv)[(size_t)gm * ldc + gn] = f2b(c);
                else                 ((float*)Cv)[(size_t)gm * ldc + gn] = c;
            }
        }
}

// ============ 256x128 MFMA GEMM, 8 waves, BK=32 dbuf (verified R7) — ff1 ============
template<typename TC, typename TR, int RELU, int QKV>
__global__ __launch_bounds__(512)
void mfma_gemm256(const unsigned short* __restrict__ A, int lda,
                  const unsigned short* __restrict__ W, int ldw,
                  const float* __restrict__ b0, const float* __restrict__ b1,
                  const float* __restrict__ b2,
                  const TR* __restrict__ res,
                  void* __restrict__ C0, void* __restrict__ C1, void* __restrict__ C2,
                  int ldc, int M, int N, int Ksplit)
{
    __shared__ unsigned short sm[2 * 8192 + 2 * 4096];   // 48KB: A dbuf [2][256][32], W dbuf [2][128][32]
    const int tid = threadIdx.x;
    const int w = tid >> 6, lane = tid & 63;
    const int quad = lane >> 4, col = lane & 15;

    const int bid = blockIdx.x + gridDim.x * blockIdx.y;
    const int xcd = bid & 7, j = bid >> 3;
    const int rh = gridDim.y >> 1, cw = gridDim.x >> 2;
    const int m0 = (((xcd & 1) * rh) + (j % rh)) * 256;
    const int n0 = (((xcd >> 1) * cw) + (j / rh)) * 128;

    const int wrow = (w & 3) * 64, wcol = (w >> 2) * 64;
    const int kz = blockIdx.z * Ksplit;
    const int NT = Ksplit >> 5;

    int sr0, sq0, sr1, sq1, sr2, sq2;
    {
        int idx = tid;
        int sp = idx & 63, rl = ((sp >> 2) ^ (sp >> 4)) & 1;
        sr0 = ((idx >> 6) << 4) | ((sp >> 2) & 0xE) | rl;
        sq0 = (sp & 3) ^ ((((sp >> 3) & 1) << 1) | rl);
        idx = 512 + tid;
        sp = idx & 63; rl = ((sp >> 2) ^ (sp >> 4)) & 1;
        sr1 = ((idx >> 6) << 4) | ((sp >> 2) & 0xE) | rl;
        sq1 = (sp & 3) ^ ((((sp >> 3) & 1) << 1) | rl);
        sr2 = sr0; sq2 = sq0;
    }
    const unsigned offA0 = (unsigned)__builtin_amdgcn_readfirstlane((unsigned)((tid & 448) * 16));
    const unsigned offA1 = (unsigned)__builtin_amdgcn_readfirstlane((unsigned)((512 + (tid & 448)) * 16));
    const unsigned offW0 = offA0;

#define STAGE(buf, k0)                                                                       \
    {                                                                                        \
        unsigned short* As_ = sm + (buf) * 8192;                                             \
        unsigned short* Ws_ = sm + 16384 + (buf) * 4096;                                     \
        const unsigned short* ga0 = A + (size_t)(m0 + sr0) * lda + (k0) + sq0 * 8;           \
        __builtin_amdgcn_global_load_lds(                                                    \
            (const __attribute__((address_space(1))) unsigned int*)ga0,                      \
            (__attribute__((address_space(3))) unsigned int*)((char*)As_ + offA0), 16, 0, 0);\
        const unsigned short* ga1 = A + (size_t)(m0 + sr1) * lda + (k0) + sq1 * 8;           \
        __builtin_amdgcn_global_load_lds(                                                    \
            (const __attribute__((address_space(1))) unsigned int*)ga1,                      \
            (__attribute__((address_space(3))) unsigned int*)((char*)As_ + offA1), 16, 0, 0);\
        const unsigned short* gw0 = W + (size_t)(n0 + sr2) * ldw + (k0) + sq2 * 8;           \
        __builtin_amdgcn_global_load_lds(                                                    \
            (const __attribute__((address_space(1))) unsigned int*)gw0,                      \
            (__attribute__((address_space(3))) unsigned int*)((char*)Ws_ + offW0), 16, 0, 0);\
    }

    f32x4 acc[4][4] = {};

    STAGE(0, kz);

    for (int t = 0; t < NT; ++t) {
        __syncthreads();
        const int cur = t & 1;
        if (t + 1 < NT) STAGE(cur ^ 1, kz + (t + 1) * 32);

        const unsigned short* As = sm + cur * 8192;
        const unsigned short* Ws = sm + 16384 + cur * 4096;
        s8v af[4], bfr[4];
        #pragma unroll
        for (int mt = 0; mt < 4; ++mt) {
            int rr = wrow + mt * 16 + col;
            af[mt] = *(const s8v*)(As + ((rr * 32 + ((quad ^ (rr & 3)) << 3)) ^ (((rr >> 2) & 1) << 5)));
        }
        #pragma unroll
        for (int nt = 0; nt < 4; ++nt) {
            int rr = wcol + nt * 16 + col;
            bfr[nt] = *(const s8v*)(Ws + ((rr * 32 + ((quad ^ (rr & 3)) << 3)) ^ (((rr >> 2) & 1) << 5)));
        }
        __builtin_amdgcn_s_setprio(1);
        #pragma unroll
        for (int mt = 0; mt < 4; ++mt)
            #pragma unroll
            for (int nt = 0; nt < 4; ++nt)
                acc[mt][nt] = __builtin_amdgcn_mfma_f32_16x16x32_bf16(af[mt], bfr[nt], acc[mt][nt], 0, 0, 0);
        __builtin_amdgcn_s_setprio(0);
    }
#undef STAGE

    if (QKV) {
        const int sel = n0 >> 10;
        unsigned short* Cb = (unsigned short*)(sel == 0 ? C0 : sel == 1 ? C1 : C2);
        const float* bs = sel == 0 ? b0 : sel == 1 ? b1 : b2;
        #pragma unroll
        for (int mt = 0; mt < 4; ++mt)
            #pragma unroll
            for (int rg = 0; rg < 4; ++rg) {
                int gm = m0 + wrow + mt * 16 + quad * 4 + rg;
                #pragma unroll
                for (int nt = 0; nt < 4; ++nt) {
                    int gnc = (n0 + wcol + nt * 16 + col) & 1023;
                    Cb[(size_t)gm * 1024 + gnc] = f2b(acc[mt][nt][rg] + bs[gnc]);
                }
            }
    } else {
        void* Cv = blockIdx.z ? C1 : C0;
        const bool z0 = (blockIdx.z == 0);
        #pragma unroll
        for (int mt = 0; mt < 4; ++mt)
            #pragma unroll
            for (int rg = 0; rg < 4; ++rg) {
                int gm = m0 + wrow + mt * 16 + quad * 4 + rg;
                #pragma unroll
                for (int nt = 0; nt < 4; ++nt) {
                    int gn = n0 + wcol + nt * 16 + col;
                    float c = acc[mt][nt][rg];
                    if (z0) {
                        if (b0)  c += b0[gn];
                        if (res) c += to_f(res[(size_t)gm * ldc + gn]);
                    }
                    if (RELU) c = fmaxf(c, 0.f);
                    if (sizeof(TC) == 2) ((unsigned short*)Cv)[(size_t)gm * ldc + gn] = f2b(c);
                    else                 ((float*)Cv)[(size_t)gm * ldc + gn] = c;
                }
            }
    }
}

// ---------------- V transpose: vb bf16 [4096][1024] -> vt bf16 [bp][d][j] ----------------
__global__ __launch_bounds__(256)
void vtrans_kernel(const unsigned short* __restrict__ v, unsigned short* __restrict__ vt)
{
    __shared__ unsigned short t[64][68];
    const int bpmm = blockIdx.x;
    const int bp = bpmm >> 6, mm = bpmm & 63;
    const unsigned short* vr = v + (size_t)(bp * 64 + mm) * 1024;
    const int tid = threadIdx.x;
    #pragma unroll
    for (int it = 0; it < 4; ++it) {
        int c = (tid >> 6) + it * 4;
        int d = tid & 63;
        t[d][c] = vr[c * 64 + d];
    }
    __syncthreads();
    int d = tid >> 2, qq = tid & 3;
    ushort4 o = { t[d][qq * 4 + 0], t[d][qq * 4 + 1], t[d][qq * 4 + 2], t[d][qq * 4 + 3] };
    *(ushort4*)(vt + (size_t)bp * 65536 + (size_t)d * 1024 + mm * 16 + qq * 4) = o;
}

// ---------------- MFMA attention v3 (unchanged, proven) ----------------
__global__ __launch_bounds__(256, 2)
void attn_mfma_kernel(const unsigned short* __restrict__ qb,
                      const unsigned short* __restrict__ kb,
                      const unsigned short* __restrict__ vt,
                      const unsigned short* __restrict__ rbias,
                      const int* __restrict__ pmask,
                      unsigned short* __restrict__ att)
{
    __shared__ unsigned short Qs[128 * 64];
    __shared__ unsigned short KP[128 * 64];
    __shared__ unsigned short Vt[64 * 128];
    __shared__ unsigned short rbs[2048];
    __shared__ unsigned short pmls[1024];

    const int tid = threadIdx.x;
    const int w = tid >> 6, lane = tid & 63;
    const int quad = lane >> 4, col = lane & 15;
    const int bp = blockIdx.x, i0 = blockIdx.y * 128;
    const int h = bp & 15, bb = bp >> 4;
    const size_t base = (size_t)bp << 16;
    const int myrow0 = w * 32, myrow1 = w * 32 + 16;

    {
        const unsigned short* qg = qb + base + (size_t)i0 * 64;
        #pragma unroll
        for (int it = 0; it < 4; ++it) {
            int idx = it * 256 + tid;
            int r = idx >> 3, c = idx & 7;
            s8v d = *(const s8v*)(qg + (size_t)r * 64 + (c ^ (r & 7)) * 8);
            *(s8v*)(Qs + r * 64 + c * 8) = d;
        }
    }
    {
        const unsigned short* rg = rbias + h * 2048;
        #pragma unroll
        for (int it = 0; it < 8; ++it) rbs[it * 256 + tid] = rg[it * 256 + tid];
    }
    #pragma unroll
    for (int it = 0; it < 4; ++it) {
        int j = it * 256 + tid;
        pmls[j] = f2b(__logf((float)pmask[bb * 1024 + j]));
    }

    f32x4 O0[4] = {}, O1[4] = {};
    float lrow0[4] = {0.f, 0.f, 0.f, 0.f};
    float lrow1[4] = {0.f, 0.f, 0.f, 0.f};

    unsigned short* Pw = KP + w * 2048;

    for (int jt = 0; jt < 8; ++jt) {
        const int j0 = jt * 128;
        __syncthreads();
        {
            const unsigned short* kg = kb + base + (size_t)j0 * 64;
            #pragma unroll
            for (int it = 0; it < 4; ++it) {
                int idx = it * 256 + tid;
                int r = idx >> 3, c = idx & 7;
                s8v d = *(const s8v*)(kg + (size_t)r * 64 + (c ^ (r & 7)) * 8);
                *(s8v*)(KP + r * 64 + c * 8) = d;
            }
            const unsigned short* vg = vt + base + j0;
            #pragma unroll
            for (int it = 0; it < 4; ++it) {
                int idx = it * 256 + tid;
                int r = idx >> 4, c = idx & 15;
                s8v d = *(const s8v*)(vg + (size_t)r * 1024 + (c ^ (r & 15)) * 8);
                *(s8v*)(Vt + r * 128 + c * 8) = d;
            }
        }
        __syncthreads();

        f32x4 S0[8] = {}, S1[8] = {};
        #pragma unroll
        for (int ks = 0; ks < 2; ++ks) {
            int ar0 = myrow0 + col, ar1 = myrow1 + col;
            s8v a0 = *(const s8v*)(Qs + ar0 * 64 + (((ks * 4 + quad) ^ (ar0 & 7)) * 8));
            s8v a1 = *(const s8v*)(Qs + ar1 * 64 + (((ks * 4 + quad) ^ (ar1 & 7)) * 8));
            #pragma unroll
            for (int ct = 0; ct < 8; ++ct) {
                int br = ct * 16 + col;
                s8v b = *(const s8v*)(KP + br * 64 + (((ks * 4 + quad) ^ (br & 7)) * 8));
                S0[ct] = __builtin_amdgcn_mfma_f32_16x16x32_bf16(a0, b, S0[ct], 0, 0, 0);
                S1[ct] = __builtin_amdgcn_mfma_f32_16x16x32_bf16(a1, b, S1[ct], 0, 0, 0);
            }
        }

        #pragma unroll
        for (int ct = 0; ct < 8; ++ct) {
            int gj = j0 + ct * 16 + col;
            float pmv = bits2f(pmls[gj]);
            int d0 = gj - (i0 + myrow0 + quad * 4) + 1023;
            int d1 = gj - (i0 + myrow1 + quad * 4) + 1023;
            #pragma unroll
            for (int r = 0; r < 4; ++r) {
                float e0 = __expf(S0[ct][r] + bits2f(rbs[d0 - r]) + pmv);
                float e1 = __expf(S1[ct][r] + bits2f(rbs[d1 - r]) + pmv);
                S0[ct][r] = e0; lrow0[r] += e0;
                S1[ct][r] = e1; lrow1[r] += e1;
            }
        }

        __syncthreads();

        #pragma unroll
        for (int ct = 0; ct < 8; ++ct)
            #pragma unroll
            for (int r = 0; r < 4; ++r) {
                int lr = quad * 4 + r;
                int j = ct * 16 + col;
                Pw[lr * 128 + (((j >> 3) ^ lr) << 3) + (j & 7)] = f2b(S0[ct][r]);
            }
        #pragma unroll
        for (int kt = 0; kt < 4; ++kt) {
            int pr = col;
            s8v a = *(const s8v*)(Pw + pr * 128 + (((kt * 4 + quad) ^ pr) * 8));
            #pragma unroll
            for (int nt = 0; nt < 4; ++nt) {
                int vr = nt * 16 + col;
                s8v b = *(const s8v*)(Vt + vr * 128 + (((kt * 4 + quad) ^ (vr & 15)) * 8));
                O0[nt] = __builtin_amdgcn_mfma_f32_16x16x32_bf16(a, b, O0[nt], 0, 0, 0);
            }
        }

        #pragma unroll
        for (int ct = 0; ct < 8; ++ct)
            #pragma unroll
            for (int r = 0; r < 4; ++r) {
                int lr = quad * 4 + r;
                int j = ct * 16 + col;
                Pw[lr * 128 + (((j >> 3) ^ lr) << 3) + (j & 7)] = f2b(S1[ct][r]);
            }
        #pragma unroll
        for (int kt = 0; kt < 4; ++kt) {
            int pr = col;
            s8v a = *(const s8v*)(Pw + pr * 128 + (((kt * 4 + quad) ^ pr) * 8));
            #pragma unroll
            for (int nt = 0; nt < 4; ++nt) {
                int vr = nt * 16 + col;
                s8v b = *(const s8v*)(Vt + vr * 128 + (((kt * 4 + quad) ^ (vr & 15)) * 8));
                O1[nt] = __builtin_amdgcn_mfma_f32_16x16x32_bf16(a, b, O1[nt], 0, 0, 0);
            }
        }
    }

    #pragma unroll
    for (int off = 1; off < 16; off <<= 1)
        #pragma unroll
        for (int r = 0; r < 4; ++r) {
            lrow0[r] += __shfl_xor(lrow0[r], off);
            lrow1[r] += __shfl_xor(lrow1[r], off);
        }
    #pragma unroll
    for (int r = 0; r < 4; ++r) {
        lrow0[r] = 1.f / lrow0[r];
        lrow1[r] = 1.f / lrow1[r];
    }

    unsigned short* ag0 = att + base + (size_t)(i0 + myrow0) * 64;
    unsigned short* ag1 = att + base + (size_t)(i0 + myrow1) * 64;
    #pragma unroll
    for (int nt = 0; nt < 4; ++nt)
        #pragma unroll
        for (int r = 0; r < 4; ++r) {
            ag0[(size_t)(quad * 4 + r) * 64 + nt * 16 + col] = f2b(O0[nt][r] * lrow0[r]);
            ag1[(size_t)(quad * 4 + r) * 64 + nt * 16 + col] = f2b(O1[nt][r] * lrow1[r]);
        }
}

// ---------------- layernorm over rows of 1024: in1+in2 -> (outF fp32, outB bf16) ----------------
template<typename TIN>
__global__ __launch_bounds__(256)
void ln_kernel(const TIN* __restrict__ in1, const TIN* __restrict__ in2,
               float* __restrict__ outF, unsigned short* __restrict__ outB)
{
    __shared__ float sred[8];
    const int row = blockIdx.x;
    const int tid = threadIdx.x;
    const size_t off = (size_t)row * 1024 + tid * 4;
    float a[4];
    load4(in1 + off, a);
    if (in2) {
        float b[4];
        load4(in2 + off, b);
        #pragma unroll
        for (int i = 0; i < 4; ++i) a[i] += b[i];
    }

    float lsum = a[0] + a[1] + a[2] + a[3];
    #pragma unroll
    for (int o = 32; o; o >>= 1) lsum += __shfl_down(lsum, o);
    const int lane = tid & 63, wid = tid >> 6;
    if (lane == 0) sred[wid] = lsum;
    __syncthreads();
    if (tid == 0) sred[4] = (sred[0] + sred[1] + sred[2] + sred[3]) * (1.f / 1024.f);
    __syncthreads();
    const float mean = sred[4];

    float d0 = a[0] - mean, d1 = a[1] - mean, d2 = a[2] - mean, d3 = a[3] - mean;
    float lsq = d0 * d0 + d1 * d1 + d2 * d2 + d3 * d3;
    #pragma unroll
    for (int o = 32; o; o >>= 1) lsq += __shfl_down(lsq, o);
    __syncthreads();
    if (lane == 0) sred[wid] = lsq;
    __syncthreads();
    if (tid == 0) sred[5] = rsqrtf((sred[0] + sred[1] + sred[2] + sred[3]) * (1.f / 1024.f));
    __syncthreads();
    const float r = sred[5];

    float o0 = d0 * r, o1 = d1 * r, o2 = d2 * r, o3 = d3 * r;
    if (outF) {
        float4 o = {o0, o1, o2, o3};
        *(float4*)&outF[off] = o;
    }
    if (outB) {
        ushort4 o = { f2b(o0), f2b(o1), f2b(o2), f2b(o3) };
        *(ushort4*)&outB[off] = o;
    }
}

extern "C" void kernel_launch(void* const* d_in, const int* in_sizes, int n_in,
                              void* d_out, int out_size, void* d_ws, size_t ws_size,
                              hipStream_t stream)
{
    const float* x     = (const float*)d_in[0];
    const int*   pmask = (const int*)  d_in[1];
    const float* Wq    = (const float*)d_in[2];
    const float* bq    = (const float*)d_in[3];
    const float* Wk    = (const float*)d_in[4];
    const float* bk    = (const float*)d_in[5];
    const float* Wv    = (const float*)d_in[6];
    const float* bv    = (const float*)d_in[7];
    const float* Wo    = (const float*)d_in[8];
    const float* bo    = (const float*)d_in[9];
    const float* rel   = (const float*)d_in[10];
    const float* W1    = (const float*)d_in[11];
    const float* b1    = (const float*)d_in[12];
    const float* W2    = (const float*)d_in[13];
    const float* b2    = (const float*)d_in[14];

    const int M = 4096, D = 1024;
    dim3 blk(256);
    dim3 gblk(512);

    // ---- workspace map (identical to round-7/8-proven; peak write 64MB+64KB) ----
    char* ws = (char*)d_ws;
    unsigned short* W1b   = (unsigned short*)(ws);                 // 0-8
    unsigned short* W2b   = (unsigned short*)(ws + ( 8u << 20));   // 8-16
    unsigned short* xb    = (unsigned short*)(ws + (16u << 20));   // 16-24
    unsigned short* Wqkvb = (unsigned short*)(ws + (24u << 20));   // 24-30
    unsigned short* Wob   = (unsigned short*)(ws + (30u << 20));   // 30-32
    unsigned short* qb    = (unsigned short*)(ws + (32u << 20));   // 32-40
    unsigned short* kb    = (unsigned short*)(ws + (40u << 20));   // 40-48
    unsigned short* vb    = (unsigned short*)(ws + (48u << 20));   // 48-56
    unsigned short* vt    = (unsigned short*)(ws + (56u << 20));   // 56-64
    unsigned short* rbias = (unsigned short*)(ws + (64u << 20));   // 64-64.0625
    float*          tmpA    = (float*)(ws + (32u << 20));          // 32-48 (qb/kb dead after attn)
    float*          tmpB    = (float*)(ws + (48u << 20));          // 48-64 (vb/vt dead after attn)
    unsigned short* attoutB = (unsigned short*)(ws + (16u << 20)); // 16-24 (xb dead after qkv)
    unsigned short* ff1     = (unsigned short*)(ws + (32u << 20)); // 32-64 (tmpA/B dead after ln1)
    unsigned short* ff2a    = (unsigned short*)(ws);               // 0-8   (W1b dead after ff1)
    unsigned short* ff2b    = (unsigned short*)(ws + (24u << 20)); // 24-32 (Wqkvb/Wob dead)
    unsigned short* attb    = (unsigned short*)d_out;              // d_out scratch (proven)

    // ---- conversions / tables ----
    cvt_all_kernel<<<16384, blk, 0, stream>>>(x, Wq, Wk, Wv, Wo, W1, W2,
                                              xb, Wqkvb, Wob, W1b, W2b);
    rbias_kernel<<<128, blk, 0, stream>>>(rel, rbias);

    // ---- fused QKV projection: 128² kernel (768 blocks = 3/CU) ----
    mfma_gemm128<unsigned short, float, 0, 1><<<dim3(24, 32), blk, 0, stream>>>(
        xb, D, Wqkvb, D, bq, bk, bv, (const float*)nullptr, qb, kb, vb, D, M, 3072, D);

    vtrans_kernel<<<4096, blk, 0, stream>>>(vb, vt);

    // ---- attention v3: 128-query tiles, bp-major grid, 2 blocks/CU even ----
    attn_mfma_kernel<<<dim3(64, 8), blk, 0, stream>>>(qb, kb, vt, rbias, pmask, attb);

    // ---- Wo projection + residual x: 128x64 tile split-K z=2 (1024 blocks = 4/CU); LN1 ----
    mfma_gemm64n<float, float, 0><<<dim3(16, 32, 2), blk, 0, stream>>>(
        attb, D, Wob, D, bo, x, tmpA, tmpB, D, M, D, 512);
    ln_kernel<float><<<4096, blk, 0, stream>>>(tmpA, tmpB, nullptr, attoutB);

    // ---- FFN: ff1 256-tile (512 = 2/CU even); ff2 128² split-K z=2 (512 = 2/CU, R8-best); LN2 ----
    mfma_gemm256<unsigned short, float, 1, 0><<<dim3(32, 16), gblk, 0, stream>>>(
        attoutB, D, W1b, D, b1, nullptr, nullptr, (const float*)nullptr,
        ff1, nullptr, nullptr, 4096, M, 4096, D);
    mfma_gemm128<unsigned short, unsigned short, 0, 0><<<dim3(8, 32, 2), blk, 0, stream>>>(
        ff1, 4096, W2b, 4096, b2, nullptr, nullptr, attoutB, ff2a, ff2b, nullptr, D, M, D, 2048);
    ln_kernel<unsigned short><<<4096, blk, 0, stream>>>(ff2a, ff2b, (float*)d_out, nullptr);
}

// Round 12
// 375.235 us; speedup vs baseline: 1.0881x; 1.0044x over previous
//
#include <hip/hip_runtime.h>
#include <hip/hip_bf16.h>

typedef __hip_bfloat16 bf16;
typedef __attribute__((ext_vector_type(8))) short s8v;      // 8 bf16 (4 VGPRs) MFMA A/B frag
typedef __attribute__((ext_vector_type(4))) float f32x4;    // MFMA C/D frag

__device__ __forceinline__ float bits2f(unsigned short u) {
    return __uint_as_float(((unsigned)u) << 16);
}
__device__ __forceinline__ unsigned short f2b(float f) {   // fp32 -> bf16 RNE
    union { float f; unsigned u; } x{f};
    return (unsigned short)((x.u + 0x7fff + ((x.u >> 16) & 1)) >> 16);
}
__device__ __forceinline__ float to_f(float x) { return x; }
__device__ __forceinline__ float to_f(unsigned short x) { return bits2f(x); }

__device__ __forceinline__ void load4(const float* p, float* a) {
    float4 t = *(const float4*)p;
    a[0] = t.x; a[1] = t.y; a[2] = t.z; a[3] = t.w;
}
__device__ __forceinline__ void load4(const unsigned short* p, float* a) {
    ushort4 t = *(const ushort4*)p;
    a[0] = bits2f(t.x); a[1] = bits2f(t.y); a[2] = bits2f(t.z); a[3] = bits2f(t.w);
}

// -------- fused fp32 -> bf16 convert of x + all weights, plus rbias table --------
// rbias (16 heads x 2048 deltas) folded into blocks 0..127: one fewer dispatch.
__global__ __launch_bounds__(256)
void cvt_all_kernel(const float* __restrict__ x,
                    const float* __restrict__ Wq, const float* __restrict__ Wk,
                    const float* __restrict__ Wv, const float* __restrict__ Wo,
                    const float* __restrict__ W1, const float* __restrict__ W2,
                    const float* __restrict__ rel_emb,
                    unsigned short* __restrict__ xb, unsigned short* __restrict__ Wqkvb,
                    unsigned short* __restrict__ Wob,
                    unsigned short* __restrict__ W1b, unsigned short* __restrict__ W2b,
                    unsigned short* __restrict__ rbias)
{
    int i = blockIdx.x * 256 + threadIdx.x;
    const float* src; unsigned short* dst; int off;
    if (i < (1 << 20))      { src = x;  dst = xb;  off = i; }
    else if (i < (2 << 20)) { src = W1; dst = W1b; off = i - (1 << 20); }
    else if (i < (3 << 20)) { src = W2; dst = W2b; off = i - (2 << 20); }
    else {
        int j = i - (3 << 20);
        int sel = j >> 18;
        off = j & ((1 << 18) - 1);
        src = sel == 0 ? Wq : sel == 1 ? Wk : sel == 2 ? Wv : Wo;
        dst = sel == 3 ? Wob : Wqkvb + ((size_t)sel << 20);
    }
    float4 v = ((const float4*)src)[off];
    ushort4 o = { f2b(v.x), f2b(v.y), f2b(v.z), f2b(v.w) };
    ((ushort4*)dst)[off] = o;

    if (blockIdx.x < 128) {
        int idx = blockIdx.x * 256 + threadIdx.x;   // 16 * 2048
        int h = idx >> 11, q = idx & 2047;
        int n = q - 1023, ret = 0;                  // n = j - i
        if (n < 0) { ret = 16; n = -n; }
        int b;
        if (n < 8) b = n;
        else {
            double t = log((double)n / 8.0) / log(16.0) * 8.0;
            int vv = 8 + (int)t;
            b = vv < 15 ? vv : 15;
        }
        rbias[idx] = f2b(rel_emb[(ret + b) * 16 + h]);
    }
}

// ============ 128x128 MFMA GEMM, BK=32 dbuf (verified R6/R8) — QKV / ff2 ============
template<typename TC, typename TR, int RELU, int QKV>
__global__ __launch_bounds__(256)
void mfma_gemm128(const unsigned short* __restrict__ A, int lda,
                  const unsigned short* __restrict__ W, int ldw,
                  const float* __restrict__ b0, const float* __restrict__ b1,
                  const float* __restrict__ b2,
                  const TR* __restrict__ res,
                  void* __restrict__ C0, void* __restrict__ C1, void* __restrict__ C2,
                  int ldc, int M, int N, int Ksplit)
{
    __shared__ unsigned short sm[4 * 128 * 32];   // 32KB: As[2] + Ws[2], [128][32] each
    const int tid = threadIdx.x;
    const int w = tid >> 6, lane = tid & 63;
    const int quad = lane >> 4, col = lane & 15;

    const int bid = blockIdx.x + gridDim.x * blockIdx.y;
    const int nwg = gridDim.x * gridDim.y;
    const int swz = (bid & 7) * (nwg >> 3) + (bid >> 3);
    const int m0 = (swz / gridDim.x) * 128;
    const int n0 = (swz % gridDim.x) * 128;

    const int wrow = (w & 1) * 64, wcol = (w >> 1) * 64;
    const int kz = blockIdx.z * Ksplit;
    const int NT = Ksplit >> 5;

    int sr0, sq0, sr1, sq1;
    {
        const int i0_ = tid;
        int sp = i0_ & 63, rl = ((sp >> 2) ^ (sp >> 4)) & 1;
        sr0 = ((i0_ >> 6) << 4) | ((sp >> 2) & 0xE) | rl;
        sq0 = (sp & 3) ^ ((((sp >> 3) & 1) << 1) | rl);
        const int i1_ = 256 + tid;
        sp = i1_ & 63; rl = ((sp >> 2) ^ (sp >> 4)) & 1;
        sr1 = ((i1_ >> 6) << 4) | ((sp >> 2) & 0xE) | rl;
        sq1 = (sp & 3) ^ ((((sp >> 3) & 1) << 1) | rl);
    }
    const unsigned off0 = (unsigned)__builtin_amdgcn_readfirstlane((unsigned)((0 * 256 + (tid & 192)) * 16));
    const unsigned off1 = (unsigned)__builtin_amdgcn_readfirstlane((unsigned)((1 * 256 + (tid & 192)) * 16));

#define STAGE32(buf, k0)                                                                     \
    {                                                                                        \
        unsigned short* As_ = sm + (buf) * 4096;                                             \
        unsigned short* Ws_ = sm + 8192 + (buf) * 4096;                                      \
        const unsigned short* ga0 = A + (size_t)(m0 + sr0) * lda + (k0) + sq0 * 8;           \
        __builtin_amdgcn_global_load_lds(                                                    \
            (const __attribute__((address_space(1))) unsigned int*)ga0,                      \
            (__attribute__((address_space(3))) unsigned int*)((char*)As_ + off0), 16, 0, 0); \
        const unsigned short* ga1 = A + (size_t)(m0 + sr1) * lda + (k0) + sq1 * 8;           \
        __builtin_amdgcn_global_load_lds(                                                    \
            (const __attribute__((address_space(1))) unsigned int*)ga1,                      \
            (__attribute__((address_space(3))) unsigned int*)((char*)As_ + off1), 16, 0, 0); \
        const unsigned short* gw0 = W + (size_t)(n0 + sr0) * ldw + (k0) + sq0 * 8;           \
        __builtin_amdgcn_global_load_lds(                                                    \
            (const __attribute__((address_space(1))) unsigned int*)gw0,                      \
            (__attribute__((address_space(3))) unsigned int*)((char*)Ws_ + off0), 16, 0, 0); \
        const unsigned short* gw1 = W + (size_t)(n0 + sr1) * ldw + (k0) + sq1 * 8;           \
        __builtin_amdgcn_global_load_lds(                                                    \
            (const __attribute__((address_space(1))) unsigned int*)gw1,                      \
            (__attribute__((address_space(3))) unsigned int*)((char*)Ws_ + off1), 16, 0, 0); \
    }

    f32x4 acc[4][4] = {};

    STAGE32(0, kz);

    for (int t = 0; t < NT; ++t) {
        __syncthreads();
        const int cur = t & 1;
        if (t + 1 < NT) STAGE32(cur ^ 1, kz + (t + 1) * 32);

        const unsigned short* As = sm + cur * 4096;
        const unsigned short* Ws = sm + 8192 + cur * 4096;
        s8v af[4], bfr[4];
        #pragma unroll
        for (int mt = 0; mt < 4; ++mt) {
            int rr = wrow + mt * 16 + col;
            af[mt] = *(const s8v*)(As + ((rr * 32 + ((quad ^ (rr & 3)) << 3)) ^ (((rr >> 2) & 1) << 5)));
        }
        #pragma unroll
        for (int nt = 0; nt < 4; ++nt) {
            int rr = wcol + nt * 16 + col;
            bfr[nt] = *(const s8v*)(Ws + ((rr * 32 + ((quad ^ (rr & 3)) << 3)) ^ (((rr >> 2) & 1) << 5)));
        }
        __builtin_amdgcn_s_setprio(1);
        #pragma unroll
        for (int mt = 0; mt < 4; ++mt)
            #pragma unroll
            for (int nt = 0; nt < 4; ++nt)
                acc[mt][nt] = __builtin_amdgcn_mfma_f32_16x16x32_bf16(af[mt], bfr[nt], acc[mt][nt], 0, 0, 0);
        __builtin_amdgcn_s_setprio(0);
    }
#undef STAGE32

    if (QKV) {
        const int sel = n0 >> 10;
        unsigned short* Cb = (unsigned short*)(sel == 0 ? C0 : sel == 1 ? C1 : C2);
        const float* bs = sel == 0 ? b0 : sel == 1 ? b1 : b2;
        #pragma unroll
        for (int mt = 0; mt < 4; ++mt)
            #pragma unroll
            for (int rg = 0; rg < 4; ++rg) {
                int gm = m0 + wrow + mt * 16 + quad * 4 + rg;
                #pragma unroll
                for (int nt = 0; nt < 4; ++nt) {
                    int gnc = (n0 + wcol + nt * 16 + col) & 1023;
                    Cb[(size_t)gm * 1024 + gnc] = f2b(acc[mt][nt][rg] + bs[gnc]);
                }
            }
    } else {
        void* Cv = blockIdx.z ? C1 : C0;
        const bool z0 = (blockIdx.z == 0);
        #pragma unroll
        for (int mt = 0; mt < 4; ++mt)
            #pragma unroll
            for (int rg = 0; rg < 4; ++rg) {
                int gm = m0 + wrow + mt * 16 + quad * 4 + rg;
                #pragma unroll
                for (int nt = 0; nt < 4; ++nt) {
                    int gn = n0 + wcol + nt * 16 + col;
                    float c = acc[mt][nt][rg];
                    if (z0) {
                        if (b0)  c += b0[gn];
                        if (res) c += to_f(res[(size_t)gm * ldc + gn]);
                    }
                    if (RELU) c = fmaxf(c, 0.f);
                    if (sizeof(TC) == 2) ((unsigned short*)Cv)[(size_t)gm * ldc + gn] = f2b(c);
                    else                 ((float*)Cv)[(size_t)gm * ldc + gn] = c;
                }
            }
    }
}

// ============ 128x64 MFMA GEMM, BK=32 dbuf (verified R10) — Wo only ============
template<typename TC, typename TR, int RELU>
__global__ __launch_bounds__(256)
void mfma_gemm64n(const unsigned short* __restrict__ A, int lda,
                  const unsigned short* __restrict__ W, int ldw,
                  const float* __restrict__ b0,
                  const TR* __restrict__ res,
                  void* __restrict__ C0, void* __restrict__ C1,
                  int ldc, int M, int N, int Ksplit)
{
    __shared__ unsigned short sm[2 * 4096 + 2 * 2048];   // 24KB: As[2][128][32], Ws[2][64][32]
    const int tid = threadIdx.x;
    const int w = tid >> 6, lane = tid & 63;
    const int quad = lane >> 4, col = lane & 15;

    const int bid = blockIdx.x + gridDim.x * blockIdx.y;
    const int nwg = gridDim.x * gridDim.y;
    const int swz = (bid & 7) * (nwg >> 3) + (bid >> 3);
    const int m0 = (swz / gridDim.x) * 128;
    const int n0 = (swz % gridDim.x) * 64;

    const int wrow = (w & 1) * 64, wcol = (w >> 1) * 32;
    const int kz = blockIdx.z * Ksplit;
    const int NT = Ksplit >> 5;

    int sr0, sq0, sr1, sq1;
    {
        const int i0_ = tid;
        int sp = i0_ & 63, rl = ((sp >> 2) ^ (sp >> 4)) & 1;
        sr0 = ((i0_ >> 6) << 4) | ((sp >> 2) & 0xE) | rl;
        sq0 = (sp & 3) ^ ((((sp >> 3) & 1) << 1) | rl);
        const int i1_ = 256 + tid;
        sp = i1_ & 63; rl = ((sp >> 2) ^ (sp >> 4)) & 1;
        sr1 = ((i1_ >> 6) << 4) | ((sp >> 2) & 0xE) | rl;
        sq1 = (sp & 3) ^ ((((sp >> 3) & 1) << 1) | rl);
    }
    const unsigned off0 = (unsigned)__builtin_amdgcn_readfirstlane((unsigned)((tid & 192) * 16));
    const unsigned off1 = (unsigned)__builtin_amdgcn_readfirstlane((unsigned)((256 + (tid & 192)) * 16));

#define STAGE64N(buf, k0)                                                                    \
    {                                                                                        \
        unsigned short* As_ = sm + (buf) * 4096;                                             \
        unsigned short* Ws_ = sm + 8192 + (buf) * 2048;                                      \
        const unsigned short* ga0 = A + (size_t)(m0 + sr0) * lda + (k0) + sq0 * 8;           \
        __builtin_amdgcn_global_load_lds(                                                    \
            (const __attribute__((address_space(1))) unsigned int*)ga0,                      \
            (__attribute__((address_space(3))) unsigned int*)((char*)As_ + off0), 16, 0, 0); \
        const unsigned short* ga1 = A + (size_t)(m0 + sr1) * lda + (k0) + sq1 * 8;           \
        __builtin_amdgcn_global_load_lds(                                                    \
            (const __attribute__((address_space(1))) unsigned int*)ga1,                      \
            (__attribute__((address_space(3))) unsigned int*)((char*)As_ + off1), 16, 0, 0); \
        const unsigned short* gw0 = W + (size_t)(n0 + sr0) * ldw + (k0) + sq0 * 8;           \
        __builtin_amdgcn_global_load_lds(                                                    \
            (const __attribute__((address_space(1))) unsigned int*)gw0,                      \
            (__attribute__((address_space(3))) unsigned int*)((char*)Ws_ + off0), 16, 0, 0); \
    }

    f32x4 acc[4][2] = {};

    STAGE64N(0, kz);

    for (int t = 0; t < NT; ++t) {
        __syncthreads();
        const int cur = t & 1;
        if (t + 1 < NT) STAGE64N(cur ^ 1, kz + (t + 1) * 32);

        const unsigned short* As = sm + cur * 4096;
        const unsigned short* Ws = sm + 8192 + cur * 2048;
        s8v af[4], bfr[2];
        #pragma unroll
        for (int mt = 0; mt < 4; ++mt) {
            int rr = wrow + mt * 16 + col;
            af[mt] = *(const s8v*)(As + ((rr * 32 + ((quad ^ (rr & 3)) << 3)) ^ (((rr >> 2) & 1) << 5)));
        }
        #pragma unroll
        for (int nt = 0; nt < 2; ++nt) {
            int rr = wcol + nt * 16 + col;
            bfr[nt] = *(const s8v*)(Ws + ((rr * 32 + ((quad ^ (rr & 3)) << 3)) ^ (((rr >> 2) & 1) << 5)));
        }
        __builtin_amdgcn_s_setprio(1);
        #pragma unroll
        for (int mt = 0; mt < 4; ++mt)
            #pragma unroll
            for (int nt = 0; nt < 2; ++nt)
                acc[mt][nt] = __builtin_amdgcn_mfma_f32_16x16x32_bf16(af[mt], bfr[nt], acc[mt][nt], 0, 0, 0);
        __builtin_amdgcn_s_setprio(0);
    }
#undef STAGE64N

    void* Cv = blockIdx.z ? C1 : C0;
    const bool z0 = (blockIdx.z == 0);
    #pragma unroll
    for (int mt = 0; mt < 4; ++mt)
        #pragma unroll
        for (int rg = 0; rg < 4; ++rg) {
            int gm = m0 + wrow + mt * 16 + quad * 4 + rg;
            #pragma unroll
            for (int nt = 0; nt < 2; ++nt) {
                int gn = n0 + wcol + nt * 16 + col;
                float c = acc[mt][nt][rg];
                if (z0) {
                    if (b0)  c += b0[gn];
                    if (res) c += to_f(res[(size_t)gm * ldc + gn]);
                }
                if (RELU) c = fmaxf(c, 0.f);
                if (sizeof(TC) == 2) ((unsigned short*)Cv)[(size_t)gm * ldc + gn] = f2b(c);
                else                 ((float*)Cv)[(size_t)gm * ldc + gn] = c;
            }
        }
}

// ============ 256x128 MFMA GEMM, 8 waves, BK=32 dbuf (verified R7) — ff1 ============
template<typename TC, typename TR, int RELU, int QKV>
__global__ __launch_bounds__(512)
void mfma_gemm256(const unsigned short* __restrict__ A, int lda,
                  const unsigned short* __restrict__ W, int ldw,
                  const float* __restrict__ b0, const float* __restrict__ b1,
                  const float* __restrict__ b2,
                  const TR* __restrict__ res,
                  void* __restrict__ C0, void* __restrict__ C1, void* __restrict__ C2,
                  int ldc, int M, int N, int Ksplit)
{
    __shared__ unsigned short sm[2 * 8192 + 2 * 4096];   // 48KB: A dbuf [2][256][32], W dbuf [2][128][32]
    const int tid = threadIdx.x;
    const int w = tid >> 6, lane = tid & 63;
    const int quad = lane >> 4, col = lane & 15;

    const int bid = blockIdx.x + gridDim.x * blockIdx.y;
    const int xcd = bid & 7, j = bid >> 3;
    const int rh = gridDim.y >> 1, cw = gridDim.x >> 2;
    const int m0 = (((xcd & 1) * rh) + (j % rh)) * 256;
    const int n0 = (((xcd >> 1) * cw) + (j / rh)) * 128;

    const int wrow = (w & 3) * 64, wcol = (w >> 2) * 64;
    const int kz = blockIdx.z * Ksplit;
    const int NT = Ksplit >> 5;

    int sr0, sq0, sr1, sq1, sr2, sq2;
    {
        int idx = tid;
        int sp = idx & 63, rl = ((sp >> 2) ^ (sp >> 4)) & 1;
        sr0 = ((idx >> 6) << 4) | ((sp >> 2) & 0xE) | rl;
        sq0 = (sp & 3) ^ ((((sp >> 3) & 1) << 1) | rl);
        idx = 512 + tid;
        sp = idx & 63; rl = ((sp >> 2) ^ (sp >> 4)) & 1;
        sr1 = ((idx >> 6) << 4) | ((sp >> 2) & 0xE) | rl;
        sq1 = (sp & 3) ^ ((((sp >> 3) & 1) << 1) | rl);
        sr2 = sr0; sq2 = sq0;
    }
    const unsigned offA0 = (unsigned)__builtin_amdgcn_readfirstlane((unsigned)((tid & 448) * 16));
    const unsigned offA1 = (unsigned)__builtin_amdgcn_readfirstlane((unsigned)((512 + (tid & 448)) * 16));
    const unsigned offW0 = offA0;

#define STAGE(buf, k0)                                                                       \
    {                                                                                        \
        unsigned short* As_ = sm + (buf) * 8192;                                             \
        unsigned short* Ws_ = sm + 16384 + (buf) * 4096;                                     \
        const unsigned short* ga0 = A + (size_t)(m0 + sr0) * lda + (k0) + sq0 * 8;           \
        __builtin_amdgcn_global_load_lds(                                                    \
            (const __attribute__((address_space(1))) unsigned int*)ga0,                      \
            (__attribute__((address_space(3))) unsigned int*)((char*)As_ + offA0), 16, 0, 0);\
        const unsigned short* ga1 = A + (size_t)(m0 + sr1) * lda + (k0) + sq1 * 8;           \
        __builtin_amdgcn_global_load_lds(                                                    \
            (const __attribute__((address_space(1))) unsigned int*)ga1,                      \
            (__attribute__((address_space(3))) unsigned int*)((char*)As_ + offA1), 16, 0, 0);\
        const unsigned short* gw0 = W + (size_t)(n0 + sr2) * ldw + (k0) + sq2 * 8;           \
        __builtin_amdgcn_global_load_lds(                                                    \
            (const __attribute__((address_space(1))) unsigned int*)gw0,                      \
            (__attribute__((address_space(3))) unsigned int*)((char*)Ws_ + offW0), 16, 0, 0);\
    }

    f32x4 acc[4][4] = {};

    STAGE(0, kz);

    for (int t = 0; t < NT; ++t) {
        __syncthreads();
        const int cur = t & 1;
        if (t + 1 < NT) STAGE(cur ^ 1, kz + (t + 1) * 32);

        const unsigned short* As = sm + cur * 8192;
        const unsigned short* Ws = sm + 16384 + cur * 4096;
        s8v af[4], bfr[4];
        #pragma unroll
        for (int mt = 0; mt < 4; ++mt) {
            int rr = wrow + mt * 16 + col;
            af[mt] = *(const s8v*)(As + ((rr * 32 + ((quad ^ (rr & 3)) << 3)) ^ (((rr >> 2) & 1) << 5)));
        }
        #pragma unroll
        for (int nt = 0; nt < 4; ++nt) {
            int rr = wcol + nt * 16 + col;
            bfr[nt] = *(const s8v*)(Ws + ((rr * 32 + ((quad ^ (rr & 3)) << 3)) ^ (((rr >> 2) & 1) << 5)));
        }
        __builtin_amdgcn_s_setprio(1);
        #pragma unroll
        for (int mt = 0; mt < 4; ++mt)
            #pragma unroll
            for (int nt = 0; nt < 4; ++nt)
                acc[mt][nt] = __builtin_amdgcn_mfma_f32_16x16x32_bf16(af[mt], bfr[nt], acc[mt][nt], 0, 0, 0);
        __builtin_amdgcn_s_setprio(0);
    }
#undef STAGE

    if (QKV) {
        const int sel = n0 >> 10;
        unsigned short* Cb = (unsigned short*)(sel == 0 ? C0 : sel == 1 ? C1 : C2);
        const float* bs = sel == 0 ? b0 : sel == 1 ? b1 : b2;
        #pragma unroll
        for (int mt = 0; mt < 4; ++mt)
            #pragma unroll
            for (int rg = 0; rg < 4; ++rg) {
                int gm = m0 + wrow + mt * 16 + quad * 4 + rg;
                #pragma unroll
                for (int nt = 0; nt < 4; ++nt) {
                    int gnc = (n0 + wcol + nt * 16 + col) & 1023;
                    Cb[(size_t)gm * 1024 + gnc] = f2b(acc[mt][nt][rg] + bs[gnc]);
                }
            }
    } else {
        void* Cv = blockIdx.z ? C1 : C0;
        const bool z0 = (blockIdx.z == 0);
        #pragma unroll
        for (int mt = 0; mt < 4; ++mt)
            #pragma unroll
            for (int rg = 0; rg < 4; ++rg) {
                int gm = m0 + wrow + mt * 16 + quad * 4 + rg;
                #pragma unroll
                for (int nt = 0; nt < 4; ++nt) {
                    int gn = n0 + wcol + nt * 16 + col;
                    float c = acc[mt][nt][rg];
                    if (z0) {
                        if (b0)  c += b0[gn];
                        if (res) c += to_f(res[(size_t)gm * ldc + gn]);
                    }
                    if (RELU) c = fmaxf(c, 0.f);
                    if (sizeof(TC) == 2) ((unsigned short*)Cv)[(size_t)gm * ldc + gn] = f2b(c);
                    else                 ((float*)Cv)[(size_t)gm * ldc + gn] = c;
                }
            }
    }
}

// ---------------- V transpose: vb bf16 [4096][1024] -> vt bf16 [bp][d][j] ----------------
__global__ __launch_bounds__(256)
void vtrans_kernel(const unsigned short* __restrict__ v, unsigned short* __restrict__ vt)
{
    __shared__ unsigned short t[64][68];
    const int bpmm = blockIdx.x;
    const int bp = bpmm >> 6, mm = bpmm & 63;
    const unsigned short* vr = v + (size_t)(bp * 64 + mm) * 1024;
    const int tid = threadIdx.x;
    #pragma unroll
    for (int it = 0; it < 4; ++it) {
        int c = (tid >> 6) + it * 4;
        int d = tid & 63;
        t[d][c] = vr[c * 64 + d];
    }
    __syncthreads();
    int d = tid >> 2, qq = tid & 3;
    ushort4 o = { t[d][qq * 4 + 0], t[d][qq * 4 + 1], t[d][qq * 4 + 2], t[d][qq * 4 + 3] };
    *(ushort4*)(vt + (size_t)bp * 65536 + (size_t)d * 1024 + mm * 16 + qq * 4) = o;
}

// ---------------- MFMA attention v4: Q-frag hoist + setprio (R12) ----------------
__global__ __launch_bounds__(256, 2)
void attn_mfma_kernel(const unsigned short* __restrict__ qb,
                      const unsigned short* __restrict__ kb,
                      const unsigned short* __restrict__ vt,
                      const unsigned short* __restrict__ rbias,
                      const int* __restrict__ pmask,
                      unsigned short* __restrict__ att)
{
    __shared__ unsigned short Qs[128 * 64];
    __shared__ unsigned short KP[128 * 64];
    __shared__ unsigned short Vt[64 * 128];
    __shared__ unsigned short rbs[2048];
    __shared__ unsigned short pmls[1024];

    const int tid = threadIdx.x;
    const int w = tid >> 6, lane = tid & 63;
    const int quad = lane >> 4, col = lane & 15;
    const int bp = blockIdx.x, i0 = blockIdx.y * 128;
    const int h = bp & 15, bb = bp >> 4;
    const size_t base = (size_t)bp << 16;
    const int myrow0 = w * 32, myrow1 = w * 32 + 16;

    {
        const unsigned short* qg = qb + base + (size_t)i0 * 64;
        #pragma unroll
        for (int it = 0; it < 4; ++it) {
            int idx = it * 256 + tid;
            int r = idx >> 3, c = idx & 7;
            s8v d = *(const s8v*)(qg + (size_t)r * 64 + (c ^ (r & 7)) * 8);
            *(s8v*)(Qs + r * 64 + c * 8) = d;
        }
    }
    {
        const unsigned short* rg = rbias + h * 2048;
        #pragma unroll
        for (int it = 0; it < 8; ++it) rbs[it * 256 + tid] = rg[it * 256 + tid];
    }
    #pragma unroll
    for (int it = 0; it < 4; ++it) {
        int j = it * 256 + tid;
        pmls[j] = f2b(__logf((float)pmask[bb * 1024 + j]));
    }

    // Q fragments are loop-invariant: hoist out of the K/V-tile loop (saves
    // 4 ds_read_b128/thread/jt). One extra barrier to make Qs visible.
    __syncthreads();
    s8v qa0[2], qa1[2];
    {
        const int ar0 = myrow0 + col, ar1 = myrow1 + col;
        #pragma unroll
        for (int ks = 0; ks < 2; ++ks) {
            qa0[ks] = *(const s8v*)(Qs + ar0 * 64 + (((ks * 4 + quad) ^ (ar0 & 7)) * 8));
            qa1[ks] = *(const s8v*)(Qs + ar1 * 64 + (((ks * 4 + quad) ^ (ar1 & 7)) * 8));
        }
    }

    f32x4 O0[4] = {}, O1[4] = {};
    float lrow0[4] = {0.f, 0.f, 0.f, 0.f};
    float lrow1[4] = {0.f, 0.f, 0.f, 0.f};

    unsigned short* Pw = KP + w * 2048;

    for (int jt = 0; jt < 8; ++jt) {
        const int j0 = jt * 128;
        __syncthreads();
        {
            const unsigned short* kg = kb + base + (size_t)j0 * 64;
            #pragma unroll
            for (int it = 0; it < 4; ++it) {
                int idx = it * 256 + tid;
                int r = idx >> 3, c = idx & 7;
                s8v d = *(const s8v*)(kg + (size_t)r * 64 + (c ^ (r & 7)) * 8);
                *(s8v*)(KP + r * 64 + c * 8) = d;
            }
            const unsigned short* vg = vt + base + j0;
            #pragma unroll
            for (int it = 0; it < 4; ++it) {
                int idx = it * 256 + tid;
                int r = idx >> 4, c = idx & 15;
                s8v d = *(const s8v*)(vg + (size_t)r * 1024 + (c ^ (r & 15)) * 8);
                *(s8v*)(Vt + r * 128 + c * 8) = d;
            }
        }
        __syncthreads();

        f32x4 S0[8] = {}, S1[8] = {};
        #pragma unroll
        for (int ks = 0; ks < 2; ++ks) {
            __builtin_amdgcn_s_setprio(1);
            #pragma unroll
            for (int ct = 0; ct < 8; ++ct) {
                int br = ct * 16 + col;
                s8v b = *(const s8v*)(KP + br * 64 + (((ks * 4 + quad) ^ (br & 7)) * 8));
                S0[ct] = __builtin_amdgcn_mfma_f32_16x16x32_bf16(qa0[ks], b, S0[ct], 0, 0, 0);
                S1[ct] = __builtin_amdgcn_mfma_f32_16x16x32_bf16(qa1[ks], b, S1[ct], 0, 0, 0);
            }
            __builtin_amdgcn_s_setprio(0);
        }

        #pragma unroll
        for (int ct = 0; ct < 8; ++ct) {
            int gj = j0 + ct * 16 + col;
            float pmv = bits2f(pmls[gj]);
            int d0 = gj - (i0 + myrow0 + quad * 4) + 1023;
            int d1 = gj - (i0 + myrow1 + quad * 4) + 1023;
            #pragma unroll
            for (int r = 0; r < 4; ++r) {
                float e0 = __expf(S0[ct][r] + bits2f(rbs[d0 - r]) + pmv);
                float e1 = __expf(S1[ct][r] + bits2f(rbs[d1 - r]) + pmv);
                S0[ct][r] = e0; lrow0[r] += e0;
                S1[ct][r] = e1; lrow1[r] += e1;
            }
        }

        __syncthreads();

        #pragma unroll
        for (int ct = 0; ct < 8; ++ct)
            #pragma unroll
            for (int r = 0; r < 4; ++r) {
                int lr = quad * 4 + r;
                int j = ct * 16 + col;
                Pw[lr * 128 + (((j >> 3) ^ lr) << 3) + (j & 7)] = f2b(S0[ct][r]);
            }
        #pragma unroll
        for (int kt = 0; kt < 4; ++kt) {
            int pr = col;
            s8v a = *(const s8v*)(Pw + pr * 128 + (((kt * 4 + quad) ^ pr) * 8));
            __builtin_amdgcn_s_setprio(1);
            #pragma unroll
            for (int nt = 0; nt < 4; ++nt) {
                int vr = nt * 16 + col;
                s8v b = *(const s8v*)(Vt + vr * 128 + (((kt * 4 + quad) ^ (vr & 15)) * 8));
                O0[nt] = __builtin_amdgcn_mfma_f32_16x16x32_bf16(a, b, O0[nt], 0, 0, 0);
            }
            __builtin_amdgcn_s_setprio(0);
        }

        #pragma unroll
        for (int ct = 0; ct < 8; ++ct)
            #pragma unroll
            for (int r = 0; r < 4; ++r) {
                int lr = quad * 4 + r;
                int j = ct * 16 + col;
                Pw[lr * 128 + (((j >> 3) ^ lr) << 3) + (j & 7)] = f2b(S1[ct][r]);
            }
        #pragma unroll
        for (int kt = 0; kt < 4; ++kt) {
            int pr = col;
            s8v a = *(const s8v*)(Pw + pr * 128 + (((kt * 4 + quad) ^ pr) * 8));
            __builtin_amdgcn_s_setprio(1);
            #pragma unroll
            for (int nt = 0; nt < 4; ++nt) {
                int vr = nt * 16 + col;
                s8v b = *(const s8v*)(Vt + vr * 128 + (((kt * 4 + quad) ^ (vr & 15)) * 8));
                O1[nt] = __builtin_amdgcn_mfma_f32_16x16x32_bf16(a, b, O1[nt], 0, 0, 0);
            }
            __builtin_amdgcn_s_setprio(0);
        }
    }

    #pragma unroll
    for (int off = 1; off < 16; off <<= 1)
        #pragma unroll
        for (int r = 0; r < 4; ++r) {
            lrow0[r] += __shfl_xor(lrow0[r], off);
            lrow1[r] += __shfl_xor(lrow1[r], off);
        }
    #pragma unroll
    for (int r = 0; r < 4; ++r) {
        lrow0[r] = 1.f / lrow0[r];
        lrow1[r] = 1.f / lrow1[r];
    }

    unsigned short* ag0 = att + base + (size_t)(i0 + myrow0) * 64;
    unsigned short* ag1 = att + base + (size_t)(i0 + myrow1) * 64;
    #pragma unroll
    for (int nt = 0; nt < 4; ++nt)
        #pragma unroll
        for (int r = 0; r < 4; ++r) {
            ag0[(size_t)(quad * 4 + r) * 64 + nt * 16 + col] = f2b(O0[nt][r] * lrow0[r]);
            ag1[(size_t)(quad * 4 + r) * 64 + nt * 16 + col] = f2b(O1[nt][r] * lrow1[r]);
        }
}

// ---------------- layernorm over rows of 1024: in1+in2 -> (outF fp32, outB bf16) ----------------
template<typename TIN>
__global__ __launch_bounds__(256)
void ln_kernel(const TIN* __restrict__ in1, const TIN* __restrict__ in2,
               float* __restrict__ outF, unsigned short* __restrict__ outB)
{
    __shared__ float sred[8];
    const int row = blockIdx.x;
    const int tid = threadIdx.x;
    const size_t off = (size_t)row * 1024 + tid * 4;
    float a[4];
    load4(in1 + off, a);
    if (in2) {
        float b[4];
        load4(in2 + off, b);
        #pragma unroll
        for (int i = 0; i < 4; ++i) a[i] += b[i];
    }

    float lsum = a[0] + a[1] + a[2] + a[3];
    #pragma unroll
    for (int o = 32; o; o >>= 1) lsum += __shfl_down(lsum, o);
    const int lane = tid & 63, wid = tid >> 6;
    if (lane == 0) sred[wid] = lsum;
    __syncthreads();
    if (tid == 0) sred[4] = (sred[0] + sred[1] + sred[2] + sred[3]) * (1.f / 1024.f);
    __syncthreads();
    const float mean = sred[4];

    float d0 = a[0] - mean, d1 = a[1] - mean, d2 = a[2] - mean, d3 = a[3] - mean;
    float lsq = d0 * d0 + d1 * d1 + d2 * d2 + d3 * d3;
    #pragma unroll
    for (int o = 32; o; o >>= 1) lsq += __shfl_down(lsq, o);
    __syncthreads();
    if (lane == 0) sred[wid] = lsq;
    __syncthreads();
    if (tid == 0) sred[5] = rsqrtf((sred[0] + sred[1] + sred[2] + sred[3]) * (1.f / 1024.f));
    __syncthreads();
    const float r = sred[5];

    float o0 = d0 * r, o1 = d1 * r, o2 = d2 * r, o3 = d3 * r;
    if (outF) {
        float4 o = {o0, o1, o2, o3};
        *(float4*)&outF[off] = o;
    }
    if (outB) {
        ushort4 o = { f2b(o0), f2b(o1), f2b(o2), f2b(o3) };
        *(ushort4*)&outB[off] = o;
    }
}

extern "C" void kernel_launch(void* const* d_in, const int* in_sizes, int n_in,
                              void* d_out, int out_size, void* d_ws, size_t ws_size,
                              hipStream_t stream)
{
    const float* x     = (const float*)d_in[0];
    const int*   pmask = (const int*)  d_in[1];
    const float* Wq    = (const float*)d_in[2];
    const float* bq    = (const float*)d_in[3];
    const float* Wk    = (const float*)d_in[4];
    const float* bk    = (const float*)d_in[5];
    const float* Wv    = (const float*)d_in[6];
    const float* bv    = (const float*)d_in[7];
    const float* Wo    = (const float*)d_in[8];
    const float* bo    = (const float*)d_in[9];
    const float* rel   = (const float*)d_in[10];
    const float* W1    = (const float*)d_in[11];
    const float* b1    = (const float*)d_in[12];
    const float* W2    = (const float*)d_in[13];
    const float* b2    = (const float*)d_in[14];

    const int M = 4096, D = 1024;
    dim3 blk(256);
    dim3 gblk(512);

    // ---- workspace map (identical to round-7/8-proven; peak write 64MB+64KB) ----
    char* ws = (char*)d_ws;
    unsigned short* W1b   = (unsigned short*)(ws);                 // 0-8
    unsigned short* W2b   = (unsigned short*)(ws + ( 8u << 20));   // 8-16
    unsigned short* xb    = (unsigned short*)(ws + (16u << 20));   // 16-24
    unsigned short* Wqkvb = (unsigned short*)(ws + (24u << 20));   // 24-30
    unsigned short* Wob   = (unsigned short*)(ws + (30u << 20));   // 30-32
    unsigned short* qb    = (unsigned short*)(ws + (32u << 20));   // 32-40
    unsigned short* kb    = (unsigned short*)(ws + (40u << 20));   // 40-48
    unsigned short* vb    = (unsigned short*)(ws + (48u << 20));   // 48-56
    unsigned short* vt    = (unsigned short*)(ws + (56u << 20));   // 56-64
    unsigned short* rbias = (unsigned short*)(ws + (64u << 20));   // 64-64.0625
    float*          tmpA    = (float*)(ws + (32u << 20));          // 32-48 (qb/kb dead after attn)
    float*          tmpB    = (float*)(ws + (48u << 20));          // 48-64 (vb/vt dead after attn)
    unsigned short* attoutB = (unsigned short*)(ws + (16u << 20)); // 16-24 (xb dead after qkv)
    unsigned short* ff1     = (unsigned short*)(ws + (32u << 20)); // 32-64 (tmpA/B dead after ln1)
    unsigned short* ff2a    = (unsigned short*)(ws);               // 0-8   (W1b dead after ff1)
    unsigned short* ff2b    = (unsigned short*)(ws + (24u << 20)); // 24-32 (Wqkvb/Wob dead)
    unsigned short* attb    = (unsigned short*)d_out;              // d_out scratch (proven)

    // ---- conversions + rbias table (merged, one dispatch) ----
    cvt_all_kernel<<<16384, blk, 0, stream>>>(x, Wq, Wk, Wv, Wo, W1, W2, rel,
                                              xb, Wqkvb, Wob, W1b, W2b, rbias);

    // ---- fused QKV projection: 128² kernel (768 blocks = 3/CU) ----
    mfma_gemm128<unsigned short, float, 0, 1><<<dim3(24, 32), blk, 0, stream>>>(
        xb, D, Wqkvb, D, bq, bk, bv, (const float*)nullptr, qb, kb, vb, D, M, 3072, D);

    vtrans_kernel<<<4096, blk, 0, stream>>>(vb, vt);

    // ---- attention v4: Q-hoist + setprio ----
    attn_mfma_kernel<<<dim3(64, 8), blk, 0, stream>>>(qb, kb, vt, rbias, pmask, attb);

    // ---- Wo projection + residual x: 128x64 tile split-K z=2 (1024 blocks = 4/CU); LN1 ----
    mfma_gemm64n<float, float, 0><<<dim3(16, 32, 2), blk, 0, stream>>>(
        attb, D, Wob, D, bo, x, tmpA, tmpB, D, M, D, 512);
    ln_kernel<float><<<4096, blk, 0, stream>>>(tmpA, tmpB, nullptr, attoutB);

    // ---- FFN: ff1 256-tile (512 = 2/CU even); ff2 128² split-K z=2 (512 = 2/CU); LN2 ----
    mfma_gemm256<unsigned short, float, 1, 0><<<dim3(32, 16), gblk, 0, stream>>>(
        attoutB, D, W1b, D, b1, nullptr, nullptr, (const float*)nullptr,
        ff1, nullptr, nullptr, 4096, M, 4096, D);
    mfma_gemm128<unsigned short, unsigned short, 0, 0><<<dim3(8, 32, 2), blk, 0, stream>>>(
        ff1, 4096, W2b, 4096, b2, nullptr, nullptr, attoutB, ff2a, ff2b, nullptr, D, M, D, 2048);
    ln_kernel<unsigned short><<<4096, blk, 0, stream>>>(ff2a, ff2b, (float*)d_out, nullptr);
}

// Round 13
// 370.659 us; speedup vs baseline: 1.1015x; 1.0123x over previous
//
#include <hip/hip_runtime.h>
#include <hip/hip_bf16.h>

typedef __hip_bfloat16 bf16;
typedef __attribute__((ext_vector_type(8))) short s8v;      // 8 bf16 (4 VGPRs) MFMA A/B frag
typedef __attribute__((ext_vector_type(4))) float f32x4;    // MFMA C/D frag

__device__ __forceinline__ float bits2f(unsigned short u) {
    return __uint_as_float(((unsigned)u) << 16);
}
__device__ __forceinline__ unsigned short f2b(float f) {   // fp32 -> bf16 RNE
    union { float f; unsigned u; } x{f};
    return (unsigned short)((x.u + 0x7fff + ((x.u >> 16) & 1)) >> 16);
}
__device__ __forceinline__ float to_f(float x) { return x; }
__device__ __forceinline__ float to_f(unsigned short x) { return bits2f(x); }

__device__ __forceinline__ void load4(const float* p, float* a) {
    float4 t = *(const float4*)p;
    a[0] = t.x; a[1] = t.y; a[2] = t.z; a[3] = t.w;
}
__device__ __forceinline__ void load4(const unsigned short* p, float* a) {
    ushort4 t = *(const ushort4*)p;
    a[0] = bits2f(t.x); a[1] = bits2f(t.y); a[2] = bits2f(t.z); a[3] = bits2f(t.w);
}

// -------- fused fp32 -> bf16 convert of x + all weights, plus rbias table --------
__global__ __launch_bounds__(256)
void cvt_all_kernel(const float* __restrict__ x,
                    const float* __restrict__ Wq, const float* __restrict__ Wk,
                    const float* __restrict__ Wv, const float* __restrict__ Wo,
                    const float* __restrict__ W1, const float* __restrict__ W2,
                    const float* __restrict__ rel_emb,
                    unsigned short* __restrict__ xb, unsigned short* __restrict__ Wqkvb,
                    unsigned short* __restrict__ Wob,
                    unsigned short* __restrict__ W1b, unsigned short* __restrict__ W2b,
                    unsigned short* __restrict__ rbias)
{
    int i = blockIdx.x * 256 + threadIdx.x;
    const float* src; unsigned short* dst; int off;
    if (i < (1 << 20))      { src = x;  dst = xb;  off = i; }
    else if (i < (2 << 20)) { src = W1; dst = W1b; off = i - (1 << 20); }
    else if (i < (3 << 20)) { src = W2; dst = W2b; off = i - (2 << 20); }
    else {
        int j = i - (3 << 20);
        int sel = j >> 18;
        off = j & ((1 << 18) - 1);
        src = sel == 0 ? Wq : sel == 1 ? Wk : sel == 2 ? Wv : Wo;
        dst = sel == 3 ? Wob : Wqkvb + ((size_t)sel << 20);
    }
    float4 v = ((const float4*)src)[off];
    ushort4 o = { f2b(v.x), f2b(v.y), f2b(v.z), f2b(v.w) };
    ((ushort4*)dst)[off] = o;

    if (blockIdx.x < 128) {
        int idx = blockIdx.x * 256 + threadIdx.x;   // 16 * 2048
        int h = idx >> 11, q = idx & 2047;
        int n = q - 1023, ret = 0;                  // n = j - i
        if (n < 0) { ret = 16; n = -n; }
        int b;
        if (n < 8) b = n;
        else {
            double t = log((double)n / 8.0) / log(16.0) * 8.0;
            int vv = 8 + (int)t;
            b = vv < 15 ? vv : 15;
        }
        rbias[idx] = f2b(rel_emb[(ret + b) * 16 + h]);
    }
}

// ====== 128x128 MFMA GEMM, BK=32, TRIPLE-buffer depth-2 counted vmcnt (R13) ======
// vs R11 dbuf (__syncthreads full drain each phase): raw s_barrier + vmcnt(4) —
// tile t+1's 4 loads stay in flight ACROSS the barrier; only tile t is waited.
// Stage t+2 goes into the buffer read two phases ago (readers' lgkm retired
// before the previous barrier). LDS 48KB: ff2 stays 2/CU (grid-limited),
// QKV 3/CU (144KB <= 160). Everything else identical to the verified kernel.
template<typename TC, typename TR, int RELU, int QKV>
__global__ __launch_bounds__(256)
void mfma_gemm128(const unsigned short* __restrict__ A, int lda,
                  const unsigned short* __restrict__ W, int ldw,
                  const float* __restrict__ b0, const float* __restrict__ b1,
                  const float* __restrict__ b2,
                  const TR* __restrict__ res,
                  void* __restrict__ C0, void* __restrict__ C1, void* __restrict__ C2,
                  int ldc, int M, int N, int Ksplit)
{
    __shared__ unsigned short sm[6 * 128 * 32];   // 48KB: As[3] + Ws[3], [128][32] each
    const int tid = threadIdx.x;
    const int w = tid >> 6, lane = tid & 63;
    const int quad = lane >> 4, col = lane & 15;

    const int bid = blockIdx.x + gridDim.x * blockIdx.y;
    const int nwg = gridDim.x * gridDim.y;
    const int swz = (bid & 7) * (nwg >> 3) + (bid >> 3);
    const int m0 = (swz / gridDim.x) * 128;
    const int n0 = (swz % gridDim.x) * 128;

    const int wrow = (w & 1) * 64, wcol = (w >> 1) * 64;
    const int kz = blockIdx.z * Ksplit;
    const int NT = Ksplit >> 5;

    int sr0, sq0, sr1, sq1;
    {
        const int i0_ = tid;
        int sp = i0_ & 63, rl = ((sp >> 2) ^ (sp >> 4)) & 1;
        sr0 = ((i0_ >> 6) << 4) | ((sp >> 2) & 0xE) | rl;
        sq0 = (sp & 3) ^ ((((sp >> 3) & 1) << 1) | rl);
        const int i1_ = 256 + tid;
        sp = i1_ & 63; rl = ((sp >> 2) ^ (sp >> 4)) & 1;
        sr1 = ((i1_ >> 6) << 4) | ((sp >> 2) & 0xE) | rl;
        sq1 = (sp & 3) ^ ((((sp >> 3) & 1) << 1) | rl);
    }
    const unsigned off0 = (unsigned)__builtin_amdgcn_readfirstlane((unsigned)((0 * 256 + (tid & 192)) * 16));
    const unsigned off1 = (unsigned)__builtin_amdgcn_readfirstlane((unsigned)((1 * 256 + (tid & 192)) * 16));

#define STAGE32(buf, k0)                                                                     \
    {                                                                                        \
        unsigned short* As_ = sm + (buf) * 4096;                                             \
        unsigned short* Ws_ = sm + 12288 + (buf) * 4096;                                     \
        const unsigned short* ga0 = A + (size_t)(m0 + sr0) * lda + (k0) + sq0 * 8;           \
        __builtin_amdgcn_global_load_lds(                                                    \
            (const __attribute__((address_space(1))) unsigned int*)ga0,                      \
            (__attribute__((address_space(3))) unsigned int*)((char*)As_ + off0), 16, 0, 0); \
        const unsigned short* ga1 = A + (size_t)(m0 + sr1) * lda + (k0) + sq1 * 8;           \
        __builtin_amdgcn_global_load_lds(                                                    \
            (const __attribute__((address_space(1))) unsigned int*)ga1,                      \
            (__attribute__((address_space(3))) unsigned int*)((char*)As_ + off1), 16, 0, 0); \
        const unsigned short* gw0 = W + (size_t)(n0 + sr0) * ldw + (k0) + sq0 * 8;           \
        __builtin_amdgcn_global_load_lds(                                                    \
            (const __attribute__((address_space(1))) unsigned int*)gw0,                      \
            (__attribute__((address_space(3))) unsigned int*)((char*)Ws_ + off0), 16, 0, 0); \
        const unsigned short* gw1 = W + (size_t)(n0 + sr1) * ldw + (k0) + sq1 * 8;           \
        __builtin_amdgcn_global_load_lds(                                                    \
            (const __attribute__((address_space(1))) unsigned int*)gw1,                      \
            (__attribute__((address_space(3))) unsigned int*)((char*)Ws_ + off1), 16, 0, 0); \
    }

    f32x4 acc[4][4] = {};

    STAGE32(0, kz);                          // tile 0
    if (NT > 1) STAGE32(1, kz + 32);         // tile 1

    for (int t = 0; t < NT; ++t) {
        // counted wait: tile t retired; tile t+1's 4 loads stay in flight.
        if (t + 1 < NT) { asm volatile("s_waitcnt vmcnt(4)" ::: "memory"); }
        else            { asm volatile("s_waitcnt vmcnt(0)" ::: "memory"); }
        __builtin_amdgcn_s_barrier();

        const int cur = t % 3;
        if (t + 2 < NT) STAGE32((t + 2) % 3, kz + (t + 2) * 32);   // into buf read 2 phases ago

        const unsigned short* As = sm + cur * 4096;
        const unsigned short* Ws = sm + 12288 + cur * 4096;
        s8v af[4], bfr[4];
        #pragma unroll
        for (int mt = 0; mt < 4; ++mt) {
            int rr = wrow + mt * 16 + col;
            af[mt] = *(const s8v*)(As + ((rr * 32 + ((quad ^ (rr & 3)) << 3)) ^ (((rr >> 2) & 1) << 5)));
        }
        #pragma unroll
        for (int nt = 0; nt < 4; ++nt) {
            int rr = wcol + nt * 16 + col;
            bfr[nt] = *(const s8v*)(Ws + ((rr * 32 + ((quad ^ (rr & 3)) << 3)) ^ (((rr >> 2) & 1) << 5)));
        }
        __builtin_amdgcn_s_setprio(1);
        #pragma unroll
        for (int mt = 0; mt < 4; ++mt)
            #pragma unroll
            for (int nt = 0; nt < 4; ++nt)
                acc[mt][nt] = __builtin_amdgcn_mfma_f32_16x16x32_bf16(af[mt], bfr[nt], acc[mt][nt], 0, 0, 0);
        __builtin_amdgcn_s_setprio(0);
    }
#undef STAGE32

    if (QKV) {
        const int sel = n0 >> 10;
        unsigned short* Cb = (unsigned short*)(sel == 0 ? C0 : sel == 1 ? C1 : C2);
        const float* bs = sel == 0 ? b0 : sel == 1 ? b1 : b2;
        #pragma unroll
        for (int mt = 0; mt < 4; ++mt)
            #pragma unroll
            for (int rg = 0; rg < 4; ++rg) {
                int gm = m0 + wrow + mt * 16 + quad * 4 + rg;
                #pragma unroll
                for (int nt = 0; nt < 4; ++nt) {
                    int gnc = (n0 + wcol + nt * 16 + col) & 1023;
                    Cb[(size_t)gm * 1024 + gnc] = f2b(acc[mt][nt][rg] + bs[gnc]);
                }
            }
    } else {
        void* Cv = blockIdx.z ? C1 : C0;
        const bool z0 = (blockIdx.z == 0);
        #pragma unroll
        for (int mt = 0; mt < 4; ++mt)
            #pragma unroll
            for (int rg = 0; rg < 4; ++rg) {
                int gm = m0 + wrow + mt * 16 + quad * 4 + rg;
                #pragma unroll
                for (int nt = 0; nt < 4; ++nt) {
                    int gn = n0 + wcol + nt * 16 + col;
                    float c = acc[mt][nt][rg];
                    if (z0) {
                        if (b0)  c += b0[gn];
                        if (res) c += to_f(res[(size_t)gm * ldc + gn]);
                    }
                    if (RELU) c = fmaxf(c, 0.f);
                    if (sizeof(TC) == 2) ((unsigned short*)Cv)[(size_t)gm * ldc + gn] = f2b(c);
                    else                 ((float*)Cv)[(size_t)gm * ldc + gn] = c;
                }
            }
    }
}

// ============ 128x64 MFMA GEMM, BK=32 dbuf (verified R10) — Wo only ============
template<typename TC, typename TR, int RELU>
__global__ __launch_bounds__(256)
void mfma_gemm64n(const unsigned short* __restrict__ A, int lda,
                  const unsigned short* __restrict__ W, int ldw,
                  const float* __restrict__ b0,
                  const TR* __restrict__ res,
                  void* __restrict__ C0, void* __restrict__ C1,
                  int ldc, int M, int N, int Ksplit)
{
    __shared__ unsigned short sm[2 * 4096 + 2 * 2048];   // 24KB: As[2][128][32], Ws[2][64][32]
    const int tid = threadIdx.x;
    const int w = tid >> 6, lane = tid & 63;
    const int quad = lane >> 4, col = lane & 15;

    const int bid = blockIdx.x + gridDim.x * blockIdx.y;
    const int nwg = gridDim.x * gridDim.y;
    const int swz = (bid & 7) * (nwg >> 3) + (bid >> 3);
    const int m0 = (swz / gridDim.x) * 128;
    const int n0 = (swz % gridDim.x) * 64;

    const int wrow = (w & 1) * 64, wcol = (w >> 1) * 32;
    const int kz = blockIdx.z * Ksplit;
    const int NT = Ksplit >> 5;

    int sr0, sq0, sr1, sq1;
    {
        const int i0_ = tid;
        int sp = i0_ & 63, rl = ((sp >> 2) ^ (sp >> 4)) & 1;
        sr0 = ((i0_ >> 6) << 4) | ((sp >> 2) & 0xE) | rl;
        sq0 = (sp & 3) ^ ((((sp >> 3) & 1) << 1) | rl);
        const int i1_ = 256 + tid;
        sp = i1_ & 63; rl = ((sp >> 2) ^ (sp >> 4)) & 1;
        sr1 = ((i1_ >> 6) << 4) | ((sp >> 2) & 0xE) | rl;
        sq1 = (sp & 3) ^ ((((sp >> 3) & 1) << 1) | rl);
    }
    const unsigned off0 = (unsigned)__builtin_amdgcn_readfirstlane((unsigned)((tid & 192) * 16));
    const unsigned off1 = (unsigned)__builtin_amdgcn_readfirstlane((unsigned)((256 + (tid & 192)) * 16));

#define STAGE64N(buf, k0)                                                                    \
    {                                                                                        \
        unsigned short* As_ = sm + (buf) * 4096;                                             \
        unsigned short* Ws_ = sm + 8192 + (buf) * 2048;                                      \
        const unsigned short* ga0 = A + (size_t)(m0 + sr0) * lda + (k0) + sq0 * 8;           \
        __builtin_amdgcn_global_load_lds(                                                    \
            (const __attribute__((address_space(1))) unsigned int*)ga0,                      \
            (__attribute__((address_space(3))) unsigned int*)((char*)As_ + off0), 16, 0, 0); \
        const unsigned short* ga1 = A + (size_t)(m0 + sr1) * lda + (k0) + sq1 * 8;           \
        __builtin_amdgcn_global_load_lds(                                                    \
            (const __attribute__((address_space(1))) unsigned int*)ga1,                      \
            (__attribute__((address_space(3))) unsigned int*)((char*)As_ + off1), 16, 0, 0); \
        const unsigned short* gw0 = W + (size_t)(n0 + sr0) * ldw + (k0) + sq0 * 8;           \
        __builtin_amdgcn_global_load_lds(                                                    \
            (const __attribute__((address_space(1))) unsigned int*)gw0,                      \
            (__attribute__((address_space(3))) unsigned int*)((char*)Ws_ + off0), 16, 0, 0); \
    }

    f32x4 acc[4][2] = {};

    STAGE64N(0, kz);

    for (int t = 0; t < NT; ++t) {
        __syncthreads();
        const int cur = t & 1;
        if (t + 1 < NT) STAGE64N(cur ^ 1, kz + (t + 1) * 32);

        const unsigned short* As = sm + cur * 4096;
        const unsigned short* Ws = sm + 8192 + cur * 2048;
        s8v af[4], bfr[2];
        #pragma unroll
        for (int mt = 0; mt < 4; ++mt) {
            int rr = wrow + mt * 16 + col;
            af[mt] = *(const s8v*)(As + ((rr * 32 + ((quad ^ (rr & 3)) << 3)) ^ (((rr >> 2) & 1) << 5)));
        }
        #pragma unroll
        for (int nt = 0; nt < 2; ++nt) {
            int rr = wcol + nt * 16 + col;
            bfr[nt] = *(const s8v*)(Ws + ((rr * 32 + ((quad ^ (rr & 3)) << 3)) ^ (((rr >> 2) & 1) << 5)));
        }
        __builtin_amdgcn_s_setprio(1);
        #pragma unroll
        for (int mt = 0; mt < 4; ++mt)
            #pragma unroll
            for (int nt = 0; nt < 2; ++nt)
                acc[mt][nt] = __builtin_amdgcn_mfma_f32_16x16x32_bf16(af[mt], bfr[nt], acc[mt][nt], 0, 0, 0);
        __builtin_amdgcn_s_setprio(0);
    }
#undef STAGE64N

    void* Cv = blockIdx.z ? C1 : C0;
    const bool z0 = (blockIdx.z == 0);
    #pragma unroll
    for (int mt = 0; mt < 4; ++mt)
        #pragma unroll
        for (int rg = 0; rg < 4; ++rg) {
            int gm = m0 + wrow + mt * 16 + quad * 4 + rg;
            #pragma unroll
            for (int nt = 0; nt < 2; ++nt) {
                int gn = n0 + wcol + nt * 16 + col;
                float c = acc[mt][nt][rg];
                if (z0) {
                    if (b0)  c += b0[gn];
                    if (res) c += to_f(res[(size_t)gm * ldc + gn]);
                }
                if (RELU) c = fmaxf(c, 0.f);
                if (sizeof(TC) == 2) ((unsigned short*)Cv)[(size_t)gm * ldc + gn] = f2b(c);
                else                 ((float*)Cv)[(size_t)gm * ldc + gn] = c;
            }
        }
}

// ============ 256x128 MFMA GEMM, 8 waves, BK=32 dbuf (verified R7) — ff1 ============
template<typename TC, typename TR, int RELU, int QKV>
__global__ __launch_bounds__(512)
void mfma_gemm256(const unsigned short* __restrict__ A, int lda,
                  const unsigned short* __restrict__ W, int ldw,
                  const float* __restrict__ b0, const float* __restrict__ b1,
                  const float* __restrict__ b2,
                  const TR* __restrict__ res,
                  void* __restrict__ C0, void* __restrict__ C1, void* __restrict__ C2,
                  int ldc, int M, int N, int Ksplit)
{
    __shared__ unsigned short sm[2 * 8192 + 2 * 4096];   // 48KB: A dbuf [2][256][32], W dbuf [2][128][32]
    const int tid = threadIdx.x;
    const int w = tid >> 6, lane = tid & 63;
    const int quad = lane >> 4, col = lane & 15;

    const int bid = blockIdx.x + gridDim.x * blockIdx.y;
    const int xcd = bid & 7, j = bid >> 3;
    const int rh = gridDim.y >> 1, cw = gridDim.x >> 2;
    const int m0 = (((xcd & 1) * rh) + (j % rh)) * 256;
    const int n0 = (((xcd >> 1) * cw) + (j / rh)) * 128;

    const int wrow = (w & 3) * 64, wcol = (w >> 2) * 64;
    const int kz = blockIdx.z * Ksplit;
    const int NT = Ksplit >> 5;

    int sr0, sq0, sr1, sq1, sr2, sq2;
    {
        int idx = tid;
        int sp = idx & 63, rl = ((sp >> 2) ^ (sp >> 4)) & 1;
        sr0 = ((idx >> 6) << 4) | ((sp >> 2) & 0xE) | rl;
        sq0 = (sp & 3) ^ ((((sp >> 3) & 1) << 1) | rl);
        idx = 512 + tid;
        sp = idx & 63; rl = ((sp >> 2) ^ (sp >> 4)) & 1;
        sr1 = ((idx >> 6) << 4) | ((sp >> 2) & 0xE) | rl;
        sq1 = (sp & 3) ^ ((((sp >> 3) & 1) << 1) | rl);
        sr2 = sr0; sq2 = sq0;
    }
    const unsigned offA0 = (unsigned)__builtin_amdgcn_readfirstlane((unsigned)((tid & 448) * 16));
    const unsigned offA1 = (unsigned)__builtin_amdgcn_readfirstlane((unsigned)((512 + (tid & 448)) * 16));
    const unsigned offW0 = offA0;

#define STAGE(buf, k0)                                                                       \
    {                                                                                        \
        unsigned short* As_ = sm + (buf) * 8192;                                             \
        unsigned short* Ws_ = sm + 16384 + (buf) * 4096;                                     \
        const unsigned short* ga0 = A + (size_t)(m0 + sr0) * lda + (k0) + sq0 * 8;           \
        __builtin_amdgcn_global_load_lds(                                                    \
            (const __attribute__((address_space(1))) unsigned int*)ga0,                      \
            (__attribute__((address_space(3))) unsigned int*)((char*)As_ + offA0), 16, 0, 0);\
        const unsigned short* ga1 = A + (size_t)(m0 + sr1) * lda + (k0) + sq1 * 8;           \
        __builtin_amdgcn_global_load_lds(                                                    \
            (const __attribute__((address_space(1))) unsigned int*)ga1,                      \
            (__attribute__((address_space(3))) unsigned int*)((char*)As_ + offA1), 16, 0, 0);\
        const unsigned short* gw0 = W + (size_t)(n0 + sr2) * ldw + (k0) + sq2 * 8;           \
        __builtin_amdgcn_global_load_lds(                                                    \
            (const __attribute__((address_space(1))) unsigned int*)gw0,                      \
            (__attribute__((address_space(3))) unsigned int*)((char*)Ws_ + offW0), 16, 0, 0);\
    }

    f32x4 acc[4][4] = {};

    STAGE(0, kz);

    for (int t = 0; t < NT; ++t) {
        __syncthreads();
        const int cur = t & 1;
        if (t + 1 < NT) STAGE(cur ^ 1, kz + (t + 1) * 32);

        const unsigned short* As = sm + cur * 8192;
        const unsigned short* Ws = sm + 16384 + cur * 4096;
        s8v af[4], bfr[4];
        #pragma unroll
        for (int mt = 0; mt < 4; ++mt) {
            int rr = wrow + mt * 16 + col;
            af[mt] = *(const s8v*)(As + ((rr * 32 + ((quad ^ (rr & 3)) << 3)) ^ (((rr >> 2) & 1) << 5)));
        }
        #pragma unroll
        for (int nt = 0; nt < 4; ++nt) {
            int rr = wcol + nt * 16 + col;
            bfr[nt] = *(const s8v*)(Ws + ((rr * 32 + ((quad ^ (rr & 3)) << 3)) ^ (((rr >> 2) & 1) << 5)));
        }
        __builtin_amdgcn_s_setprio(1);
        #pragma unroll
        for (int mt = 0; mt < 4; ++mt)
            #pragma unroll
            for (int nt = 0; nt < 4; ++nt)
                acc[mt][nt] = __builtin_amdgcn_mfma_f32_16x16x32_bf16(af[mt], bfr[nt], acc[mt][nt], 0, 0, 0);
        __builtin_amdgcn_s_setprio(0);
    }
#undef STAGE

    if (QKV) {
        const int sel = n0 >> 10;
        unsigned short* Cb = (unsigned short*)(sel == 0 ? C0 : sel == 1 ? C1 : C2);
        const float* bs = sel == 0 ? b0 : sel == 1 ? b1 : b2;
        #pragma unroll
        for (int mt = 0; mt < 4; ++mt)
            #pragma unroll
            for (int rg = 0; rg < 4; ++rg) {
                int gm = m0 + wrow + mt * 16 + quad * 4 + rg;
                #pragma unroll
                for (int nt = 0; nt < 4; ++nt) {
                    int gnc = (n0 + wcol + nt * 16 + col) & 1023;
                    Cb[(size_t)gm * 1024 + gnc] = f2b(acc[mt][nt][rg] + bs[gnc]);
                }
            }
    } else {
        void* Cv = blockIdx.z ? C1 : C0;
        const bool z0 = (blockIdx.z == 0);
        #pragma unroll
        for (int mt = 0; mt < 4; ++mt)
            #pragma unroll
            for (int rg = 0; rg < 4; ++rg) {
                int gm = m0 + wrow + mt * 16 + quad * 4 + rg;
                #pragma unroll
                for (int nt = 0; nt < 4; ++nt) {
                    int gn = n0 + wcol + nt * 16 + col;
                    float c = acc[mt][nt][rg];
                    if (z0) {
                        if (b0)  c += b0[gn];
                        if (res) c += to_f(res[(size_t)gm * ldc + gn]);
                    }
                    if (RELU) c = fmaxf(c, 0.f);
                    if (sizeof(TC) == 2) ((unsigned short*)Cv)[(size_t)gm * ldc + gn] = f2b(c);
                    else                 ((float*)Cv)[(size_t)gm * ldc + gn] = c;
                }
            }
    }
}

// ---------------- V transpose: vb bf16 [4096][1024] -> vt bf16 [bp][d][j] ----------------
__global__ __launch_bounds__(256)
void vtrans_kernel(const unsigned short* __restrict__ v, unsigned short* __restrict__ vt)
{
    __shared__ unsigned short t[64][68];
    const int bpmm = blockIdx.x;
    const int bp = bpmm >> 6, mm = bpmm & 63;
    const unsigned short* vr = v + (size_t)(bp * 64 + mm) * 1024;
    const int tid = threadIdx.x;
    #pragma unroll
    for (int it = 0; it < 4; ++it) {
        int c = (tid >> 6) + it * 4;
        int d = tid & 63;
        t[d][c] = vr[c * 64 + d];
    }
    __syncthreads();
    int d = tid >> 2, qq = tid & 3;
    ushort4 o = { t[d][qq * 4 + 0], t[d][qq * 4 + 1], t[d][qq * 4 + 2], t[d][qq * 4 + 3] };
    *(ushort4*)(vt + (size_t)bp * 65536 + (size_t)d * 1024 + mm * 16 + qq * 4) = o;
}

// ---------------- MFMA attention v4: Q-frag hoist + setprio (verified R12) ----------------
__global__ __launch_bounds__(256, 2)
void attn_mfma_kernel(const unsigned short* __restrict__ qb,
                      const unsigned short* __restrict__ kb,
                      const unsigned short* __restrict__ vt,
                      const unsigned short* __restrict__ rbias,
                      const int* __restrict__ pmask,
                      unsigned short* __restrict__ att)
{
    __shared__ unsigned short Qs[128 * 64];
    __shared__ unsigned short KP[128 * 64];
    __shared__ unsigned short Vt[64 * 128];
    __shared__ unsigned short rbs[2048];
    __shared__ unsigned short pmls[1024];

    const int tid = threadIdx.x;
    const int w = tid >> 6, lane = tid & 63;
    const int quad = lane >> 4, col = lane & 15;
    const int bp = blockIdx.x, i0 = blockIdx.y * 128;
    const int h = bp & 15, bb = bp >> 4;
    const size_t base = (size_t)bp << 16;
    const int myrow0 = w * 32, myrow1 = w * 32 + 16;

    {
        const unsigned short* qg = qb + base + (size_t)i0 * 64;
        #pragma unroll
        for (int it = 0; it < 4; ++it) {
            int idx = it * 256 + tid;
            int r = idx >> 3, c = idx & 7;
            s8v d = *(const s8v*)(qg + (size_t)r * 64 + (c ^ (r & 7)) * 8);
            *(s8v*)(Qs + r * 64 + c * 8) = d;
        }
    }
    {
        const unsigned short* rg = rbias + h * 2048;
        #pragma unroll
        for (int it = 0; it < 8; ++it) rbs[it * 256 + tid] = rg[it * 256 + tid];
    }
    #pragma unroll
    for (int it = 0; it < 4; ++it) {
        int j = it * 256 + tid;
        pmls[j] = f2b(__logf((float)pmask[bb * 1024 + j]));
    }

    __syncthreads();
    s8v qa0[2], qa1[2];
    {
        const int ar0 = myrow0 + col, ar1 = myrow1 + col;
        #pragma unroll
        for (int ks = 0; ks < 2; ++ks) {
            qa0[ks] = *(const s8v*)(Qs + ar0 * 64 + (((ks * 4 + quad) ^ (ar0 & 7)) * 8));
            qa1[ks] = *(const s8v*)(Qs + ar1 * 64 + (((ks * 4 + quad) ^ (ar1 & 7)) * 8));
        }
    }

    f32x4 O0[4] = {}, O1[4] = {};
    float lrow0[4] = {0.f, 0.f, 0.f, 0.f};
    float lrow1[4] = {0.f, 0.f, 0.f, 0.f};

    unsigned short* Pw = KP + w * 2048;

    for (int jt = 0; jt < 8; ++jt) {
        const int j0 = jt * 128;
        __syncthreads();
        {
            const unsigned short* kg = kb + base + (size_t)j0 * 64;
            #pragma unroll
            for (int it = 0; it < 4; ++it) {
                int idx = it * 256 + tid;
                int r = idx >> 3, c = idx & 7;
                s8v d = *(const s8v*)(kg + (size_t)r * 64 + (c ^ (r & 7)) * 8);
                *(s8v*)(KP + r * 64 + c * 8) = d;
            }
            const unsigned short* vg = vt + base + j0;
            #pragma unroll
            for (int it = 0; it < 4; ++it) {
                int idx = it * 256 + tid;
                int r = idx >> 4, c = idx & 15;
                s8v d = *(const s8v*)(vg + (size_t)r * 1024 + (c ^ (r & 15)) * 8);
                *(s8v*)(Vt + r * 128 + c * 8) = d;
            }
        }
        __syncthreads();

        f32x4 S0[8] = {}, S1[8] = {};
        #pragma unroll
        for (int ks = 0; ks < 2; ++ks) {
            __builtin_amdgcn_s_setprio(1);
            #pragma unroll
            for (int ct = 0; ct < 8; ++ct) {
                int br = ct * 16 + col;
                s8v b = *(const s8v*)(KP + br * 64 + (((ks * 4 + quad) ^ (br & 7)) * 8));
                S0[ct] = __builtin_amdgcn_mfma_f32_16x16x32_bf16(qa0[ks], b, S0[ct], 0, 0, 0);
                S1[ct] = __builtin_amdgcn_mfma_f32_16x16x32_bf16(qa1[ks], b, S1[ct], 0, 0, 0);
            }
            __builtin_amdgcn_s_setprio(0);
        }

        #pragma unroll
        for (int ct = 0; ct < 8; ++ct) {
            int gj = j0 + ct * 16 + col;
            float pmv = bits2f(pmls[gj]);
            int d0 = gj - (i0 + myrow0 + quad * 4) + 1023;
            int d1 = gj - (i0 + myrow1 + quad * 4) + 1023;
            #pragma unroll
            for (int r = 0; r < 4; ++r) {
                float e0 = __expf(S0[ct][r] + bits2f(rbs[d0 - r]) + pmv);
                float e1 = __expf(S1[ct][r] + bits2f(rbs[d1 - r]) + pmv);
                S0[ct][r] = e0; lrow0[r] += e0;
                S1[ct][r] = e1; lrow1[r] += e1;
            }
        }

        __syncthreads();

        #pragma unroll
        for (int ct = 0; ct < 8; ++ct)
            #pragma unroll
            for (int r = 0; r < 4; ++r) {
                int lr = quad * 4 + r;
                int j = ct * 16 + col;
                Pw[lr * 128 + (((j >> 3) ^ lr) << 3) + (j & 7)] = f2b(S0[ct][r]);
            }
        #pragma unroll
        for (int kt = 0; kt < 4; ++kt) {
            int pr = col;
            s8v a = *(const s8v*)(Pw + pr * 128 + (((kt * 4 + quad) ^ pr) * 8));
            __builtin_amdgcn_s_setprio(1);
            #pragma unroll
            for (int nt = 0; nt < 4; ++nt) {
                int vr = nt * 16 + col;
                s8v b = *(const s8v*)(Vt + vr * 128 + (((kt * 4 + quad) ^ (vr & 15)) * 8));
                O0[nt] = __builtin_amdgcn_mfma_f32_16x16x32_bf16(a, b, O0[nt], 0, 0, 0);
            }
            __builtin_amdgcn_s_setprio(0);
        }

        #pragma unroll
        for (int ct = 0; ct < 8; ++ct)
            #pragma unroll
            for (int r = 0; r < 4; ++r) {
                int lr = quad * 4 + r;
                int j = ct * 16 + col;
                Pw[lr * 128 + (((j >> 3) ^ lr) << 3) + (j & 7)] = f2b(S1[ct][r]);
            }
        #pragma unroll
        for (int kt = 0; kt < 4; ++kt) {
            int pr = col;
            s8v a = *(const s8v*)(Pw + pr * 128 + (((kt * 4 + quad) ^ pr) * 8));
            __builtin_amdgcn_s_setprio(1);
            #pragma unroll
            for (int nt = 0; nt < 4; ++nt) {
                int vr = nt * 16 + col;
                s8v b = *(const s8v*)(Vt + vr * 128 + (((kt * 4 + quad) ^ (vr & 15)) * 8));
                O1[nt] = __builtin_amdgcn_mfma_f32_16x16x32_bf16(a, b, O1[nt], 0, 0, 0);
            }
            __builtin_amdgcn_s_setprio(0);
        }
    }

    #pragma unroll
    for (int off = 1; off < 16; off <<= 1)
        #pragma unroll
        for (int r = 0; r < 4; ++r) {
            lrow0[r] += __shfl_xor(lrow0[r], off);
            lrow1[r] += __shfl_xor(lrow1[r], off);
        }
    #pragma unroll
    for (int r = 0; r < 4; ++r) {
        lrow0[r] = 1.f / lrow0[r];
        lrow1[r] = 1.f / lrow1[r];
    }

    unsigned short* ag0 = att + base + (size_t)(i0 + myrow0) * 64;
    unsigned short* ag1 = att + base + (size_t)(i0 + myrow1) * 64;
    #pragma unroll
    for (int nt = 0; nt < 4; ++nt)
        #pragma unroll
        for (int r = 0; r < 4; ++r) {
            ag0[(size_t)(quad * 4 + r) * 64 + nt * 16 + col] = f2b(O0[nt][r] * lrow0[r]);
            ag1[(size_t)(quad * 4 + r) * 64 + nt * 16 + col] = f2b(O1[nt][r] * lrow1[r]);
        }
}

// ---------------- layernorm over rows of 1024: in1+in2 -> (outF fp32, outB bf16) ----------------
template<typename TIN>
__global__ __launch_bounds__(256)
void ln_kernel(const TIN* __restrict__ in1, const TIN* __restrict__ in2,
               float* __restrict__ outF, unsigned short* __restrict__ outB)
{
    __shared__ float sred[8];
    const int row = blockIdx.x;
    const int tid = threadIdx.x;
    const size_t off = (size_t)row * 1024 + tid * 4;
    float a[4];
    load4(in1 + off, a);
    if (in2) {
        float b[4];
        load4(in2 + off, b);
        #pragma unroll
        for (int i = 0; i < 4; ++i) a[i] += b[i];
    }

    float lsum = a[0] + a[1] + a[2] + a[3];
    #pragma unroll
    for (int o = 32; o; o >>= 1) lsum += __shfl_down(lsum, o);
    const int lane = tid & 63, wid = tid >> 6;
    if (lane == 0) sred[wid] = lsum;
    __syncthreads();
    if (tid == 0) sred[4] = (sred[0] + sred[1] + sred[2] + sred[3]) * (1.f / 1024.f);
    __syncthreads();
    const float mean = sred[4];

    float d0 = a[0] - mean, d1 = a[1] - mean, d2 = a[2] - mean, d3 = a[3] - mean;
    float lsq = d0 * d0 + d1 * d1 + d2 * d2 + d3 * d3;
    #pragma unroll
    for (int o = 32; o; o >>= 1) lsq += __shfl_down(lsq, o);
    __syncthreads();
    if (lane == 0) sred[wid] = lsq;
    __syncthreads();
    if (tid == 0) sred[5] = rsqrtf((sred[0] + sred[1] + sred[2] + sred[3]) * (1.f / 1024.f));
    __syncthreads();
    const float r = sred[5];

    float o0 = d0 * r, o1 = d1 * r, o2 = d2 * r, o3 = d3 * r;
    if (outF) {
        float4 o = {o0, o1, o2, o3};
        *(float4*)&outF[off] = o;
    }
    if (outB) {
        ushort4 o = { f2b(o0), f2b(o1), f2b(o2), f2b(o3) };
        *(ushort4*)&outB[off] = o;
    }
}

extern "C" void kernel_launch(void* const* d_in, const int* in_sizes, int n_in,
                              void* d_out, int out_size, void* d_ws, size_t ws_size,
                              hipStream_t stream)
{
    const float* x     = (const float*)d_in[0];
    const int*   pmask = (const int*)  d_in[1];
    const float* Wq    = (const float*)d_in[2];
    const float* bq    = (const float*)d_in[3];
    const float* Wk    = (const float*)d_in[4];
    const float* bk    = (const float*)d_in[5];
    const float* Wv    = (const float*)d_in[6];
    const float* bv    = (const float*)d_in[7];
    const float* Wo    = (const float*)d_in[8];
    const float* bo    = (const float*)d_in[9];
    const float* rel   = (const float*)d_in[10];
    const float* W1    = (const float*)d_in[11];
    const float* b1    = (const float*)d_in[12];
    const float* W2    = (const float*)d_in[13];
    const float* b2    = (const float*)d_in[14];

    const int M = 4096, D = 1024;
    dim3 blk(256);
    dim3 gblk(512);

    // ---- workspace map (identical to round-7/8-proven; peak write 64MB+64KB) ----
    char* ws = (char*)d_ws;
    unsigned short* W1b   = (unsigned short*)(ws);                 // 0-8
    unsigned short* W2b   = (unsigned short*)(ws + ( 8u << 20));   // 8-16
    unsigned short* xb    = (unsigned short*)(ws + (16u << 20));   // 16-24
    unsigned short* Wqkvb = (unsigned short*)(ws + (24u << 20));   // 24-30
    unsigned short* Wob   = (unsigned short*)(ws + (30u << 20));   // 30-32
    unsigned short* qb    = (unsigned short*)(ws + (32u << 20));   // 32-40
    unsigned short* kb    = (unsigned short*)(ws + (40u << 20));   // 40-48
    unsigned short* vb    = (unsigned short*)(ws + (48u << 20));   // 48-56
    unsigned short* vt    = (unsigned short*)(ws + (56u << 20));   // 56-64
    unsigned short* rbias = (unsigned short*)(ws + (64u << 20));   // 64-64.0625
    float*          tmpA    = (float*)(ws + (32u << 20));          // 32-48 (qb/kb dead after attn)
    float*          tmpB    = (float*)(ws + (48u << 20));          // 48-64 (vb/vt dead after attn)
    unsigned short* attoutB = (unsigned short*)(ws + (16u << 20)); // 16-24 (xb dead after qkv)
    unsigned short* ff1     = (unsigned short*)(ws + (32u << 20)); // 32-64 (tmpA/B dead after ln1)
    unsigned short* ff2a    = (unsigned short*)(ws);               // 0-8   (W1b dead after ff1)
    unsigned short* ff2b    = (unsigned short*)(ws + (24u << 20)); // 24-32 (Wqkvb/Wob dead)
    unsigned short* attb    = (unsigned short*)d_out;              // d_out scratch (proven)

    // ---- conversions + rbias table (merged, one dispatch) ----
    cvt_all_kernel<<<16384, blk, 0, stream>>>(x, Wq, Wk, Wv, Wo, W1, W2, rel,
                                              xb, Wqkvb, Wob, W1b, W2b, rbias);

    // ---- fused QKV projection: 128² depth-2 counted-vmcnt (768 blocks = 3/CU) ----
    mfma_gemm128<unsigned short, float, 0, 1><<<dim3(24, 32), blk, 0, stream>>>(
        xb, D, Wqkvb, D, bq, bk, bv, (const float*)nullptr, qb, kb, vb, D, M, 3072, D);

    vtrans_kernel<<<4096, blk, 0, stream>>>(vb, vt);

    // ---- attention v4 (unchanged from R12) ----
    attn_mfma_kernel<<<dim3(64, 8), blk, 0, stream>>>(qb, kb, vt, rbias, pmask, attb);

    // ---- Wo projection + residual x: 128x64 tile split-K z=2 (1024 blocks = 4/CU); LN1 ----
    mfma_gemm64n<float, float, 0><<<dim3(16, 32, 2), blk, 0, stream>>>(
        attb, D, Wob, D, bo, x, tmpA, tmpB, D, M, D, 512);
    ln_kernel<float><<<4096, blk, 0, stream>>>(tmpA, tmpB, nullptr, attoutB);

    // ---- FFN: ff1 256-tile (512 = 2/CU even); ff2 128² depth-2 counted-vmcnt z=2; LN2 ----
    mfma_gemm256<unsigned short, float, 1, 0><<<dim3(32, 16), gblk, 0, stream>>>(
        attoutB, D, W1b, D, b1, nullptr, nullptr, (const float*)nullptr,
        ff1, nullptr, nullptr, 4096, M, 4096, D);
    mfma_gemm128<unsigned short, unsigned short, 0, 0><<<dim3(8, 32, 2), blk, 0, stream>>>(
        ff1, 4096, W2b, 4096, b2, nullptr, nullptr, attoutB, ff2a, ff2b, nullptr, D, M, D, 2048);
    ln_kernel<unsigned short><<<4096, blk, 0, stream>>>(ff2a, ff2b, (float*)d_out, nullptr);
}